// Round 1
// baseline (44905.420 us; speedup 1.0000x reference)
//
#include <hip/hip_runtime.h>

#define Bb 64
#define Ss 512
#define Ff 512
#define Hh 1024
#define Oo 512
#define NWG 256
#define NW0 128
#define COLS 8
#define HB (Bb*Hh)   // 65536 floats per h buffer

__device__ __forceinline__ float sigm(float x){ return 1.0f/(1.0f+__expf(-x)); }
__device__ __forceinline__ float tanhf_(float x){
  x = fminf(15.0f, fmaxf(-15.0f, x));
  float e = __expf(-2.0f*x);
  return (1.0f - e)/(1.0f + e);
}

// grid barrier: all 256 WGs co-resident (1 WG/CU forced by 128KB LDS, grid==CU count)
__device__ __forceinline__ void gridbar(unsigned* cnt, unsigned* gen, unsigned nwg){
  __threadfence();                 // release: drain my stores to device scope
  __syncthreads();                 // whole WG's fences done before arrival
  if (threadIdx.x == 0) {
    unsigned g = __hip_atomic_load(gen, __ATOMIC_RELAXED, __HIP_MEMORY_SCOPE_AGENT);
    unsigned a = __hip_atomic_fetch_add(cnt, 1u, __ATOMIC_ACQ_REL, __HIP_MEMORY_SCOPE_AGENT);
    if (a == nwg - 1u) {
      __hip_atomic_store(cnt, 0u, __ATOMIC_RELAXED, __HIP_MEMORY_SCOPE_AGENT);
      __hip_atomic_store(gen, g + 1u, __ATOMIC_RELEASE, __HIP_MEMORY_SCOPE_AGENT);
    } else {
      while (__hip_atomic_load(gen, __ATOMIC_RELAXED, __HIP_MEMORY_SCOPE_AGENT) == g)
        __builtin_amdgcn_s_sleep(4);
    }
    __threadfence();               // acquire: invalidate L1/L2 so fresh h is read
  }
  __syncthreads();
}

__global__ void init_ws_kernel(float* ws, int n){
  int i = blockIdx.x*blockDim.x + threadIdx.x;
  for (; i < n; i += gridDim.x*blockDim.x) ws[i] = 0.0f;
}

__global__ __launch_bounds__(256) void janet_persistent(
    const float* __restrict__ x,
    const float* __restrict__ Wf0, const float* __restrict__ bf0,
    const float* __restrict__ Wc0, const float* __restrict__ bc0,
    const float* __restrict__ Wf1, const float* __restrict__ bf1,
    const float* __restrict__ Wc1, const float* __restrict__ bc1,
    const float* __restrict__ Wfc, const float* __restrict__ bfc,
    float* __restrict__ out, float* __restrict__ ws)
{
  __shared__ float smem[32768];    // 128 KB -> 1 WG/CU
  unsigned* bar  = (unsigned*)ws;  // [0]=cnt [1]=gen
  float* h0buf = ws + 16;              // 2 x HB
  float* h1buf = ws + 16 + 2*HB;       // 2 x HB

  const int wid = blockIdx.x;
  const int tid = threadIdx.x;
  const bool isL0 = (wid < NW0);
  const int lw   = isL0 ? wid : (wid - NW0);
  const int col0 = lw * COLS;
  const int K    = isL0 ? (Ff + Hh) : (2*Hh);  // 1536 / 2048

  const float* Wf  = isL0 ? Wf0 : Wf1;
  const float* Wc  = isL0 ? Wc0 : Wc1;
  const float* bfp = isL0 ? bf0 : bf1;
  const float* bcp = isL0 ? bc0 : bc1;

  // stage weights to LDS, column-major [j][K] (conflict-free b128 reads later)
  float* smf = smem;
  float* smc = smem + COLS*K;
  for (int e = tid; e < COLS*K; e += 256) {
    int k = e >> 3, j = e & 7;
    smf[j*K + k] = Wf[(size_t)k*Hh + col0 + j];
    smc[j*K + k] = Wc[(size_t)k*Hh + col0 + j];
  }
  __syncthreads();

  const int b = tid >> 2;          // 0..63
  const int q = tid & 3;           // K-quarter
  const int ja = 2*q, jb = 2*q+1;  // the 2 columns this lane owns
  const float bfa = bfp[col0+ja], bfb = bfp[col0+jb];
  const float bca = bcp[col0+ja], bcb = bcp[col0+jb];
  float crega = 0.0f, cregb = 0.0f;   // cell state lives in registers

  const int niter = K >> 4;        // i covers 16 k's (4 per q-lane)

  for (int p = 0; p <= Ss; ++p) {
    const bool active = isL0 ? (p < Ss) : (p >= 1);
    if (active) {
      const float* r0; const float* r1; int split; float* hdst;
      if (isL0) {
        const int t = p;
        r0 = x + ((size_t)b*Ss + t)*Ff;              // k < 512 : x_t
        r1 = h0buf + ((p+1)&1)*HB + b*Hh;            // h0 at step p-1
        split = Ff;
        hdst = h0buf + (p&1)*HB;
      } else {
        r0 = h0buf + ((p-1)&1)*HB + b*Hh;            // h0 at step p-1
        r1 = h1buf + (p&1)*HB + b*Hh;                // h1 at step p-2
        split = Hh;
        hdst = h1buf + ((p-1)&1)*HB;
      }
      float accf[8] = {0,0,0,0,0,0,0,0};
      float accc[8] = {0,0,0,0,0,0,0,0};
      for (int i = 0; i < niter; ++i) {
        const int kk = i*16 + q*4;
        const float* src = (kk < split) ? (r0 + kk) : (r1 + (kk - split));
        const float4 cv = *(const float4*)src;
        #pragma unroll
        for (int j = 0; j < 8; ++j) {
          const float4 wf = *(const float4*)&smf[j*K + kk];
          const float4 wc = *(const float4*)&smc[j*K + kk];
          accf[j] += cv.x*wf.x + cv.y*wf.y + cv.z*wf.z + cv.w*wf.w;
          accc[j] += cv.x*wc.x + cv.y*wc.y + cv.z*wc.z + cv.w*wc.w;
        }
      }
      // reduce across the 4 k-quarter lanes (same wave, quads are lane-aligned)
      #pragma unroll
      for (int j = 0; j < 8; ++j) {
        accf[j] += __shfl_xor(accf[j], 1, 64);
        accf[j] += __shfl_xor(accf[j], 2, 64);
        accc[j] += __shfl_xor(accc[j], 1, 64);
        accc[j] += __shfl_xor(accc[j], 2, 64);
      }
      // this lane updates its 2 columns
      {
        float f  = sigm(accf[ja] + bfa);
        float ct = tanhf_(accc[ja] + bca);
        crega = f*crega + (1.0f - f)*ct;
        float f2  = sigm(accf[jb] + bfb);
        float ct2 = tanhf_(accc[jb] + bcb);
        cregb = f2*cregb + (1.0f - f2)*ct2;
        float2 hv = make_float2(tanhf_(crega), tanhf_(cregb));
        *(float2*)&hdst[(size_t)b*Hh + col0 + ja] = hv;
      }
    }
    gridbar(&bar[0], &bar[1], NWG);
  }

  // final projection: out = h1[t=511] @ Wfc + bfc ; h1 final is h1buf[1]
  const float* hf = h1buf + HB;          // parity (S-1)&1 == 1
  const int e0 = wid * 128;              // 32768 outputs / 256 WGs
  const int bb = e0 >> 9;                // same b for whole WG
  if (tid < 128) {
    const int oo = (e0 & 511) + tid;
    const float* hrow = hf + (size_t)bb*Hh;
    float acc = bfc[oo];
    for (int k = 0; k < Hh; ++k)
      acc += hrow[k] * Wfc[(size_t)k*Oo + oo];
    out[(size_t)bb*Oo + oo] = acc;
  }
}

extern "C" void kernel_launch(void* const* d_in, const int* in_sizes, int n_in,
                              void* d_out, int out_size, void* d_ws, size_t ws_size,
                              hipStream_t stream) {
  const float* x   = (const float*)d_in[0];
  const float* Wf0 = (const float*)d_in[1];
  const float* bf0 = (const float*)d_in[2];
  const float* Wc0 = (const float*)d_in[3];
  const float* bc0 = (const float*)d_in[4];
  const float* Wf1 = (const float*)d_in[5];
  const float* bf1 = (const float*)d_in[6];
  const float* Wc1 = (const float*)d_in[7];
  const float* bc1 = (const float*)d_in[8];
  const float* Wfc = (const float*)d_in[9];
  const float* bfc = (const float*)d_in[10];

  float* ws = (float*)d_ws;
  const int ws_init = 16 + 4*HB;   // barrier words + h0buf[2] + h1buf[2]

  init_ws_kernel<<<512, 256, 0, stream>>>(ws, ws_init);
  janet_persistent<<<NWG, 256, 0, stream>>>(x, Wf0, bf0, Wc0, bc0,
                                            Wf1, bf1, Wc1, bc1, Wfc, bfc,
                                            (float*)d_out, ws);
}

// Round 2
// 16002.129 us; speedup vs baseline: 2.8062x; 2.8062x over previous
//
#include <hip/hip_runtime.h>
#include <stdint.h>

typedef _Float16 f16;
typedef _Float16 f16x8 __attribute__((ext_vector_type(8)));
typedef float    f32x4 __attribute__((ext_vector_type(4)));

#define Bm 64
#define Ss 512
#define Ff 512
#define Hh 1024
#define Oo 512
#define NWG 128          // 64 L0 + 64 L1
#define HBh (Bm*Hh)      // halves per h half-buffer (65536)

// ws layout (bytes)
#define BAR_BYTES 4096
#define H0_OFF  BAR_BYTES
#define H1_OFF  (BAR_BYTES + 2*HBh*2)
#define WS_BYTES (BAR_BYTES + 4*HBh*2)   // 528384

__device__ __forceinline__ float sigm(float x){ return 1.0f/(1.0f+__expf(-x)); }
__device__ __forceinline__ float tanhf_(float x){
  x = fminf(15.0f, fmaxf(-15.0f, x));
  float e = __expf(-2.0f*x);
  return (1.0f - e)/(1.0f + e);
}

__global__ void init_ws_kernel(uint4* ws){
  const uint4 z = {0,0,0,0};
  int n = WS_BYTES/16;
  for (int i = blockIdx.x*blockDim.x + threadIdx.x; i < n; i += gridDim.x*blockDim.x)
    ws[i] = z;
}

// two-level monotonic barrier: 16 leaves x 8 WGs, then root, then gen broadcast
__device__ __forceinline__ void gridbar(unsigned* wsu, int p){
  __threadfence();               // drain my h stores to device scope
  __syncthreads();
  if (threadIdx.x == 0) {
    unsigned* leaf = wsu + (blockIdx.x & 15)*32;   // 128B apart
    unsigned* root = wsu + 512;
    unsigned* gen  = wsu + 544;
    unsigned tgt = (unsigned)(p + 1);
    unsigned a = __hip_atomic_fetch_add(leaf, 1u, __ATOMIC_ACQ_REL, __HIP_MEMORY_SCOPE_AGENT);
    if (a + 1u == 8u*tgt) {
      unsigned r = __hip_atomic_fetch_add(root, 1u, __ATOMIC_ACQ_REL, __HIP_MEMORY_SCOPE_AGENT);
      if (r + 1u == 16u*tgt)
        __hip_atomic_store(gen, tgt, __ATOMIC_RELEASE, __HIP_MEMORY_SCOPE_AGENT);
    }
    while (__hip_atomic_load(gen, __ATOMIC_RELAXED, __HIP_MEMORY_SCOPE_AGENT) < tgt)
      __builtin_amdgcn_s_sleep(1);
  }
  __syncthreads();
  __builtin_amdgcn_fence(__ATOMIC_ACQUIRE, "agent");  // all threads invalidate
}

__device__ __forceinline__ f16x8 cvt8(float4 v0, float4 v1){
  f16x8 a;
  a[0]=v0.x; a[1]=v0.y; a[2]=v0.z; a[3]=v0.w;
  a[4]=v1.x; a[5]=v1.y; a[6]=v1.z; a[7]=v1.w;
  return a;
}

__global__ __launch_bounds__(256,1) void janet_persistent(
    const float* __restrict__ x,
    const float* __restrict__ Wf0, const float* __restrict__ bf0,
    const float* __restrict__ Wc0, const float* __restrict__ bc0,
    const float* __restrict__ Wf1, const float* __restrict__ bf1,
    const float* __restrict__ Wc1, const float* __restrict__ bc1,
    const float* __restrict__ Wfc, const float* __restrict__ bfc,
    float* __restrict__ out, void* __restrict__ ws)
{
  __shared__ __align__(16) unsigned char smem[131072];   // 128 KB -> 1 WG/CU
  unsigned* wsu = (unsigned*)ws;
  f16* h0buf = (f16*)((char*)ws + H0_OFF);
  f16* h1buf = (f16*)((char*)ws + H1_OFF);

  const int wid  = blockIdx.x;
  const int tid  = threadIdx.x;
  const bool isL0 = (wid < 64);
  const int col0 = (isL0 ? wid : wid - 64) * 16;
  const int K    = isL0 ? (Ff + Hh) : (2*Hh);   // 1536 / 2048
  const int KS   = K >> 5;                      // 48 / 64 k-steps

  // ---- stage weights into LDS in MFMA B-fragment order [gate][ks][lane] ----
  {
    const float* Wg[2] = { isL0 ? Wf0 : Wf1, isL0 ? Wc0 : Wc1 };
    for (int g = 0; g < 2; ++g) {
      const float* W = Wg[g];
      for (int e = tid; e < 16*K; e += 256) {
        int n = e & 15, k = e >> 4;                 // coalesced 64B global reads
        float v = W[(size_t)k*Hh + col0 + n];
        int ks = k >> 5, sub = (k >> 3) & 3, j = k & 7;
        int lane = n + (sub << 4);
        int byte = ((g*KS + ks) << 10) + (lane << 4) + (j << 1);
        *(f16*)(smem + byte) = (f16)v;
      }
    }
  }
  __syncthreads();

  const int lane = tid & 63;
  const int wv   = tid >> 6;       // wave 0..3 -> rows 16*wv..16*wv+15
  const int n    = lane & 15;      // output col (within slice) & A/B frag index
  const int kg   = lane >> 4;      // k-group
  const int e8   = kg * 8;
  const int arow = 16*wv + n;      // row this lane LOADS (A-frag)
  const int row0 = 16*wv + kg*4;   // first row this lane OWNS (C/D frag)

  const float* bfp = isL0 ? bf0 : bf1;
  const float* bcp = isL0 ? bc0 : bc1;
  const float bfv = bfp[col0 + n];
  const float bcv = bcp[col0 + n];

  // per-lane LDS read base: frag ks at byte (g*KS+ks)*1024 + lane*16
  const f16x8* ldsA = (const f16x8*)(smem + (size_t)lane*16);   // stride 64 elems = 1024B

  f32x4 cst = {0.f,0.f,0.f,0.f};   // cell state (4 owned rows)

  for (int p = 0; p <= Ss; ++p) {
    bool active = isL0 ? (p < Ss) : (p >= 1);
    if (active) {
      f32x4 aF0={0.f,0.f,0.f,0.f}, aF1={0.f,0.f,0.f,0.f};
      f32x4 aC0={0.f,0.f,0.f,0.f}, aC1={0.f,0.f,0.f,0.f};
      f16* hdst;

      if (isL0) {
        const int t = p;
        const float* xb  = x + ((size_t)arow*Ss + (size_t)t)*Ff + e8;
        const f16*   h0r = h0buf + (size_t)((p+1)&1)*HBh + (size_t)arow*Hh + e8;
        hdst = h0buf + (size_t)(p&1)*HBh;
        #pragma unroll 8
        for (int ks = 0; ks < 16; ++ks) {           // x region (fp32 -> f16)
          float4 v0 = *(const float4*)(xb + 32*ks);
          float4 v1 = *(const float4*)(xb + 32*ks + 4);
          f16x8 a  = cvt8(v0, v1);
          f16x8 bf = ldsA[(size_t)ks*64];
          f16x8 bc = ldsA[(size_t)(48 + ks)*64];
          if (ks & 1) { aF1 = __builtin_amdgcn_mfma_f32_16x16x32_f16(a, bf, aF1, 0,0,0);
                        aC1 = __builtin_amdgcn_mfma_f32_16x16x32_f16(a, bc, aC1, 0,0,0); }
          else        { aF0 = __builtin_amdgcn_mfma_f32_16x16x32_f16(a, bf, aF0, 0,0,0);
                        aC0 = __builtin_amdgcn_mfma_f32_16x16x32_f16(a, bc, aC0, 0,0,0); }
        }
        #pragma unroll 8
        for (int ks2 = 0; ks2 < 32; ++ks2) {        // h0_{t-1} region
          int ks = 16 + ks2;
          f16x8 a  = *(const f16x8*)(h0r + 32*ks2);
          f16x8 bf = ldsA[(size_t)ks*64];
          f16x8 bc = ldsA[(size_t)(48 + ks)*64];
          if (ks & 1) { aF1 = __builtin_amdgcn_mfma_f32_16x16x32_f16(a, bf, aF1, 0,0,0);
                        aC1 = __builtin_amdgcn_mfma_f32_16x16x32_f16(a, bc, aC1, 0,0,0); }
          else        { aF0 = __builtin_amdgcn_mfma_f32_16x16x32_f16(a, bf, aF0, 0,0,0);
                        aC0 = __builtin_amdgcn_mfma_f32_16x16x32_f16(a, bc, aC0, 0,0,0); }
        }
      } else {
        const int s = p - 1;
        const f16* h0c = h0buf + (size_t)(s&1)*HBh     + (size_t)arow*Hh + e8;   // h0_s
        const f16* h1p = h1buf + (size_t)((s-1)&1)*HBh + (size_t)arow*Hh + e8;   // h1_{s-1}
        hdst = h1buf + (size_t)(s&1)*HBh;
        #pragma unroll 8
        for (int ks = 0; ks < 32; ++ks) {           // h0_s region
          f16x8 a  = *(const f16x8*)(h0c + 32*ks);
          f16x8 bf = ldsA[(size_t)ks*64];
          f16x8 bc = ldsA[(size_t)(64 + ks)*64];
          if (ks & 1) { aF1 = __builtin_amdgcn_mfma_f32_16x16x32_f16(a, bf, aF1, 0,0,0);
                        aC1 = __builtin_amdgcn_mfma_f32_16x16x32_f16(a, bc, aC1, 0,0,0); }
          else        { aF0 = __builtin_amdgcn_mfma_f32_16x16x32_f16(a, bf, aF0, 0,0,0);
                        aC0 = __builtin_amdgcn_mfma_f32_16x16x32_f16(a, bc, aC0, 0,0,0); }
        }
        #pragma unroll 8
        for (int ks2 = 0; ks2 < 32; ++ks2) {        // h1_{s-1} region
          int ks = 32 + ks2;
          f16x8 a  = *(const f16x8*)(h1p + 32*ks2);
          f16x8 bf = ldsA[(size_t)ks*64];
          f16x8 bc = ldsA[(size_t)(64 + ks)*64];
          if (ks & 1) { aF1 = __builtin_amdgcn_mfma_f32_16x16x32_f16(a, bf, aF1, 0,0,0);
                        aC1 = __builtin_amdgcn_mfma_f32_16x16x32_f16(a, bc, aC1, 0,0,0); }
          else        { aF0 = __builtin_amdgcn_mfma_f32_16x16x32_f16(a, bf, aF0, 0,0,0);
                        aC0 = __builtin_amdgcn_mfma_f32_16x16x32_f16(a, bc, aC0, 0,0,0); }
        }
      }

      f32x4 pF = aF0 + aF1;
      f32x4 pC = aC0 + aC1;
      #pragma unroll
      for (int j = 0; j < 4; ++j) {
        float f  = sigm(pF[j] + bfv);
        float ct = tanhf_(pC[j] + bcv);
        cst[j] = f*cst[j] + (1.0f - f)*ct;
        hdst[(size_t)(row0 + j)*Hh + col0 + n] = (f16)tanhf_(cst[j]);
      }
    }
    gridbar(wsu, p);
  }

  // ---- final projection: out[b][o] = h1[:,511,:] @ Wfc + bfc ----
  // WG w owns output cols 4w..4w+3; thread: b = tid>>2, oo = tid&3
  {
    const f16* h1f = h1buf + (size_t)1*HBh;        // step 511 parity = 1
    const int o = wid*4 + (tid & 3);
    const int b = tid >> 2;
    const f16* hrow = h1f + (size_t)b*Hh;
    float acc = bfc[o];
    #pragma unroll 8
    for (int k = 0; k < Hh; ++k)
      acc += (float)hrow[k] * Wfc[(size_t)k*Oo + o];
    out[(size_t)b*Oo + o] = acc;
  }
}

extern "C" void kernel_launch(void* const* d_in, const int* in_sizes, int n_in,
                              void* d_out, int out_size, void* d_ws, size_t ws_size,
                              hipStream_t stream) {
  const float* x   = (const float*)d_in[0];
  const float* Wf0 = (const float*)d_in[1];
  const float* bf0 = (const float*)d_in[2];
  const float* Wc0 = (const float*)d_in[3];
  const float* bc0 = (const float*)d_in[4];
  const float* Wf1 = (const float*)d_in[5];
  const float* bf1 = (const float*)d_in[6];
  const float* Wc1 = (const float*)d_in[7];
  const float* bc1 = (const float*)d_in[8];
  const float* Wfc = (const float*)d_in[9];
  const float* bfc = (const float*)d_in[10];

  init_ws_kernel<<<64, 256, 0, stream>>>((uint4*)d_ws);
  janet_persistent<<<NWG, 256, 0, stream>>>(x, Wf0, bf0, Wc0, bc0,
                                            Wf1, bf1, Wc1, bc1, Wfc, bfc,
                                            (float*)d_out, d_ws);
}

// Round 3
// 5292.588 us; speedup vs baseline: 8.4846x; 3.0235x over previous
//
#include <hip/hip_runtime.h>
#include <stdint.h>

typedef _Float16 f16;
typedef _Float16 f16x8 __attribute__((ext_vector_type(8)));
typedef float    f32x4 __attribute__((ext_vector_type(4)));

#define Bm 64
#define Ss 512
#define Ff 512
#define Hh 1024
#define Oo 512
#define NWG 128          // 64 L0 + 64 L1
#define HBh (Bm*Hh)      // halves per h slot (65536)

// ws layout
#define CNT0_U32 0                       // cnt0[t] at u32 index 16*t (64B stride)
#define CNT1_U32 8192                    // cnt1[s] at u32 index 8192+16*s
#define H0_BYTE  65536                   // 4 slots x 128KB
#define H1_BYTE  (65536 + 4*HBh*2)      // 2 slots x 128KB
#define WS_BYTES (H1_BYTE + 2*HBh*2)    // 851968

#define MFMA16 __builtin_amdgcn_mfma_f32_16x16x32_f16

__device__ __forceinline__ float sigm(float x){ return 1.0f/(1.0f+__expf(-x)); }
__device__ __forceinline__ float tanhf_(float x){
  x = fminf(15.0f, fmaxf(-15.0f, x));
  float e = __expf(-2.0f*x);
  return (1.0f - e)/(1.0f + e);
}

__global__ void init_ws_kernel(uint4* ws){
  const uint4 z = {0,0,0,0};
  int n = WS_BYTES/16;
  for (int i = blockIdx.x*blockDim.x + threadIdx.x; i < n; i += gridDim.x*blockDim.x)
    ws[i] = z;
}

// issue 8 LLC-coherent 16B loads, 64B apart (A-fragment stride = 32 halves)
#define ISSUE8(A, P) asm volatile( \
  "global_load_dwordx4 %0, %8, off sc0 sc1\n\t" \
  "global_load_dwordx4 %1, %8, off offset:64 sc0 sc1\n\t" \
  "global_load_dwordx4 %2, %8, off offset:128 sc0 sc1\n\t" \
  "global_load_dwordx4 %3, %8, off offset:192 sc0 sc1\n\t" \
  "global_load_dwordx4 %4, %8, off offset:256 sc0 sc1\n\t" \
  "global_load_dwordx4 %5, %8, off offset:320 sc0 sc1\n\t" \
  "global_load_dwordx4 %6, %8, off offset:384 sc0 sc1\n\t" \
  "global_load_dwordx4 %7, %8, off offset:448 sc0 sc1" \
  : "=&v"(A[0]), "=&v"(A[1]), "=&v"(A[2]), "=&v"(A[3]), \
    "=&v"(A[4]), "=&v"(A[5]), "=&v"(A[6]), "=&v"(A[7]) \
  : "v"(P) : "memory")

// contiguous variant (16B apart) for the projection
#define ISSUE8C(A, P) asm volatile( \
  "global_load_dwordx4 %0, %8, off sc0 sc1\n\t" \
  "global_load_dwordx4 %1, %8, off offset:16 sc0 sc1\n\t" \
  "global_load_dwordx4 %2, %8, off offset:32 sc0 sc1\n\t" \
  "global_load_dwordx4 %3, %8, off offset:48 sc0 sc1\n\t" \
  "global_load_dwordx4 %4, %8, off offset:64 sc0 sc1\n\t" \
  "global_load_dwordx4 %5, %8, off offset:80 sc0 sc1\n\t" \
  "global_load_dwordx4 %6, %8, off offset:96 sc0 sc1\n\t" \
  "global_load_dwordx4 %7, %8, off offset:112 sc0 sc1" \
  : "=&v"(A[0]), "=&v"(A[1]), "=&v"(A[2]), "=&v"(A[3]), \
    "=&v"(A[4]), "=&v"(A[5]), "=&v"(A[6]), "=&v"(A[7]) \
  : "v"(P) : "memory")

// counted wait; block MFMA & VMEM motion across, allow DS_READ/VALU/SALU (0x106)
#define WAITV(N) do{ asm volatile("s_waitcnt vmcnt(" #N ")" ::: "memory"); \
                     __builtin_amdgcn_sched_barrier(0x106); }while(0)

// 8 k-steps of dual-gate MFMA from LDS weights
#define CONS8(Aarr, KSB, KSC) do{ \
  _Pragma("unroll") \
  for (int j = 0; j < 8; ++j){ \
    f16x8 bw = ldsA[(size_t)((KSB)+j)*64]; \
    f16x8 cw = ldsA[(size_t)((KSC)+(KSB)+j)*64]; \
    if (j & 1){ aF1 = MFMA16(Aarr[j], bw, aF1, 0,0,0); aC1 = MFMA16(Aarr[j], cw, aC1, 0,0,0); } \
    else      { aF0 = MFMA16(Aarr[j], bw, aF0, 0,0,0); aC0 = MFMA16(Aarr[j], cw, aC0, 0,0,0); } \
  } \
}while(0)

__device__ __forceinline__ f16x8 cvt8(float4 v0, float4 v1){
  f16x8 a;
  a[0]=v0.x; a[1]=v0.y; a[2]=v0.z; a[3]=v0.w;
  a[4]=v1.x; a[5]=v1.y; a[6]=v1.z; a[7]=v1.w;
  return a;
}

__device__ __forceinline__ void pollcnts(const unsigned* a, const unsigned* b){
  if (threadIdx.x == 0) {
    if (a) while (__hip_atomic_load(a, __ATOMIC_RELAXED, __HIP_MEMORY_SCOPE_AGENT) < 64u)
             __builtin_amdgcn_s_sleep(1);
    if (b) while (__hip_atomic_load(b, __ATOMIC_RELAXED, __HIP_MEMORY_SCOPE_AGENT) < 64u)
             __builtin_amdgcn_s_sleep(1);
  }
  __syncthreads();
}

__global__ __launch_bounds__(256,1) void janet_persistent(
    const float* __restrict__ x,
    const float* __restrict__ Wf0, const float* __restrict__ bf0,
    const float* __restrict__ Wc0, const float* __restrict__ bc0,
    const float* __restrict__ Wf1, const float* __restrict__ bf1,
    const float* __restrict__ Wc1, const float* __restrict__ bc1,
    const float* __restrict__ Wfc, const float* __restrict__ bfc,
    float* __restrict__ out, void* __restrict__ ws)
{
  __shared__ __align__(16) unsigned char smem[131072];   // 128 KB -> 1 WG/CU
  unsigned* wsu = (unsigned*)ws;
  unsigned* cnt0p = wsu + CNT0_U32;
  unsigned* cnt1p = wsu + CNT1_U32;
  f16* h0buf = (f16*)((char*)ws + H0_BYTE);   // 4 slots
  f16* h1buf = (f16*)((char*)ws + H1_BYTE);   // 2 slots

  const int wid  = blockIdx.x;
  const int tid  = threadIdx.x;
  const bool isL0 = (wid < 64);
  const int col0 = (isL0 ? wid : wid - 64) * 16;
  const int K    = isL0 ? (Ff + Hh) : (2*Hh);   // 1536 / 2048
  const int KS   = K >> 5;                      // 48 / 64

  // ---- stage weights into LDS in MFMA B-fragment order [gate][ks][lane] ----
  {
    const float* Wg[2] = { isL0 ? Wf0 : Wf1, isL0 ? Wc0 : Wc1 };
    for (int g = 0; g < 2; ++g) {
      const float* W = Wg[g];
      for (int e = tid; e < 16*K; e += 256) {
        int n = e & 15, k = e >> 4;
        float v = W[(size_t)k*Hh + col0 + n];
        int ks = k >> 5, sub = (k >> 3) & 3, j = k & 7;
        int lane = n + (sub << 4);
        int byte = ((g*KS + ks) << 10) + (lane << 4) + (j << 1);
        *(f16*)(smem + byte) = (f16)v;
      }
    }
  }
  __syncthreads();

  const int lane = tid & 63;
  const int wv   = tid >> 6;
  const int n    = lane & 15;
  const int kg   = lane >> 4;
  const int e8   = kg * 8;
  const int arow = 16*wv + n;      // row this lane LOADS (A-frag)
  const int row0 = 16*wv + kg*4;   // first row this lane OWNS (C/D frag)

  const float* bfp = isL0 ? bf0 : bf1;
  const float* bcp = isL0 ? bc0 : bc1;
  const float bfv = bfp[col0 + n];
  const float bcv = bcp[col0 + n];

  const f16x8* ldsA = (const f16x8*)(smem + (size_t)lane*16);

  f32x4 cst = {0.f,0.f,0.f,0.f};

  if (isL0) {
    for (int t = 0; t < Ss; ++t) {
      f32x4 aF0={0.f,0.f,0.f,0.f}, aF1={0.f,0.f,0.f,0.f};
      f32x4 aC0={0.f,0.f,0.f,0.f}, aC1={0.f,0.f,0.f,0.f};
      // ---- x region (independent of other WGs; overlaps producers) ----
      const float* xb = x + ((size_t)arow*Ss + (size_t)t)*Ff + e8;
      #pragma unroll 4
      for (int ks = 0; ks < 16; ++ks) {
        float4 v0 = *(const float4*)(xb + 32*ks);
        float4 v1 = *(const float4*)(xb + 32*ks + 4);
        f16x8 a = cvt8(v0, v1);
        f16x8 bw = ldsA[(size_t)ks*64];
        f16x8 cw = ldsA[(size_t)(48 + ks)*64];
        if (ks & 1){ aF1 = MFMA16(a, bw, aF1, 0,0,0); aC1 = MFMA16(a, cw, aC1, 0,0,0); }
        else       { aF0 = MFMA16(a, bw, aF0, 0,0,0); aC0 = MFMA16(a, cw, aC0, 0,0,0); }
      }
      // ---- wait for h0(t-1) complete, and L1 done reading h0(t-4) (WAR) ----
      pollcnts(t > 0 ? cnt0p + 16*(t-1) : nullptr,
               t >= 4 ? cnt1p + 16*(t-4) : nullptr);
      // ---- h0(t-1) region: 32 ks, LLC-coherent pipelined loads ----
      const f16* h0r = h0buf + (size_t)((t+3)&3)*HBh + (size_t)arow*Hh + e8;
      f16x8 A0[8], A1[8], A2[8], A3[8];
      __builtin_amdgcn_sched_barrier(0);
      ISSUE8(A0, h0r); ISSUE8(A1, h0r+256); ISSUE8(A2, h0r+512); ISSUE8(A3, h0r+768);
      WAITV(24); CONS8(A0, 16, 48);
      WAITV(16); CONS8(A1, 24, 48);
      WAITV(8);  CONS8(A2, 32, 48);
      WAITV(0);  CONS8(A3, 40, 48);
      // ---- activations + LLC store + completion ----
      f16* hd = h0buf + (size_t)(t&3)*HBh + (size_t)row0*Hh + col0 + n;
      f32x4 pF = aF0 + aF1, pC = aC0 + aC1;
      #pragma unroll
      for (int j = 0; j < 4; ++j) {
        float f  = sigm(pF[j] + bfv);
        float ct = tanhf_(pC[j] + bcv);
        cst[j] = f*cst[j] + (1.0f - f)*ct;
        union { _Float16 h; unsigned short u; } cv; cv.h = (f16)tanhf_(cst[j]);
        unsigned uu = cv.u;
        asm volatile("global_store_short %0, %1, off sc0 sc1"
                     :: "v"(hd + (size_t)j*Hh), "v"(uu) : "memory");
      }
      asm volatile("s_waitcnt vmcnt(0)" ::: "memory");
      __syncthreads();
      if (tid == 0)
        __hip_atomic_fetch_add(cnt0p + 16*t, 1u, __ATOMIC_RELAXED, __HIP_MEMORY_SCOPE_AGENT);
    }
  } else {
    for (int s = 0; s < Ss; ++s) {
      f32x4 aF0={0.f,0.f,0.f,0.f}, aF1={0.f,0.f,0.f,0.f};
      f32x4 aC0={0.f,0.f,0.f,0.f}, aC1={0.f,0.f,0.f,0.f};
      // need h0(s) complete and own-layer h1(s-1) complete
      pollcnts(cnt0p + 16*s, s > 0 ? cnt1p + 16*(s-1) : nullptr);
      const f16* h0c = h0buf + (size_t)(s&3)*HBh     + (size_t)arow*Hh + e8;
      const f16* h1p = h1buf + (size_t)((s+1)&1)*HBh + (size_t)arow*Hh + e8;
      f16x8 A0[8], A1[8], A2[8], A3[8];
      f16x8 B0[8], B1[8], B2[8], B3[8];
      __builtin_amdgcn_sched_barrier(0);
      ISSUE8(A0, h0c); ISSUE8(A1, h0c+256); ISSUE8(A2, h0c+512); ISSUE8(A3, h0c+768);
      WAITV(24); CONS8(A0, 0, 64);
      WAITV(16); CONS8(A1, 8, 64);
      WAITV(8);  CONS8(A2, 16, 64);
      ISSUE8(B0, h1p); ISSUE8(B1, h1p+256); ISSUE8(B2, h1p+512); ISSUE8(B3, h1p+768);
      WAITV(32); CONS8(A3, 24, 64);
      WAITV(24); CONS8(B0, 32, 64);
      WAITV(16); CONS8(B1, 40, 64);
      WAITV(8);  CONS8(B2, 48, 64);
      WAITV(0);  CONS8(B3, 56, 64);
      // ---- activations + LLC store + completion ----
      f16* hd = h1buf + (size_t)(s&1)*HBh + (size_t)row0*Hh + col0 + n;
      f32x4 pF = aF0 + aF1, pC = aC0 + aC1;
      #pragma unroll
      for (int j = 0; j < 4; ++j) {
        float f  = sigm(pF[j] + bfv);
        float ct = tanhf_(pC[j] + bcv);
        cst[j] = f*cst[j] + (1.0f - f)*ct;
        union { _Float16 h; unsigned short u; } cv; cv.h = (f16)tanhf_(cst[j]);
        unsigned uu = cv.u;
        asm volatile("global_store_short %0, %1, off sc0 sc1"
                     :: "v"(hd + (size_t)j*Hh), "v"(uu) : "memory");
      }
      asm volatile("s_waitcnt vmcnt(0)" ::: "memory");
      __syncthreads();
      if (tid == 0)
        __hip_atomic_fetch_add(cnt1p + 16*s, 1u, __ATOMIC_RELAXED, __HIP_MEMORY_SCOPE_AGENT);
    }
  }

  // ---- final projection: out = h1(511) @ Wfc + bfc (all 128 WGs) ----
  pollcnts(cnt1p + 16*(Ss-1), nullptr);
  {
    const f16* h1f = h1buf + (size_t)1*HBh;        // 511 & 1 == 1
    const int o = wid*4 + (tid & 3);
    const int b = tid >> 2;
    const f16* hrow = h1f + (size_t)b*Hh;
    float acc = bfc[o];
    for (int blk = 0; blk < 16; ++blk) {
      f16x8 A[8];
      ISSUE8C(A, hrow + blk*64);
      asm volatile("s_waitcnt vmcnt(0)" ::: "memory");
      __builtin_amdgcn_sched_barrier(0);
      #pragma unroll
      for (int i = 0; i < 8; ++i)
        #pragma unroll
        for (int j = 0; j < 8; ++j)
          acc += (float)A[i][j] * Wfc[(size_t)(blk*64 + i*8 + j)*Oo + o];
    }
    out[(size_t)b*Oo + o] = acc;
  }
}

extern "C" void kernel_launch(void* const* d_in, const int* in_sizes, int n_in,
                              void* d_out, int out_size, void* d_ws, size_t ws_size,
                              hipStream_t stream) {
  const float* x   = (const float*)d_in[0];
  const float* Wf0 = (const float*)d_in[1];
  const float* bf0 = (const float*)d_in[2];
  const float* Wc0 = (const float*)d_in[3];
  const float* bc0 = (const float*)d_in[4];
  const float* Wf1 = (const float*)d_in[5];
  const float* bf1 = (const float*)d_in[6];
  const float* Wc1 = (const float*)d_in[7];
  const float* bc1 = (const float*)d_in[8];
  const float* Wfc = (const float*)d_in[9];
  const float* bfc = (const float*)d_in[10];

  init_ws_kernel<<<64, 256, 0, stream>>>((uint4*)d_ws);
  janet_persistent<<<NWG, 256, 0, stream>>>(x, Wf0, bf0, Wc0, bc0,
                                            Wf1, bf1, Wc1, bc1, Wfc, bfc,
                                            (float*)d_out, d_ws);
}

// Round 5
// 5264.926 us; speedup vs baseline: 8.5292x; 1.0053x over previous
//
#include <hip/hip_runtime.h>
#include <stdint.h>

typedef _Float16 f16;
typedef _Float16 f16x8 __attribute__((ext_vector_type(8)));
typedef float    f32x4 __attribute__((ext_vector_type(4)));

#define Bm 64
#define Ss 512
#define Ff 512
#define Hh 1024
#define Oo 512
#define NWG 128          // 64 L0 + 64 L1
#define HBh (Bm*Hh)      // halves per h slot (65536)

// ws layout
#define FL0_U32 0                        // flags0[wg] at u32 index 4*wg (16B stride)
#define FL1_U32 1024                     // flags1[wg] at u32 index 1024+4*wg
#define H0_BYTE  65536                   // 4 slots x 128KB
#define H1_BYTE  (65536 + 4*HBh*2)      // 2 slots x 128KB
#define WS_BYTES (H1_BYTE + 2*HBh*2)    // 851968

#define MFMA16 __builtin_amdgcn_mfma_f32_16x16x32_f16

__device__ __forceinline__ float sigm(float x){ return 1.0f/(1.0f+__expf(-x)); }
__device__ __forceinline__ float tanhf_(float x){
  x = fminf(15.0f, fmaxf(-15.0f, x));
  float e = __expf(-2.0f*x);
  return (1.0f - e)/(1.0f + e);
}

__global__ void init_ws_kernel(uint4* ws){
  const uint4 z = {0,0,0,0};
  int n = WS_BYTES/16;
  for (int i = blockIdx.x*blockDim.x + threadIdx.x; i < n; i += gridDim.x*blockDim.x)
    ws[i] = z;
}

// ---- sync primitives: per-producer epoch flags, no atomics ----
__device__ __forceinline__ void setflag(unsigned* p, unsigned v){
  asm volatile("global_store_dword %0, %1, off sc0 sc1" :: "v"(p), "v"(v) : "memory");
}

__device__ __forceinline__ void pollflags(unsigned* wsu, unsigned tgt0, unsigned tgt1, int tid){
  if (tid < 64) {
    const unsigned* p0 = wsu + FL0_U32 + 4*tid;   // lane l watches producer l
    const unsigned* p1 = wsu + FL1_U32 + 4*tid;
    for (;;) {
      unsigned v0, v1;
      asm volatile("global_load_dword %0, %2, off sc0 sc1\n\t"
                   "global_load_dword %1, %3, off sc0 sc1\n\t"
                   "s_waitcnt vmcnt(0)"
                   : "=&v"(v0), "=&v"(v1) : "v"(p0), "v"(p1) : "memory");
      if (__all((v0 >= tgt0) && (v1 >= tgt1))) break;
    }
  }
  asm volatile("s_waitcnt vmcnt(0)" ::: "memory");  // all waves: ordered before consume
  __builtin_amdgcn_sched_barrier(0);                // rule #18: pin consumers below
  __syncthreads();
}

// issue 8 LLC-coherent 16B loads, 64B apart (A-fragment row stride)
#define ISSUE8(A, P) asm volatile( \
  "global_load_dwordx4 %0, %8, off sc0 sc1\n\t" \
  "global_load_dwordx4 %1, %8, off offset:64 sc0 sc1\n\t" \
  "global_load_dwordx4 %2, %8, off offset:128 sc0 sc1\n\t" \
  "global_load_dwordx4 %3, %8, off offset:192 sc0 sc1\n\t" \
  "global_load_dwordx4 %4, %8, off offset:256 sc0 sc1\n\t" \
  "global_load_dwordx4 %5, %8, off offset:320 sc0 sc1\n\t" \
  "global_load_dwordx4 %6, %8, off offset:384 sc0 sc1\n\t" \
  "global_load_dwordx4 %7, %8, off offset:448 sc0 sc1" \
  : "=&v"(A[0]), "=&v"(A[1]), "=&v"(A[2]), "=&v"(A[3]), \
    "=&v"(A[4]), "=&v"(A[5]), "=&v"(A[6]), "=&v"(A[7]) \
  : "v"(P) : "memory")

// contiguous variant (16B apart) for the projection
#define ISSUE8C(A, P) asm volatile( \
  "global_load_dwordx4 %0, %8, off sc0 sc1\n\t" \
  "global_load_dwordx4 %1, %8, off offset:16 sc0 sc1\n\t" \
  "global_load_dwordx4 %2, %8, off offset:32 sc0 sc1\n\t" \
  "global_load_dwordx4 %3, %8, off offset:48 sc0 sc1\n\t" \
  "global_load_dwordx4 %4, %8, off offset:64 sc0 sc1\n\t" \
  "global_load_dwordx4 %5, %8, off offset:80 sc0 sc1\n\t" \
  "global_load_dwordx4 %6, %8, off offset:96 sc0 sc1\n\t" \
  "global_load_dwordx4 %7, %8, off offset:112 sc0 sc1" \
  : "=&v"(A[0]), "=&v"(A[1]), "=&v"(A[2]), "=&v"(A[3]), \
    "=&v"(A[4]), "=&v"(A[5]), "=&v"(A[6]), "=&v"(A[7]) \
  : "v"(P) : "memory")

// counted wait; block MFMA & VMEM motion across, allow DS_READ/VALU/SALU (0x106)
#define WAITV(N) do{ asm volatile("s_waitcnt vmcnt(" #N ")" ::: "memory"); \
                     __builtin_amdgcn_sched_barrier(0x106); }while(0)

// 8 k-steps of dual-gate MFMA from LDS weights
#define CONS8(Aarr, KSB, KSC) do{ \
  _Pragma("unroll") \
  for (int j = 0; j < 8; ++j){ \
    f16x8 bw = ldsA[(size_t)((KSB)+j)*64]; \
    f16x8 cw = ldsA[(size_t)((KSC)+(KSB)+j)*64]; \
    if (j & 1){ aF1 = MFMA16(Aarr[j], bw, aF1, 0,0,0); aC1 = MFMA16(Aarr[j], cw, aC1, 0,0,0); } \
    else      { aF0 = MFMA16(Aarr[j], bw, aF0, 0,0,0); aC0 = MFMA16(Aarr[j], cw, aC0, 0,0,0); } \
  } \
}while(0)

__device__ __forceinline__ f16x8 cvt8(float4 v0, float4 v1){
  f16x8 a;
  a[0]=v0.x; a[1]=v0.y; a[2]=v0.z; a[3]=v0.w;
  a[4]=v1.x; a[5]=v1.y; a[6]=v1.z; a[7]=v1.w;
  return a;
}

__global__ __launch_bounds__(256,1) void janet_persistent(
    const float* __restrict__ x,
    const float* __restrict__ Wf0, const float* __restrict__ bf0,
    const float* __restrict__ Wc0, const float* __restrict__ bc0,
    const float* __restrict__ Wf1, const float* __restrict__ bf1,
    const float* __restrict__ Wc1, const float* __restrict__ bc1,
    const float* __restrict__ Wfc, const float* __restrict__ bfc,
    float* __restrict__ out, void* __restrict__ ws)
{
  __shared__ __align__(16) unsigned char smem[131072];   // 128 KB -> 1 WG/CU
  unsigned* wsu = (unsigned*)ws;
  f16* h0buf = (f16*)((char*)ws + H0_BYTE);   // 4 slots
  f16* h1buf = (f16*)((char*)ws + H1_BYTE);   // 2 slots

  const int wid  = blockIdx.x;
  const int tid  = threadIdx.x;
  const bool isL0 = (wid < 64);
  const int lw   = isL0 ? wid : wid - 64;
  const int col0 = lw * 16;
  const int K    = isL0 ? (Ff + Hh) : (2*Hh);   // 1536 / 2048
  const int KS   = K >> 5;                      // 48 / 64

  // ---- stage weights into LDS in MFMA B-fragment order [gate][ks][lane] ----
  {
    const float* Wg[2] = { isL0 ? Wf0 : Wf1, isL0 ? Wc0 : Wc1 };
    for (int g = 0; g < 2; ++g) {
      const float* W = Wg[g];
      for (int e = tid; e < 16*K; e += 256) {
        int n = e & 15, k = e >> 4;
        float v = W[(size_t)k*Hh + col0 + n];
        int ks = k >> 5, sub = (k >> 3) & 3, j = k & 7;
        int lane = n + (sub << 4);
        int byte = ((g*KS + ks) << 10) + (lane << 4) + (j << 1);
        *(f16*)(smem + byte) = (f16)v;
      }
    }
  }
  __syncthreads();

  const int lane = tid & 63;
  const int wv   = tid >> 6;
  const int n    = lane & 15;
  const int kg   = lane >> 4;
  const int e8   = kg * 8;
  const int arow = 16*wv + n;      // row this lane LOADS (A-frag)
  const int row0 = 16*wv + kg*4;   // first row this lane OWNS (C/D frag)

  const float* bfp = isL0 ? bf0 : bf1;
  const float* bcp = isL0 ? bc0 : bc1;
  const float bfv = bfp[col0 + n];
  const float bcv = bcp[col0 + n];

  const f16x8* ldsA = (const f16x8*)(smem + (size_t)lane*16);

  f32x4 cst = {0.f,0.f,0.f,0.f};

  if (isL0) {
    for (int t = 0; t < Ss; ++t) {
      f32x4 aF0={0.f,0.f,0.f,0.f}, aF1={0.f,0.f,0.f,0.f};
      f32x4 aC0={0.f,0.f,0.f,0.f}, aC1={0.f,0.f,0.f,0.f};
      // ---- x region first (plain cached loads; overlaps waiting on peers) ----
      const float* xb = x + ((size_t)arow*Ss + (size_t)t)*Ff + e8;
      #pragma unroll 4
      for (int ks = 0; ks < 16; ++ks) {
        float4 v0 = *(const float4*)(xb + 32*ks);
        float4 v1 = *(const float4*)(xb + 32*ks + 4);
        f16x8 a = cvt8(v0, v1);
        f16x8 bw = ldsA[(size_t)ks*64];
        f16x8 cw = ldsA[(size_t)(48 + ks)*64];
        if (ks & 1){ aF1 = MFMA16(a, bw, aF1, 0,0,0); aC1 = MFMA16(a, cw, aC1, 0,0,0); }
        else       { aF0 = MFMA16(a, bw, aF0, 0,0,0); aC0 = MFMA16(a, cw, aC0, 0,0,0); }
      }
      // ---- wait: h0(t-1) complete; L1 done reading h0(t-4) (WAR) ----
      pollflags(wsu, (unsigned)t, t >= 4 ? (unsigned)(t-3) : 0u, tid);
      // ---- h0(t-1) region: LLC-coherent pipelined loads ----
      const f16* h0r = h0buf + (size_t)((t+3)&3)*HBh + (size_t)arow*Hh + e8;
      f16x8 A0[8], A1[8], A2[8], A3[8];
      __builtin_amdgcn_sched_barrier(0);
      ISSUE8(A0, h0r); ISSUE8(A1, h0r+256); ISSUE8(A2, h0r+512); ISSUE8(A3, h0r+768);
      WAITV(24); CONS8(A0, 16, 48);
      WAITV(16); CONS8(A1, 24, 48);
      WAITV(8);  CONS8(A2, 32, 48);
      WAITV(0);  CONS8(A3, 40, 48);
      // ---- activations + LLC store + flag ----
      f16* hd = h0buf + (size_t)(t&3)*HBh + (size_t)row0*Hh + col0 + n;
      f32x4 pF = aF0 + aF1, pC = aC0 + aC1;
      #pragma unroll
      for (int j = 0; j < 4; ++j) {
        float f  = sigm(pF[j] + bfv);
        float ct = tanhf_(pC[j] + bcv);
        cst[j] = f*cst[j] + (1.0f - f)*ct;
        union { _Float16 h; unsigned short u; } cv; cv.h = (f16)tanhf_(cst[j]);
        unsigned uu = cv.u;
        asm volatile("global_store_short %0, %1, off sc0 sc1"
                     :: "v"(hd + (size_t)j*Hh), "v"(uu) : "memory");
      }
      asm volatile("s_waitcnt vmcnt(0)" ::: "memory");
      __syncthreads();
      if (tid == 0) setflag(wsu + FL0_U32 + 4*lw, (unsigned)(t+1));
    }
  } else {
    for (int s = 0; s < Ss; ++s) {
      // need h0(s) complete and own-layer h1(s-1) complete
      pollflags(wsu, (unsigned)(s+1), (unsigned)s, tid);
      f32x4 aF0={0.f,0.f,0.f,0.f}, aF1={0.f,0.f,0.f,0.f};
      f32x4 aC0={0.f,0.f,0.f,0.f}, aC1={0.f,0.f,0.f,0.f};
      const f16* h0c = h0buf + (size_t)(s&3)*HBh     + (size_t)arow*Hh + e8;
      const f16* h1p = h1buf + (size_t)((s+1)&1)*HBh + (size_t)arow*Hh + e8;
      f16x8 A0[8], A1[8], A2[8], A3[8];
      f16x8 B0[8], B1[8], B2[8], B3[8];
      __builtin_amdgcn_sched_barrier(0);
      ISSUE8(A0, h0c); ISSUE8(A1, h0c+256); ISSUE8(A2, h0c+512); ISSUE8(A3, h0c+768);
      WAITV(24); CONS8(A0, 0, 64);
      WAITV(16); CONS8(A1, 8, 64);
      WAITV(8);  CONS8(A2, 16, 64);
      ISSUE8(B0, h1p); ISSUE8(B1, h1p+256); ISSUE8(B2, h1p+512); ISSUE8(B3, h1p+768);
      WAITV(32); CONS8(A3, 24, 64);
      WAITV(24); CONS8(B0, 32, 64);
      WAITV(16); CONS8(B1, 40, 64);
      WAITV(8);  CONS8(B2, 48, 64);
      WAITV(0);  CONS8(B3, 56, 64);
      // ---- activations + LLC store + flag ----
      f16* hd = h1buf + (size_t)(s&1)*HBh + (size_t)row0*Hh + col0 + n;
      f32x4 pF = aF0 + aF1, pC = aC0 + aC1;
      #pragma unroll
      for (int j = 0; j < 4; ++j) {
        float f  = sigm(pF[j] + bfv);
        float ct = tanhf_(pC[j] + bcv);
        cst[j] = f*cst[j] + (1.0f - f)*ct;
        union { _Float16 h; unsigned short u; } cv; cv.h = (f16)tanhf_(cst[j]);
        unsigned uu = cv.u;
        asm volatile("global_store_short %0, %1, off sc0 sc1"
                     :: "v"(hd + (size_t)j*Hh), "v"(uu) : "memory");
      }
      asm volatile("s_waitcnt vmcnt(0)" ::: "memory");
      __syncthreads();
      if (tid == 0) setflag(wsu + FL1_U32 + 4*lw, (unsigned)(s+1));
    }
  }

  // ---- final projection: out = h1(511) @ Wfc + bfc (all 128 WGs) ----
  pollflags(wsu, 0u, (unsigned)Ss, tid);
  {
    const f16* h1f = h1buf + (size_t)1*HBh;        // 511 & 1 == 1
    const int o = wid*4 + (tid & 3);
    const int b = tid >> 2;
    const f16* hrow = h1f + (size_t)b*Hh;
    float acc = bfc[o];
    for (int blk = 0; blk < 16; ++blk) {
      f16x8 A[8];
      ISSUE8C(A, hrow + blk*64);
      asm volatile("s_waitcnt vmcnt(0)" ::: "memory");
      __builtin_amdgcn_sched_barrier(0);
      #pragma unroll
      for (int i = 0; i < 8; ++i)
        #pragma unroll
        for (int j = 0; j < 8; ++j)
          acc += (float)A[i][j] * Wfc[(size_t)(blk*64 + i*8 + j)*Oo + o];
    }
    out[(size_t)b*Oo + o] = acc;
  }
}

extern "C" void kernel_launch(void* const* d_in, const int* in_sizes, int n_in,
                              void* d_out, int out_size, void* d_ws, size_t ws_size,
                              hipStream_t stream) {
  const float* x   = (const float*)d_in[0];
  const float* Wf0 = (const float*)d_in[1];
  const float* bf0 = (const float*)d_in[2];
  const float* Wc0 = (const float*)d_in[3];
  const float* bc0 = (const float*)d_in[4];
  const float* Wf1 = (const float*)d_in[5];
  const float* bf1 = (const float*)d_in[6];
  const float* Wc1 = (const float*)d_in[7];
  const float* bc1 = (const float*)d_in[8];
  const float* Wfc = (const float*)d_in[9];
  const float* bfc = (const float*)d_in[10];

  init_ws_kernel<<<64, 256, 0, stream>>>((uint4*)d_ws);
  janet_persistent<<<NWG, 256, 0, stream>>>(x, Wf0, bf0, Wc0, bc0,
                                            Wf1, bf1, Wc1, bc1, Wfc, bfc,
                                            (float*)d_out, d_ws);
}

// Round 6
// 5155.937 us; speedup vs baseline: 8.7095x; 1.0211x over previous
//
#include <hip/hip_runtime.h>
#include <stdint.h>

typedef _Float16 f16;
typedef _Float16 f16x8 __attribute__((ext_vector_type(8)));
typedef float    f32x4 __attribute__((ext_vector_type(4)));

#define Bm 64
#define Ss 512
#define Ff 512
#define Hh 1024
#define Oo 512
#define NWG 128          // 64 L0 + 64 L1
#define HBh (Bm*Hh)      // halves per h slot (65536)
#define SLOTB (HBh*2)    // 131072 bytes per slot

// ---- shared flag layout (both kernels) ----
#define FL0_U32 0                        // flags0[wg] at u32 index 4*wg (16B stride)
#define FL1_U32 1024                     // flags1[wg] at u32 index 1024+4*wg

// ---- ring (fallback, == proven v5) layout ----
#define RH0_BYTE  65536                  // 4 slots x 128KB
#define RH1_BYTE  (65536 + 4*HBh*2)      // 2 slots x 128KB
#define RWS_BYTES (RH1_BYTE + 2*HBh*2)   // 851968

// ---- fresh (write-once slots) layout ----
#define NSLOT 513                        // slot -1 (zeros) + 512 steps
#define H0F_BYTE ((size_t)65536)
#define H1F_BYTE (H0F_BYTE + (size_t)NSLOT*SLOTB)          // 67305472
#define WSF_NEED (H1F_BYTE + (size_t)NSLOT*SLOTB)          // 134545408

#define MFMA16 __builtin_amdgcn_mfma_f32_16x16x32_f16

__device__ __forceinline__ float sigm(float x){ return 1.0f/(1.0f+__expf(-x)); }
__device__ __forceinline__ float tanhf_(float x){
  x = fminf(15.0f, fmaxf(-15.0f, x));
  float e = __expf(-2.0f*x);
  return (1.0f - e)/(1.0f + e);
}

__global__ void init_ring(uint4* ws){
  const uint4 z = {0,0,0,0};
  int n = RWS_BYTES/16;
  for (int i = blockIdx.x*blockDim.x + threadIdx.x; i < n; i += gridDim.x*blockDim.x)
    ws[i] = z;
}

__global__ void init_fresh(void* ws){
  const uint4 z = {0,0,0,0};
  int idx = blockIdx.x*blockDim.x + threadIdx.x;
  const int total = 512 + 8192 + 8192;   // 8KB flags + 128KB h0 zero-slot + 128KB h1 zero-slot
  for (int i = idx; i < total; i += gridDim.x*blockDim.x) {
    if (i < 512)        ((uint4*)ws)[i] = z;
    else if (i < 8704)  ((uint4*)((char*)ws + H0F_BYTE))[i-512]  = z;
    else                ((uint4*)((char*)ws + H1F_BYTE))[i-8704] = z;
  }
}

// ---- sync primitives: per-producer epoch flags ----
__device__ __forceinline__ void setflag(unsigned* p, unsigned v){
  asm volatile("global_store_dword %0, %1, off sc0 sc1" :: "v"(p), "v"(v) : "memory");
}

__device__ __forceinline__ void pollflags(unsigned* wsu, unsigned tgt0, unsigned tgt1, int tid){
  if (tid < 64) {
    const unsigned* p0 = wsu + FL0_U32 + 4*tid;   // lane l watches producer l
    const unsigned* p1 = wsu + FL1_U32 + 4*tid;
    for (;;) {
      unsigned v0, v1;
      asm volatile("global_load_dword %0, %2, off sc0 sc1\n\t"
                   "global_load_dword %1, %3, off sc0 sc1\n\t"
                   "s_waitcnt vmcnt(0)"
                   : "=&v"(v0), "=&v"(v1) : "v"(p0), "v"(p1) : "memory");
      if (__all((v0 >= tgt0) && (v1 >= tgt1))) break;
    }
  }
  asm volatile("s_waitcnt vmcnt(0)" ::: "memory");
  __builtin_amdgcn_sched_barrier(0);
  __syncthreads();
}

__device__ __forceinline__ void pollf0(unsigned* wsu, unsigned tgt0, int tid){
  if (tid < 64) {
    const unsigned* p0 = wsu + FL0_U32 + 4*tid;
    for (;;) {
      unsigned v0;
      asm volatile("global_load_dword %0, %1, off sc0 sc1\n\t"
                   "s_waitcnt vmcnt(0)"
                   : "=&v"(v0) : "v"(p0) : "memory");
      if (__all(v0 >= tgt0)) break;
    }
  }
  asm volatile("s_waitcnt vmcnt(0)" ::: "memory");
  __builtin_amdgcn_sched_barrier(0);
  __syncthreads();
}

// LLC-coherent 16B loads, 64B apart (A-fragment row stride)
#define ISSUE8(A, P) asm volatile( \
  "global_load_dwordx4 %0, %8, off sc0 sc1\n\t" \
  "global_load_dwordx4 %1, %8, off offset:64 sc0 sc1\n\t" \
  "global_load_dwordx4 %2, %8, off offset:128 sc0 sc1\n\t" \
  "global_load_dwordx4 %3, %8, off offset:192 sc0 sc1\n\t" \
  "global_load_dwordx4 %4, %8, off offset:256 sc0 sc1\n\t" \
  "global_load_dwordx4 %5, %8, off offset:320 sc0 sc1\n\t" \
  "global_load_dwordx4 %6, %8, off offset:384 sc0 sc1\n\t" \
  "global_load_dwordx4 %7, %8, off offset:448 sc0 sc1" \
  : "=&v"(A[0]), "=&v"(A[1]), "=&v"(A[2]), "=&v"(A[3]), \
    "=&v"(A[4]), "=&v"(A[5]), "=&v"(A[6]), "=&v"(A[7]) \
  : "v"(P) : "memory")

// plain cached variant (L2-dedup path, fresh kernel)
#define ISSUE8P(A, P) asm volatile( \
  "global_load_dwordx4 %0, %8, off\n\t" \
  "global_load_dwordx4 %1, %8, off offset:64\n\t" \
  "global_load_dwordx4 %2, %8, off offset:128\n\t" \
  "global_load_dwordx4 %3, %8, off offset:192\n\t" \
  "global_load_dwordx4 %4, %8, off offset:256\n\t" \
  "global_load_dwordx4 %5, %8, off offset:320\n\t" \
  "global_load_dwordx4 %6, %8, off offset:384\n\t" \
  "global_load_dwordx4 %7, %8, off offset:448" \
  : "=&v"(A[0]), "=&v"(A[1]), "=&v"(A[2]), "=&v"(A[3]), \
    "=&v"(A[4]), "=&v"(A[5]), "=&v"(A[6]), "=&v"(A[7]) \
  : "v"(P) : "memory")

// contiguous variants (16B apart) for the projection
#define ISSUE8C(A, P) asm volatile( \
  "global_load_dwordx4 %0, %8, off sc0 sc1\n\t" \
  "global_load_dwordx4 %1, %8, off offset:16 sc0 sc1\n\t" \
  "global_load_dwordx4 %2, %8, off offset:32 sc0 sc1\n\t" \
  "global_load_dwordx4 %3, %8, off offset:48 sc0 sc1\n\t" \
  "global_load_dwordx4 %4, %8, off offset:64 sc0 sc1\n\t" \
  "global_load_dwordx4 %5, %8, off offset:80 sc0 sc1\n\t" \
  "global_load_dwordx4 %6, %8, off offset:96 sc0 sc1\n\t" \
  "global_load_dwordx4 %7, %8, off offset:112 sc0 sc1" \
  : "=&v"(A[0]), "=&v"(A[1]), "=&v"(A[2]), "=&v"(A[3]), \
    "=&v"(A[4]), "=&v"(A[5]), "=&v"(A[6]), "=&v"(A[7]) \
  : "v"(P) : "memory")

#define ISSUE8CP(A, P) asm volatile( \
  "global_load_dwordx4 %0, %8, off\n\t" \
  "global_load_dwordx4 %1, %8, off offset:16\n\t" \
  "global_load_dwordx4 %2, %8, off offset:32\n\t" \
  "global_load_dwordx4 %3, %8, off offset:48\n\t" \
  "global_load_dwordx4 %4, %8, off offset:64\n\t" \
  "global_load_dwordx4 %5, %8, off offset:80\n\t" \
  "global_load_dwordx4 %6, %8, off offset:96\n\t" \
  "global_load_dwordx4 %7, %8, off offset:112" \
  : "=&v"(A[0]), "=&v"(A[1]), "=&v"(A[2]), "=&v"(A[3]), \
    "=&v"(A[4]), "=&v"(A[5]), "=&v"(A[6]), "=&v"(A[7]) \
  : "v"(P) : "memory")

// counted wait; block MFMA & VMEM motion across, allow DS_READ/VALU/SALU (0x106)
#define WAITV(N) do{ asm volatile("s_waitcnt vmcnt(" #N ")" ::: "memory"); \
                     __builtin_amdgcn_sched_barrier(0x106); }while(0)

// 8 k-steps of dual-gate MFMA from LDS weights
#define CONS8(Aarr, KSB, KSC) do{ \
  _Pragma("unroll") \
  for (int j = 0; j < 8; ++j){ \
    f16x8 bw = ldsA[(size_t)((KSB)+j)*64]; \
    f16x8 cw = ldsA[(size_t)((KSC)+(KSB)+j)*64]; \
    if (j & 1){ aF1 = MFMA16(Aarr[j], bw, aF1, 0,0,0); aC1 = MFMA16(Aarr[j], cw, aC1, 0,0,0); } \
    else      { aF0 = MFMA16(Aarr[j], bw, aF0, 0,0,0); aC0 = MFMA16(Aarr[j], cw, aC0, 0,0,0); } \
  } \
}while(0)

__device__ __forceinline__ f16x8 cvt8(float4 v0, float4 v1){
  f16x8 a;
  a[0]=v0.x; a[1]=v0.y; a[2]=v0.z; a[3]=v0.w;
  a[4]=v1.x; a[5]=v1.y; a[6]=v1.z; a[7]=v1.w;
  return a;
}

// common body, parameterized by addressing mode
template<bool FRESH>
__global__ __launch_bounds__(256,1) void janet_kernel(
    const float* __restrict__ x,
    const float* __restrict__ Wf0, const float* __restrict__ bf0,
    const float* __restrict__ Wc0, const float* __restrict__ bc0,
    const float* __restrict__ Wf1, const float* __restrict__ bf1,
    const float* __restrict__ Wc1, const float* __restrict__ bc1,
    const float* __restrict__ Wfc, const float* __restrict__ bfc,
    float* __restrict__ out, void* __restrict__ ws)
{
  __shared__ __align__(16) unsigned char smem[131072];   // 128 KB -> 1 WG/CU
  if (FRESH) {
    // clear any stale L1/L2 lines left by the previous graph replay
    __builtin_amdgcn_fence(__ATOMIC_ACQUIRE, "agent");
  }
  unsigned* wsu = (unsigned*)ws;
  f16* h0buf = (f16*)((char*)ws + (FRESH ? H0F_BYTE : (size_t)RH0_BYTE));
  f16* h1buf = (f16*)((char*)ws + (FRESH ? H1F_BYTE : (size_t)RH1_BYTE));

  const int wid  = blockIdx.x;
  const int tid  = threadIdx.x;
  const bool isL0 = (wid < 64);
  const int lw   = isL0 ? wid : wid - 64;
  const int col0 = lw * 16;
  const int K    = isL0 ? (Ff + Hh) : (2*Hh);   // 1536 / 2048
  const int KS   = K >> 5;                      // 48 / 64

  // ---- stage weights into LDS in MFMA B-fragment order [gate][ks][lane] ----
  {
    const float* Wg[2] = { isL0 ? Wf0 : Wf1, isL0 ? Wc0 : Wc1 };
    for (int g = 0; g < 2; ++g) {
      const float* W = Wg[g];
      for (int e = tid; e < 16*K; e += 256) {
        int n = e & 15, k = e >> 4;
        float v = W[(size_t)k*Hh + col0 + n];
        int ks = k >> 5, sub = (k >> 3) & 3, j = k & 7;
        int lane = n + (sub << 4);
        int byte = ((g*KS + ks) << 10) + (lane << 4) + (j << 1);
        *(f16*)(smem + byte) = (f16)v;
      }
    }
  }
  __syncthreads();

  const int lane = tid & 63;
  const int wv   = tid >> 6;
  const int n    = lane & 15;
  const int kg   = lane >> 4;
  const int e8   = kg * 8;
  const int arow = 16*wv + n;      // row this lane LOADS (A-frag)
  const int row0 = 16*wv + kg*4;   // first row this lane OWNS (C/D frag)

  const float* bfp = isL0 ? bf0 : bf1;
  const float* bcp = isL0 ? bc0 : bc1;
  const float bfv = bfp[col0 + n];
  const float bcv = bcp[col0 + n];

  const f16x8* ldsA = (const f16x8*)(smem + (size_t)lane*16);

  f32x4 cst = {0.f,0.f,0.f,0.f};

  if (isL0) {
    for (int t = 0; t < Ss; ++t) {
      f32x4 aF0={0.f,0.f,0.f,0.f}, aF1={0.f,0.f,0.f,0.f};
      f32x4 aC0={0.f,0.f,0.f,0.f}, aC1={0.f,0.f,0.f,0.f};
      // ---- x region first (plain cached loads; overlaps waiting on peers) ----
      const float* xb = x + ((size_t)arow*Ss + (size_t)t)*Ff + e8;
      #pragma unroll 4
      for (int ks = 0; ks < 16; ++ks) {
        float4 v0 = *(const float4*)(xb + 32*ks);
        float4 v1 = *(const float4*)(xb + 32*ks + 4);
        f16x8 a = cvt8(v0, v1);
        f16x8 bw = ldsA[(size_t)ks*64];
        f16x8 cw = ldsA[(size_t)(48 + ks)*64];
        if (ks & 1){ aF1 = MFMA16(a, bw, aF1, 0,0,0); aC1 = MFMA16(a, cw, aC1, 0,0,0); }
        else       { aF0 = MFMA16(a, bw, aF0, 0,0,0); aC0 = MFMA16(a, cw, aC0, 0,0,0); }
      }
      // ---- wait: h0(t-1) complete (FRESH: no WAR; ring: also L1 read h0(t-4)) ----
      if (FRESH) pollf0(wsu, (unsigned)t, tid);
      else       pollflags(wsu, (unsigned)t, t >= 4 ? (unsigned)(t-3) : 0u, tid);
      // ---- h0(t-1) region ----
      const f16* h0r = FRESH
        ? h0buf + (size_t)t*HBh + (size_t)arow*Hh + e8            // slot t-1
        : h0buf + (size_t)((t+3)&3)*HBh + (size_t)arow*Hh + e8;
      f16x8 A0[8], A1[8], A2[8], A3[8];
      __builtin_amdgcn_sched_barrier(0);
      if (FRESH) { ISSUE8P(A0, h0r); ISSUE8P(A1, h0r+256); ISSUE8P(A2, h0r+512); ISSUE8P(A3, h0r+768); }
      else       { ISSUE8 (A0, h0r); ISSUE8 (A1, h0r+256); ISSUE8 (A2, h0r+512); ISSUE8 (A3, h0r+768); }
      WAITV(24); CONS8(A0, 16, 48);
      WAITV(16); CONS8(A1, 24, 48);
      WAITV(8);  CONS8(A2, 32, 48);
      WAITV(0);  CONS8(A3, 40, 48);
      // ---- activations + write-through store + flag ----
      f16* hd = FRESH
        ? h0buf + (size_t)(t+1)*HBh + (size_t)row0*Hh + col0 + n  // slot t
        : h0buf + (size_t)(t&3)*HBh + (size_t)row0*Hh + col0 + n;
      f32x4 pF = aF0 + aF1, pC = aC0 + aC1;
      #pragma unroll
      for (int j = 0; j < 4; ++j) {
        float f  = sigm(pF[j] + bfv);
        float ct = tanhf_(pC[j] + bcv);
        cst[j] = f*cst[j] + (1.0f - f)*ct;
        union { _Float16 h; unsigned short u; } cv; cv.h = (f16)tanhf_(cst[j]);
        unsigned uu = cv.u;
        asm volatile("global_store_short %0, %1, off sc0 sc1"
                     :: "v"(hd + (size_t)j*Hh), "v"(uu) : "memory");
      }
      asm volatile("s_waitcnt vmcnt(0)" ::: "memory");
      __syncthreads();
      if (tid == 0) setflag(wsu + FL0_U32 + 4*lw, (unsigned)(t+1));
    }
  } else {
    for (int s = 0; s < Ss; ++s) {
      // need h0(s) complete and own-layer h1(s-1) complete
      pollflags(wsu, (unsigned)(s+1), (unsigned)s, tid);
      f32x4 aF0={0.f,0.f,0.f,0.f}, aF1={0.f,0.f,0.f,0.f};
      f32x4 aC0={0.f,0.f,0.f,0.f}, aC1={0.f,0.f,0.f,0.f};
      const f16* h0c = FRESH
        ? h0buf + (size_t)(s+1)*HBh + (size_t)arow*Hh + e8        // slot s
        : h0buf + (size_t)(s&3)*HBh + (size_t)arow*Hh + e8;
      const f16* h1p = FRESH
        ? h1buf + (size_t)s*HBh + (size_t)arow*Hh + e8            // slot s-1
        : h1buf + (size_t)((s+1)&1)*HBh + (size_t)arow*Hh + e8;
      f16x8 A0[8], A1[8], A2[8], A3[8];
      f16x8 B0[8], B1[8], B2[8], B3[8];
      __builtin_amdgcn_sched_barrier(0);
      if (FRESH) { ISSUE8P(A0, h0c); ISSUE8P(A1, h0c+256); ISSUE8P(A2, h0c+512); ISSUE8P(A3, h0c+768); }
      else       { ISSUE8 (A0, h0c); ISSUE8 (A1, h0c+256); ISSUE8 (A2, h0c+512); ISSUE8 (A3, h0c+768); }
      WAITV(24); CONS8(A0, 0, 64);
      WAITV(16); CONS8(A1, 8, 64);
      WAITV(8);  CONS8(A2, 16, 64);
      if (FRESH) { ISSUE8P(B0, h1p); ISSUE8P(B1, h1p+256); ISSUE8P(B2, h1p+512); ISSUE8P(B3, h1p+768); }
      else       { ISSUE8 (B0, h1p); ISSUE8 (B1, h1p+256); ISSUE8 (B2, h1p+512); ISSUE8 (B3, h1p+768); }
      WAITV(32); CONS8(A3, 24, 64);
      WAITV(24); CONS8(B0, 32, 64);
      WAITV(16); CONS8(B1, 40, 64);
      WAITV(8);  CONS8(B2, 48, 64);
      WAITV(0);  CONS8(B3, 56, 64);
      // ---- activations + write-through store + flag ----
      f16* hd = FRESH
        ? h1buf + (size_t)(s+1)*HBh + (size_t)row0*Hh + col0 + n  // slot s
        : h1buf + (size_t)(s&1)*HBh + (size_t)row0*Hh + col0 + n;
      f32x4 pF = aF0 + aF1, pC = aC0 + aC1;
      #pragma unroll
      for (int j = 0; j < 4; ++j) {
        float f  = sigm(pF[j] + bfv);
        float ct = tanhf_(pC[j] + bcv);
        cst[j] = f*cst[j] + (1.0f - f)*ct;
        union { _Float16 h; unsigned short u; } cv; cv.h = (f16)tanhf_(cst[j]);
        unsigned uu = cv.u;
        asm volatile("global_store_short %0, %1, off sc0 sc1"
                     :: "v"(hd + (size_t)j*Hh), "v"(uu) : "memory");
      }
      asm volatile("s_waitcnt vmcnt(0)" ::: "memory");
      __syncthreads();
      if (tid == 0) setflag(wsu + FL1_U32 + 4*lw, (unsigned)(s+1));
    }
  }

  // ---- final projection: out = h1(511) @ Wfc + bfc (all 128 WGs) ----
  pollflags(wsu, 0u, (unsigned)Ss, tid);
  {
    const f16* h1f = FRESH ? h1buf + (size_t)Ss*HBh     // slot 511
                           : h1buf + (size_t)1*HBh;     // ring parity 1
    const int o = wid*4 + (tid & 3);
    const int b = tid >> 2;
    const f16* hrow = h1f + (size_t)b*Hh;
    float acc = bfc[o];
    for (int blk = 0; blk < 16; ++blk) {
      f16x8 A[8];
      if (FRESH) { ISSUE8CP(A, hrow + blk*64); }
      else       { ISSUE8C (A, hrow + blk*64); }
      asm volatile("s_waitcnt vmcnt(0)" ::: "memory");
      __builtin_amdgcn_sched_barrier(0);
      #pragma unroll
      for (int i = 0; i < 8; ++i)
        #pragma unroll
        for (int j = 0; j < 8; ++j)
          acc += (float)A[i][j] * Wfc[(size_t)(blk*64 + i*8 + j)*Oo + o];
    }
    out[(size_t)b*Oo + o] = acc;
  }
}

extern "C" void kernel_launch(void* const* d_in, const int* in_sizes, int n_in,
                              void* d_out, int out_size, void* d_ws, size_t ws_size,
                              hipStream_t stream) {
  const float* x   = (const float*)d_in[0];
  const float* Wf0 = (const float*)d_in[1];
  const float* bf0 = (const float*)d_in[2];
  const float* Wc0 = (const float*)d_in[3];
  const float* bc0 = (const float*)d_in[4];
  const float* Wf1 = (const float*)d_in[5];
  const float* bf1 = (const float*)d_in[6];
  const float* Wc1 = (const float*)d_in[7];
  const float* bc1 = (const float*)d_in[8];
  const float* Wfc = (const float*)d_in[9];
  const float* bfc = (const float*)d_in[10];

  const bool fresh = (ws_size >= (size_t)WSF_NEED);
  if (fresh) {
    init_fresh<<<64, 256, 0, stream>>>(d_ws);
    janet_kernel<true><<<NWG, 256, 0, stream>>>(x, Wf0, bf0, Wc0, bc0,
                                                Wf1, bf1, Wc1, bc1, Wfc, bfc,
                                                (float*)d_out, d_ws);
  } else {
    init_ring<<<64, 256, 0, stream>>>((uint4*)d_ws);
    janet_kernel<false><<<NWG, 256, 0, stream>>>(x, Wf0, bf0, Wc0, bc0,
                                                 Wf1, bf1, Wc1, bc1, Wfc, bfc,
                                                 (float*)d_out, d_ws);
  }
}

// Round 7
// 3803.292 us; speedup vs baseline: 11.8070x; 1.3557x over previous
//
#include <hip/hip_runtime.h>
#include <stdint.h>

typedef _Float16 f16;
typedef _Float16 f16x8 __attribute__((ext_vector_type(8)));
typedef float    f32x4 __attribute__((ext_vector_type(4)));

#define Bm 64
#define Ss 512
#define Ff 512
#define Hh 1024
#define Oo 512
#define NWG 128          // 64 L0 + 64 L1
#define HBh (Bm*Hh)      // halves per h slot (65536)
#define SLOTB (HBh*2)    // 131072 bytes per slot (64 tiles x 2048B)

// ---- flag layout ----
#define FL0_U32 0                        // flags0[wg] at u32 index 4*wg (16B stride)
#define FL1_U32 1024                     // flags1[wg] at u32 index 1024+4*wg

// ---- fresh (write-once slots) layout ----
#define NSLOT 513                        // slot 0 (zeros) + 512 steps
#define H0F_BYTE ((size_t)65536)
#define H1F_BYTE (H0F_BYTE + (size_t)NSLOT*SLOTB)
#define WSF_NEED (H1F_BYTE + (size_t)NSLOT*SLOTB)          // ~134.5 MB (fits: r6 used it)

#define MFMA16 __builtin_amdgcn_mfma_f32_16x16x32_f16

__device__ __forceinline__ float sigm(float x){ return 1.0f/(1.0f+__expf(-x)); }
__device__ __forceinline__ float tanhf_(float x){
  x = fminf(15.0f, fmaxf(-15.0f, x));
  float e = __expf(-2.0f*x);
  return (1.0f - e)/(1.0f + e);
}

__global__ void init_fresh(void* ws){
  const uint4 z = {0,0,0,0};
  int idx = blockIdx.x*blockDim.x + threadIdx.x;
  const int total = 512 + 8192 + 8192;   // 8KB flags + 128KB h0 slot0 + 128KB h1 slot0
  for (int i = idx; i < total; i += gridDim.x*blockDim.x) {
    if (i < 512)        ((uint4*)ws)[i] = z;
    else if (i < 8704)  ((uint4*)((char*)ws + H0F_BYTE))[i-512]  = z;
    else                ((uint4*)((char*)ws + H1F_BYTE))[i-8704] = z;
  }
}

// ---- sync primitives: per-producer epoch flags ----
__device__ __forceinline__ void setflag(unsigned* p, unsigned v){
  asm volatile("global_store_dword %0, %1, off sc0 sc1" :: "v"(p), "v"(v) : "memory");
}

__device__ __forceinline__ void pollflags(unsigned* wsu, unsigned tgt0, unsigned tgt1, int tid){
  if (tid < 64) {
    const unsigned* p0 = wsu + FL0_U32 + 4*tid;   // lane l watches producer l
    const unsigned* p1 = wsu + FL1_U32 + 4*tid;
    for (;;) {
      unsigned v0, v1;
      asm volatile("global_load_dword %0, %2, off sc0 sc1\n\t"
                   "global_load_dword %1, %3, off sc0 sc1\n\t"
                   "s_waitcnt vmcnt(0)"
                   : "=&v"(v0), "=&v"(v1) : "v"(p0), "v"(p1) : "memory");
      if (__all((v0 >= tgt0) && (v1 >= tgt1))) break;
    }
  }
  asm volatile("s_waitcnt vmcnt(0)" ::: "memory");
  __builtin_amdgcn_sched_barrier(0);
  __syncthreads();
}

__device__ __forceinline__ void pollf0(unsigned* wsu, unsigned tgt0, int tid){
  if (tid < 64) {
    const unsigned* p0 = wsu + FL0_U32 + 4*tid;
    for (;;) {
      unsigned v0;
      asm volatile("global_load_dword %0, %1, off sc0 sc1\n\t"
                   "s_waitcnt vmcnt(0)"
                   : "=&v"(v0) : "v"(p0) : "memory");
      if (__all(v0 >= tgt0)) break;
    }
  }
  asm volatile("s_waitcnt vmcnt(0)" ::: "memory");
  __builtin_amdgcn_sched_barrier(0);
  __syncthreads();
}

// tiled-layout batch: 8 plain cached 16B loads; P* = base + 4096 (+8192*k);
// each pointer serves offsets {-4096, 0} -> ks stride 4096B
#define ISSUE8T(A, P0, P1, P2, P3) asm volatile( \
  "global_load_dwordx4 %0, %8, off offset:-4096\n\t" \
  "global_load_dwordx4 %1, %8, off\n\t" \
  "global_load_dwordx4 %2, %9, off offset:-4096\n\t" \
  "global_load_dwordx4 %3, %9, off\n\t" \
  "global_load_dwordx4 %4, %10, off offset:-4096\n\t" \
  "global_load_dwordx4 %5, %10, off\n\t" \
  "global_load_dwordx4 %6, %11, off offset:-4096\n\t" \
  "global_load_dwordx4 %7, %11, off" \
  : "=&v"(A[0]), "=&v"(A[1]), "=&v"(A[2]), "=&v"(A[3]), \
    "=&v"(A[4]), "=&v"(A[5]), "=&v"(A[6]), "=&v"(A[7]) \
  : "v"(P0), "v"(P1), "v"(P2), "v"(P3) : "memory")

// counted wait; block MFMA & VMEM motion across, allow DS_READ/VALU/SALU (0x106)
#define WAITV(N) do{ asm volatile("s_waitcnt vmcnt(" #N ")" ::: "memory"); \
                     __builtin_amdgcn_sched_barrier(0x106); }while(0)

// 8 k-steps of dual-gate MFMA from LDS weights
#define CONS8(Aarr, KSB, KSC) do{ \
  _Pragma("unroll") \
  for (int j = 0; j < 8; ++j){ \
    f16x8 bw = ldsA[(size_t)((KSB)+j)*64]; \
    f16x8 cw = ldsA[(size_t)((KSC)+(KSB)+j)*64]; \
    if (j & 1){ aF1 = MFMA16(Aarr[j], bw, aF1, 0,0,0); aC1 = MFMA16(Aarr[j], cw, aC1, 0,0,0); } \
    else      { aF0 = MFMA16(Aarr[j], bw, aF0, 0,0,0); aC0 = MFMA16(Aarr[j], cw, aC0, 0,0,0); } \
  } \
}while(0)

__device__ __forceinline__ f16x8 cvt8(float4 v0, float4 v1){
  f16x8 a;
  a[0]=v0.x; a[1]=v0.y; a[2]=v0.z; a[3]=v0.w;
  a[4]=v1.x; a[5]=v1.y; a[6]=v1.z; a[7]=v1.w;
  return a;
}

__global__ __launch_bounds__(256,1) void janet_persistent(
    const float* __restrict__ x,
    const float* __restrict__ Wf0, const float* __restrict__ bf0,
    const float* __restrict__ Wc0, const float* __restrict__ bc0,
    const float* __restrict__ Wf1, const float* __restrict__ bf1,
    const float* __restrict__ Wc1, const float* __restrict__ bc1,
    const float* __restrict__ Wfc, const float* __restrict__ bfc,
    float* __restrict__ out, void* __restrict__ ws)
{
  __shared__ __align__(16) unsigned char smem[131072];   // 128 KB -> 1 WG/CU
  // clear stale L1/L2 lines left by the previous graph replay (write-once scheme)
  __builtin_amdgcn_fence(__ATOMIC_ACQUIRE, "agent");

  unsigned* wsu = (unsigned*)ws;
  char* h0base = (char*)ws + H0F_BYTE;
  char* h1base = (char*)ws + H1F_BYTE;

  const int wid  = blockIdx.x;
  const int tid  = threadIdx.x;
  const bool isL0 = (wid < 64);
  const int lw   = isL0 ? wid : wid - 64;
  const int col0 = lw * 16;
  const int K    = isL0 ? (Ff + Hh) : (2*Hh);   // 1536 / 2048
  const int KS   = K >> 5;                      // 48 / 64

  // ---- stage weights into LDS in MFMA B-fragment order [gate][ks][lane] ----
  {
    const float* Wg[2] = { isL0 ? Wf0 : Wf1, isL0 ? Wc0 : Wc1 };
    for (int g = 0; g < 2; ++g) {
      const float* W = Wg[g];
      for (int e = tid; e < 16*K; e += 256) {
        int n = e & 15, k = e >> 4;
        float v = W[(size_t)k*Hh + col0 + n];
        int ks = k >> 5, sub = (k >> 3) & 3, j = k & 7;
        int lane = n + (sub << 4);
        int byte = ((g*KS + ks) << 10) + (lane << 4) + (j << 1);
        *(f16*)(smem + byte) = (f16)v;
      }
    }
  }
  __syncthreads();

  const int lane = tid & 63;
  const int wv   = tid >> 6;
  const int n    = lane & 15;
  const int kg   = lane >> 4;
  const int e8   = kg * 8;
  const int arow = 16*wv + n;      // row this lane LOADS (A-frag)
  const int part = n & 3;          // store: 8B column-quarter
  const int rsel = n >> 2;         // store: which j to gather
  const int srow = 16*wv + 4*kg + rsel;   // store: row this lane writes

  const float* bfp = isL0 ? bf0 : bf1;
  const float* bcp = isL0 ? bc0 : bc1;
  const float bfv = bfp[col0 + n];
  const float bcv = bcp[col0 + n];

  const f16x8* ldsA = (const f16x8*)(smem + (size_t)lane*16);
  // per-lane read offset into a tiled h slot (+4096 for the -4096/0 pair trick)
  const size_t rdoff = (size_t)(kg>>1)*2048 + (size_t)arow*32 + (size_t)(kg&1)*16 + 4096;

  f32x4 cst = {0.f,0.f,0.f,0.f};

  if (isL0) {
    for (int t = 0; t < Ss; ++t) {
      // ---- issue ALL x(t) loads (plain cached); poll's vmcnt(0) drains them ----
      const float* xb = x + ((size_t)arow*Ss + (size_t)t)*Ff + e8;
      float4 xv0[16], xv1[16];
      #pragma unroll
      for (int i = 0; i < 16; ++i) {
        xv0[i] = *(const float4*)(xb + 32*i);
        xv1[i] = *(const float4*)(xb + 32*i + 4);
      }
      // ---- wait: h0(t-1) complete (no WAR: write-once slots) ----
      pollf0(wsu, (unsigned)t, tid);

      f32x4 aF0={0.f,0.f,0.f,0.f}, aF1={0.f,0.f,0.f,0.f};
      f32x4 aC0={0.f,0.f,0.f,0.f}, aC1={0.f,0.f,0.f,0.f};
      // ---- x-region MFMAs from registers (x already drained) ----
      #pragma unroll
      for (int ks = 0; ks < 16; ++ks) {
        f16x8 a  = cvt8(xv0[ks], xv1[ks]);
        f16x8 bw = ldsA[(size_t)ks*64];
        f16x8 cw = ldsA[(size_t)(48 + ks)*64];
        if (ks & 1){ aF1 = MFMA16(a, bw, aF1, 0,0,0); aC1 = MFMA16(a, cw, aC1, 0,0,0); }
        else       { aF0 = MFMA16(a, bw, aF0, 0,0,0); aC0 = MFMA16(a, cw, aC0, 0,0,0); }
      }
      // ---- h0(t-1) region: tiled slot t, pipelined loads ----
      const char* hb = h0base + (size_t)t*SLOTB + rdoff;
      f16x8 A0[8], A1[8], A2[8], A3[8];
      __builtin_amdgcn_sched_barrier(0);
      ISSUE8T(A0, hb,       hb+8192,  hb+16384, hb+24576);
      ISSUE8T(A1, hb+32768, hb+40960, hb+49152, hb+57344);
      ISSUE8T(A2, hb+65536, hb+73728, hb+81920, hb+90112);
      ISSUE8T(A3, hb+98304, hb+106496, hb+114688, hb+122880);
      WAITV(24); CONS8(A0, 16, 48);
      WAITV(16); CONS8(A1, 24, 48);
      WAITV(8);  CONS8(A2, 32, 48);
      WAITV(0);  CONS8(A3, 40, 48);
      // ---- activations + shuffle-transpose + coalesced store + flag ----
      f32x4 pF = aF0 + aF1, pC = aC0 + aC1;
      unsigned cu[4];
      #pragma unroll
      for (int j = 0; j < 4; ++j) {
        float f  = sigm(pF[j] + bfv);
        float ct = tanhf_(pC[j] + bcv);
        cst[j] = f*cst[j] + (1.0f - f)*ct;
        union { _Float16 h; unsigned short u; } cv; cv.h = (f16)tanhf_(cst[j]);
        cu[j] = cv.u;
      }
      {
        unsigned u01 = cu[0] | (cu[1] << 16);
        unsigned u23 = cu[2] | (cu[3] << 16);
        int sb = (kg << 4) + (part << 2);
        unsigned wsel[4];
        #pragma unroll
        for (int i = 0; i < 4; ++i) {
          unsigned w01 = __shfl(u01, sb + i, 64);
          unsigned w23 = __shfl(u23, sb + i, 64);
          unsigned w = (rsel < 2) ? w01 : w23;
          wsel[i] = (rsel & 1) ? (w >> 16) : (w & 0xffffu);
        }
        unsigned d0 = wsel[0] | (wsel[1] << 16);
        unsigned d1 = wsel[2] | (wsel[3] << 16);
        uint64_t dd = (uint64_t)d0 | ((uint64_t)d1 << 32);
        char* hd = h0base + (size_t)(t+1)*SLOTB + (size_t)lw*2048 + (size_t)srow*32 + (size_t)part*8;
        asm volatile("global_store_dwordx2 %0, %1, off sc0 sc1" :: "v"(hd), "v"(dd) : "memory");
      }
      asm volatile("s_waitcnt vmcnt(0)" ::: "memory");
      __syncthreads();
      if (tid == 0) setflag(wsu + FL0_U32 + 4*lw, (unsigned)(t+1));
    }
  } else {
    for (int s = 0; s < Ss; ++s) {
      // need h0(s) complete and own-layer h1(s-1) complete
      pollflags(wsu, (unsigned)(s+1), (unsigned)s, tid);
      f32x4 aF0={0.f,0.f,0.f,0.f}, aF1={0.f,0.f,0.f,0.f};
      f32x4 aC0={0.f,0.f,0.f,0.f}, aC1={0.f,0.f,0.f,0.f};
      const char* hbA = h0base + (size_t)(s+1)*SLOTB + rdoff;   // h0(s)
      const char* hbB = h1base + (size_t)s*SLOTB + rdoff;       // h1(s-1)
      f16x8 A0[8], A1[8], A2[8], A3[8];
      f16x8 B0[8], B1[8], B2[8], B3[8];
      __builtin_amdgcn_sched_barrier(0);
      ISSUE8T(A0, hbA,       hbA+8192,  hbA+16384, hbA+24576);
      ISSUE8T(A1, hbA+32768, hbA+40960, hbA+49152, hbA+57344);
      ISSUE8T(A2, hbA+65536, hbA+73728, hbA+81920, hbA+90112);
      ISSUE8T(A3, hbA+98304, hbA+106496, hbA+114688, hbA+122880);
      WAITV(24); CONS8(A0, 0, 64);
      WAITV(16); CONS8(A1, 8, 64);
      WAITV(8);  CONS8(A2, 16, 64);
      ISSUE8T(B0, hbB,       hbB+8192,  hbB+16384, hbB+24576);
      ISSUE8T(B1, hbB+32768, hbB+40960, hbB+49152, hbB+57344);
      ISSUE8T(B2, hbB+65536, hbB+73728, hbB+81920, hbB+90112);
      ISSUE8T(B3, hbB+98304, hbB+106496, hbB+114688, hbB+122880);
      WAITV(32); CONS8(A3, 24, 64);
      WAITV(24); CONS8(B0, 32, 64);
      WAITV(16); CONS8(B1, 40, 64);
      WAITV(8);  CONS8(B2, 48, 64);
      WAITV(0);  CONS8(B3, 56, 64);
      // ---- activations + shuffle-transpose + coalesced store + flag ----
      f32x4 pF = aF0 + aF1, pC = aC0 + aC1;
      unsigned cu[4];
      #pragma unroll
      for (int j = 0; j < 4; ++j) {
        float f  = sigm(pF[j] + bfv);
        float ct = tanhf_(pC[j] + bcv);
        cst[j] = f*cst[j] + (1.0f - f)*ct;
        union { _Float16 h; unsigned short u; } cv; cv.h = (f16)tanhf_(cst[j]);
        cu[j] = cv.u;
      }
      {
        unsigned u01 = cu[0] | (cu[1] << 16);
        unsigned u23 = cu[2] | (cu[3] << 16);
        int sb = (kg << 4) + (part << 2);
        unsigned wsel[4];
        #pragma unroll
        for (int i = 0; i < 4; ++i) {
          unsigned w01 = __shfl(u01, sb + i, 64);
          unsigned w23 = __shfl(u23, sb + i, 64);
          unsigned w = (rsel < 2) ? w01 : w23;
          wsel[i] = (rsel & 1) ? (w >> 16) : (w & 0xffffu);
        }
        unsigned d0 = wsel[0] | (wsel[1] << 16);
        unsigned d1 = wsel[2] | (wsel[3] << 16);
        uint64_t dd = (uint64_t)d0 | ((uint64_t)d1 << 32);
        char* hd = h1base + (size_t)(s+1)*SLOTB + (size_t)lw*2048 + (size_t)srow*32 + (size_t)part*8;
        asm volatile("global_store_dwordx2 %0, %1, off sc0 sc1" :: "v"(hd), "v"(dd) : "memory");
      }
      asm volatile("s_waitcnt vmcnt(0)" ::: "memory");
      __syncthreads();
      if (tid == 0) setflag(wsu + FL1_U32 + 4*lw, (unsigned)(s+1));
    }
  }

  // ---- final projection: out = h1(511) @ Wfc + bfc (all 128 WGs) ----
  pollflags(wsu, 0u, (unsigned)Ss, tid);
  {
    const char* fin = h1base + (size_t)Ss*SLOTB;   // slot 512 = h1(511)
    const int o = wid*4 + (tid & 3);
    const int b = tid >> 2;
    const char* rowp = fin + (size_t)b*32;
    float acc = bfc[o];
    for (int tile = 0; tile < 64; ++tile) {
      const f16x8* tp = (const f16x8*)(rowp + (size_t)tile*2048);
      f16x8 lo = tp[0];
      f16x8 hi = tp[1];
      #pragma unroll
      for (int i = 0; i < 8; ++i) {
        acc += (float)lo[i] * Wfc[(size_t)(tile*16 + i)*Oo + o];
        acc += (float)hi[i] * Wfc[(size_t)(tile*16 + 8 + i)*Oo + o];
      }
    }
    out[(size_t)b*Oo + o] = acc;
  }
}

extern "C" void kernel_launch(void* const* d_in, const int* in_sizes, int n_in,
                              void* d_out, int out_size, void* d_ws, size_t ws_size,
                              hipStream_t stream) {
  const float* x   = (const float*)d_in[0];
  const float* Wf0 = (const float*)d_in[1];
  const float* bf0 = (const float*)d_in[2];
  const float* Wc0 = (const float*)d_in[3];
  const float* bc0 = (const float*)d_in[4];
  const float* Wf1 = (const float*)d_in[5];
  const float* bf1 = (const float*)d_in[6];
  const float* Wc1 = (const float*)d_in[7];
  const float* bc1 = (const float*)d_in[8];
  const float* Wfc = (const float*)d_in[9];
  const float* bfc = (const float*)d_in[10];

  init_fresh<<<64, 256, 0, stream>>>(d_ws);
  janet_persistent<<<NWG, 256, 0, stream>>>(x, Wf0, bf0, Wc0, bc0,
                                            Wf1, bf1, Wc1, bc1, Wfc, bfc,
                                            (float*)d_out, d_ws);
}

// Round 8
// 3716.169 us; speedup vs baseline: 12.0838x; 1.0234x over previous
//
#include <hip/hip_runtime.h>
#include <stdint.h>

typedef _Float16 f16;
typedef _Float16 f16x8 __attribute__((ext_vector_type(8)));
typedef float    f32x4 __attribute__((ext_vector_type(4)));

#define Bm 64
#define Ss 512
#define Ff 512
#define Hh 1024
#define Oo 512
#define NWG 128          // 64 L0 + 64 L1
#define HBh (Bm*Hh)      // halves per h slot (65536)
#define SLOTB (HBh*2)    // 131072 bytes per slot (64 tiles x 2048B)

// ---- flag layout: 64B stride to cut LLC line contention ----
#define FL0_U32 0                        // flags0[wg] at u32 index 16*wg
#define FL1_U32 1024                     // flags1[wg] at byte 4096 + 64*wg

// ---- fresh (write-once slots) layout ----
#define NSLOT 513                        // slot 0 (zeros) + 512 steps
#define H0F_BYTE ((size_t)65536)
#define H1F_BYTE (H0F_BYTE + (size_t)NSLOT*SLOTB)
#define WSF_NEED (H1F_BYTE + (size_t)NSLOT*SLOTB)          // ~134.5 MB

#define MFMA16 __builtin_amdgcn_mfma_f32_16x16x32_f16

__device__ __forceinline__ float sigm(float x){ return 1.0f/(1.0f+__expf(-x)); }
__device__ __forceinline__ float tanhf_(float x){
  x = fminf(15.0f, fmaxf(-15.0f, x));
  float e = __expf(-2.0f*x);
  return (1.0f - e)/(1.0f + e);
}

__global__ void init_fresh(void* ws){
  const uint4 z = {0,0,0,0};
  int idx = blockIdx.x*blockDim.x + threadIdx.x;
  const int total = 512 + 8192 + 8192;   // 8KB flags + 128KB h0 slot0 + 128KB h1 slot0
  for (int i = idx; i < total; i += gridDim.x*blockDim.x) {
    if (i < 512)        ((uint4*)ws)[i] = z;
    else if (i < 8704)  ((uint4*)((char*)ws + H0F_BYTE))[i-512]  = z;
    else                ((uint4*)((char*)ws + H1F_BYTE))[i-8704] = z;
  }
}

// ---- sync primitives: far-atomic stores (perform+allocate at LLC) ----
__device__ __forceinline__ void setflag(unsigned* p, unsigned v){
  asm volatile("global_atomic_swap %0, %1, off" :: "v"(p), "v"(v) : "memory");
}

__device__ __forceinline__ void pollflags(unsigned* wsu, unsigned tgt0, unsigned tgt1, int tid){
  if (tid < 64) {
    const unsigned* p0 = wsu + FL0_U32 + 16*tid;   // lane l watches producer l
    const unsigned* p1 = wsu + FL1_U32 + 16*tid;
    for (;;) {
      unsigned v0, v1;
      asm volatile("global_load_dword %0, %2, off sc0 sc1\n\t"
                   "global_load_dword %1, %3, off sc0 sc1\n\t"
                   "s_waitcnt vmcnt(0)"
                   : "=&v"(v0), "=&v"(v1) : "v"(p0), "v"(p1) : "memory");
      if (__all((v0 >= tgt0) && (v1 >= tgt1))) break;
    }
  }
  asm volatile("s_waitcnt vmcnt(0)" ::: "memory");
  __builtin_amdgcn_sched_barrier(0);
  __syncthreads();
}

__device__ __forceinline__ void pollf0(unsigned* wsu, unsigned tgt0, int tid){
  if (tid < 64) {
    const unsigned* p0 = wsu + FL0_U32 + 16*tid;
    for (;;) {
      unsigned v0;
      asm volatile("global_load_dword %0, %1, off sc0 sc1\n\t"
                   "s_waitcnt vmcnt(0)"
                   : "=&v"(v0) : "v"(p0) : "memory");
      if (__all(v0 >= tgt0)) break;
    }
  }
  asm volatile("s_waitcnt vmcnt(0)" ::: "memory");
  __builtin_amdgcn_sched_barrier(0);
  __syncthreads();
}

// tiled-layout batch: 8 plain cached 16B loads; P* = base + 4096 (+8192*k);
// each pointer serves offsets {-4096, 0} -> ks stride 4096B
#define ISSUE8T(A, P0, P1, P2, P3) asm volatile( \
  "global_load_dwordx4 %0, %8, off offset:-4096\n\t" \
  "global_load_dwordx4 %1, %8, off\n\t" \
  "global_load_dwordx4 %2, %9, off offset:-4096\n\t" \
  "global_load_dwordx4 %3, %9, off\n\t" \
  "global_load_dwordx4 %4, %10, off offset:-4096\n\t" \
  "global_load_dwordx4 %5, %10, off\n\t" \
  "global_load_dwordx4 %6, %11, off offset:-4096\n\t" \
  "global_load_dwordx4 %7, %11, off" \
  : "=&v"(A[0]), "=&v"(A[1]), "=&v"(A[2]), "=&v"(A[3]), \
    "=&v"(A[4]), "=&v"(A[5]), "=&v"(A[6]), "=&v"(A[7]) \
  : "v"(P0), "v"(P1), "v"(P2), "v"(P3) : "memory")

// counted wait; block MFMA & VMEM motion across, allow DS_READ/VALU/SALU (0x106)
#define WAITV(N) do{ asm volatile("s_waitcnt vmcnt(" #N ")" ::: "memory"); \
                     __builtin_amdgcn_sched_barrier(0x106); }while(0)

// 8 k-steps of dual-gate MFMA from LDS weights
#define CONS8(Aarr, KSB, KSC) do{ \
  _Pragma("unroll") \
  for (int j = 0; j < 8; ++j){ \
    f16x8 bw = ldsA[(size_t)((KSB)+j)*64]; \
    f16x8 cw = ldsA[(size_t)((KSC)+(KSB)+j)*64]; \
    if (j & 1){ aF1 = MFMA16(Aarr[j], bw, aF1, 0,0,0); aC1 = MFMA16(Aarr[j], cw, aC1, 0,0,0); } \
    else      { aF0 = MFMA16(Aarr[j], bw, aF0, 0,0,0); aC0 = MFMA16(Aarr[j], cw, aC0, 0,0,0); } \
  } \
}while(0)

__device__ __forceinline__ f16x8 cvt8(float4 v0, float4 v1){
  f16x8 a;
  a[0]=v0.x; a[1]=v0.y; a[2]=v0.z; a[3]=v0.w;
  a[4]=v1.x; a[5]=v1.y; a[6]=v1.z; a[7]=v1.w;
  return a;
}

__global__ __launch_bounds__(256,1) void janet_persistent(
    const float* __restrict__ x,
    const float* __restrict__ Wf0, const float* __restrict__ bf0,
    const float* __restrict__ Wc0, const float* __restrict__ bc0,
    const float* __restrict__ Wf1, const float* __restrict__ bf1,
    const float* __restrict__ Wc1, const float* __restrict__ bc1,
    const float* __restrict__ Wfc, const float* __restrict__ bfc,
    float* __restrict__ out, void* __restrict__ ws)
{
  __shared__ __align__(16) unsigned char smem[131072];   // 128 KB -> 1 WG/CU
  // clear stale L1/L2 lines left by the previous graph replay (write-once scheme)
  __builtin_amdgcn_fence(__ATOMIC_ACQUIRE, "agent");

  unsigned* wsu = (unsigned*)ws;
  char* h0base = (char*)ws + H0F_BYTE;
  char* h1base = (char*)ws + H1F_BYTE;

  const int wid  = blockIdx.x;
  const int tid  = threadIdx.x;
  const bool isL0 = (wid < 64);
  const int lw   = isL0 ? wid : wid - 64;
  const int col0 = lw * 16;
  const int K    = isL0 ? (Ff + Hh) : (2*Hh);   // 1536 / 2048
  const int KS   = K >> 5;                      // 48 / 64

  // ---- stage weights into LDS in MFMA B-fragment order [gate][ks][lane] ----
  {
    const float* Wg[2] = { isL0 ? Wf0 : Wf1, isL0 ? Wc0 : Wc1 };
    for (int g = 0; g < 2; ++g) {
      const float* W = Wg[g];
      for (int e = tid; e < 16*K; e += 256) {
        int n = e & 15, k = e >> 4;
        float v = W[(size_t)k*Hh + col0 + n];
        int ks = k >> 5, sub = (k >> 3) & 3, j = k & 7;
        int lane = n + (sub << 4);
        int byte = ((g*KS + ks) << 10) + (lane << 4) + (j << 1);
        *(f16*)(smem + byte) = (f16)v;
      }
    }
  }
  __syncthreads();

  const int lane = tid & 63;
  const int wv   = tid >> 6;
  const int n    = lane & 15;
  const int kg   = lane >> 4;
  const int e8   = kg * 8;
  const int arow = 16*wv + n;      // row this lane LOADS (A-frag)
  const int part = n & 3;          // store: 8B column-quarter
  const int rsel = n >> 2;         // store: which j to gather
  const int srow = 16*wv + 4*kg + rsel;   // store: row this lane writes

  const float* bfp = isL0 ? bf0 : bf1;
  const float* bcp = isL0 ? bc0 : bc1;
  const float bfv = bfp[col0 + n];
  const float bcv = bcp[col0 + n];

  const f16x8* ldsA = (const f16x8*)(smem + (size_t)lane*16);
  // per-lane read offset into a tiled h slot (+4096 for the -4096/0 pair trick)
  const size_t rdoff = (size_t)(kg>>1)*2048 + (size_t)arow*32 + (size_t)(kg&1)*16 + 4096;

  f32x4 cst = {0.f,0.f,0.f,0.f};

  if (isL0) {
    for (int t = 0; t < Ss; ++t) {
      // ---- issue ALL x(t) loads (plain cached); poll's vmcnt(0) drains them ----
      const float* xb = x + ((size_t)arow*Ss + (size_t)t)*Ff + e8;
      float4 xv0[16], xv1[16];
      #pragma unroll
      for (int i = 0; i < 16; ++i) {
        xv0[i] = *(const float4*)(xb + 32*i);
        xv1[i] = *(const float4*)(xb + 32*i + 4);
      }
      // ---- wait: h0(t-1) complete (no WAR: write-once slots) ----
      pollf0(wsu, (unsigned)t, tid);

      f32x4 aF0={0.f,0.f,0.f,0.f}, aF1={0.f,0.f,0.f,0.f};
      f32x4 aC0={0.f,0.f,0.f,0.f}, aC1={0.f,0.f,0.f,0.f};
      // ---- x-region MFMAs from registers (x already drained) ----
      #pragma unroll
      for (int ks = 0; ks < 16; ++ks) {
        f16x8 a  = cvt8(xv0[ks], xv1[ks]);
        f16x8 bw = ldsA[(size_t)ks*64];
        f16x8 cw = ldsA[(size_t)(48 + ks)*64];
        if (ks & 1){ aF1 = MFMA16(a, bw, aF1, 0,0,0); aC1 = MFMA16(a, cw, aC1, 0,0,0); }
        else       { aF0 = MFMA16(a, bw, aF0, 0,0,0); aC0 = MFMA16(a, cw, aC0, 0,0,0); }
      }
      // ---- h0(t-1) region: tiled slot t, pipelined loads ----
      const char* hb = h0base + (size_t)t*SLOTB + rdoff;
      f16x8 A0[8], A1[8], A2[8], A3[8];
      __builtin_amdgcn_sched_barrier(0);
      ISSUE8T(A0, hb,       hb+8192,  hb+16384, hb+24576);
      ISSUE8T(A1, hb+32768, hb+40960, hb+49152, hb+57344);
      ISSUE8T(A2, hb+65536, hb+73728, hb+81920, hb+90112);
      ISSUE8T(A3, hb+98304, hb+106496, hb+114688, hb+122880);
      WAITV(24); CONS8(A0, 16, 48);
      WAITV(16); CONS8(A1, 24, 48);
      WAITV(8);  CONS8(A2, 32, 48);
      WAITV(0);  CONS8(A3, 40, 48);
      // ---- activations + shuffle-transpose + far-atomic store + flag ----
      f32x4 pF = aF0 + aF1, pC = aC0 + aC1;
      unsigned cu[4];
      #pragma unroll
      for (int j = 0; j < 4; ++j) {
        float f  = sigm(pF[j] + bfv);
        float ct = tanhf_(pC[j] + bcv);
        cst[j] = f*cst[j] + (1.0f - f)*ct;
        union { _Float16 h; unsigned short u; } cv; cv.h = (f16)tanhf_(cst[j]);
        cu[j] = cv.u;
      }
      {
        unsigned u01 = cu[0] | (cu[1] << 16);
        unsigned u23 = cu[2] | (cu[3] << 16);
        int sb = (kg << 4) + (part << 2);
        unsigned wsel[4];
        #pragma unroll
        for (int i = 0; i < 4; ++i) {
          unsigned w01 = __shfl(u01, sb + i, 64);
          unsigned w23 = __shfl(u23, sb + i, 64);
          unsigned w = (rsel < 2) ? w01 : w23;
          wsel[i] = (rsel & 1) ? (w >> 16) : (w & 0xffffu);
        }
        unsigned d0 = wsel[0] | (wsel[1] << 16);
        unsigned d1 = wsel[2] | (wsel[3] << 16);
        uint64_t dd = (uint64_t)d0 | ((uint64_t)d1 << 32);
        char* hd = h0base + (size_t)(t+1)*SLOTB + (size_t)lw*2048 + (size_t)srow*32 + (size_t)part*8;
        asm volatile("global_atomic_swap_x2 %0, %1, off" :: "v"(hd), "v"(dd) : "memory");
      }
      asm volatile("s_waitcnt vmcnt(0)" ::: "memory");
      __syncthreads();
      if (tid == 0) setflag(wsu + FL0_U32 + 16*lw, (unsigned)(t+1));
    }
  } else {
    for (int s = 0; s < Ss; ++s) {
      // need h0(s) complete and own-layer h1(s-1) complete
      pollflags(wsu, (unsigned)(s+1), (unsigned)s, tid);
      f32x4 aF0={0.f,0.f,0.f,0.f}, aF1={0.f,0.f,0.f,0.f};
      f32x4 aC0={0.f,0.f,0.f,0.f}, aC1={0.f,0.f,0.f,0.f};
      const char* hbA = h0base + (size_t)(s+1)*SLOTB + rdoff;   // h0(s)
      const char* hbB = h1base + (size_t)s*SLOTB + rdoff;       // h1(s-1)
      f16x8 A0[8], A1[8], A2[8], A3[8];
      f16x8 B0[8], B1[8], B2[8], B3[8];
      __builtin_amdgcn_sched_barrier(0);
      ISSUE8T(A0, hbA,       hbA+8192,  hbA+16384, hbA+24576);
      ISSUE8T(A1, hbA+32768, hbA+40960, hbA+49152, hbA+57344);
      ISSUE8T(A2, hbA+65536, hbA+73728, hbA+81920, hbA+90112);
      ISSUE8T(A3, hbA+98304, hbA+106496, hbA+114688, hbA+122880);
      WAITV(24); CONS8(A0, 0, 64);
      WAITV(16); CONS8(A1, 8, 64);
      WAITV(8);  CONS8(A2, 16, 64);
      ISSUE8T(B0, hbB,       hbB+8192,  hbB+16384, hbB+24576);
      ISSUE8T(B1, hbB+32768, hbB+40960, hbB+49152, hbB+57344);
      ISSUE8T(B2, hbB+65536, hbB+73728, hbB+81920, hbB+90112);
      ISSUE8T(B3, hbB+98304, hbB+106496, hbB+114688, hbB+122880);
      WAITV(32); CONS8(A3, 24, 64);
      WAITV(24); CONS8(B0, 32, 64);
      WAITV(16); CONS8(B1, 40, 64);
      WAITV(8);  CONS8(B2, 48, 64);
      WAITV(0);  CONS8(B3, 56, 64);
      // ---- activations + shuffle-transpose + far-atomic store + flag ----
      f32x4 pF = aF0 + aF1, pC = aC0 + aC1;
      unsigned cu[4];
      #pragma unroll
      for (int j = 0; j < 4; ++j) {
        float f  = sigm(pF[j] + bfv);
        float ct = tanhf_(pC[j] + bcv);
        cst[j] = f*cst[j] + (1.0f - f)*ct;
        union { _Float16 h; unsigned short u; } cv; cv.h = (f16)tanhf_(cst[j]);
        cu[j] = cv.u;
      }
      {
        unsigned u01 = cu[0] | (cu[1] << 16);
        unsigned u23 = cu[2] | (cu[3] << 16);
        int sb = (kg << 4) + (part << 2);
        unsigned wsel[4];
        #pragma unroll
        for (int i = 0; i < 4; ++i) {
          unsigned w01 = __shfl(u01, sb + i, 64);
          unsigned w23 = __shfl(u23, sb + i, 64);
          unsigned w = (rsel < 2) ? w01 : w23;
          wsel[i] = (rsel & 1) ? (w >> 16) : (w & 0xffffu);
        }
        unsigned d0 = wsel[0] | (wsel[1] << 16);
        unsigned d1 = wsel[2] | (wsel[3] << 16);
        uint64_t dd = (uint64_t)d0 | ((uint64_t)d1 << 32);
        char* hd = h1base + (size_t)(s+1)*SLOTB + (size_t)lw*2048 + (size_t)srow*32 + (size_t)part*8;
        asm volatile("global_atomic_swap_x2 %0, %1, off" :: "v"(hd), "v"(dd) : "memory");
      }
      asm volatile("s_waitcnt vmcnt(0)" ::: "memory");
      __syncthreads();
      if (tid == 0) setflag(wsu + FL1_U32 + 16*lw, (unsigned)(s+1));
    }
  }

  // ---- final projection: out = h1(511) @ Wfc + bfc (all 128 WGs) ----
  pollflags(wsu, 0u, (unsigned)Ss, tid);
  {
    const char* fin = h1base + (size_t)Ss*SLOTB;   // slot 512 = h1(511)
    const int o = wid*4 + (tid & 3);
    const int b = tid >> 2;
    const char* rowp = fin + (size_t)b*32;
    float acc = bfc[o];
    for (int tile = 0; tile < 64; ++tile) {
      const f16x8* tp = (const f16x8*)(rowp + (size_t)tile*2048);
      f16x8 lo = tp[0];
      f16x8 hi = tp[1];
      #pragma unroll
      for (int i = 0; i < 8; ++i) {
        acc += (float)lo[i] * Wfc[(size_t)(tile*16 + i)*Oo + o];
        acc += (float)hi[i] * Wfc[(size_t)(tile*16 + 8 + i)*Oo + o];
      }
    }
    out[(size_t)b*Oo + o] = acc;
  }
}

extern "C" void kernel_launch(void* const* d_in, const int* in_sizes, int n_in,
                              void* d_out, int out_size, void* d_ws, size_t ws_size,
                              hipStream_t stream) {
  const float* x   = (const float*)d_in[0];
  const float* Wf0 = (const float*)d_in[1];
  const float* bf0 = (const float*)d_in[2];
  const float* Wc0 = (const float*)d_in[3];
  const float* bc0 = (const float*)d_in[4];
  const float* Wf1 = (const float*)d_in[5];
  const float* bf1 = (const float*)d_in[6];
  const float* Wc1 = (const float*)d_in[7];
  const float* bc1 = (const float*)d_in[8];
  const float* Wfc = (const float*)d_in[9];
  const float* bfc = (const float*)d_in[10];

  init_fresh<<<64, 256, 0, stream>>>(d_ws);
  janet_persistent<<<NWG, 256, 0, stream>>>(x, Wf0, bf0, Wc0, bc0,
                                            Wf1, bf1, Wc1, bc1, Wfc, bfc,
                                            (float*)d_out, d_ws);
}

// Round 9
// 3583.417 us; speedup vs baseline: 12.5315x; 1.0370x over previous
//
#include <hip/hip_runtime.h>
#include <stdint.h>

typedef _Float16 f16;
typedef _Float16 f16x8 __attribute__((ext_vector_type(8)));
typedef float    f32x4 __attribute__((ext_vector_type(4)));

#define Bm 64
#define Ss 512
#define Ff 512
#define Hh 1024
#define Oo 512
#define NWG 256          // {L0,L1} x {half0,half1} x 64 col-groups
#define HBh (Bm*Hh)      // halves per h slot (65536)
#define SLOTB (HBh*2)    // 131072 B per slot: 64 cg x (2 half x 32 row x 16 col x 2B)

// ---- flag layout: flags[layer][half][cg], 64B stride ----
#define FL0_U32 0                        // byte 0:      flags0[half*64+cg]*16 u32
#define FL1_U32 4096                     // byte 16384:  flags1[...]
// ---- fresh (write-once slots) layout ----
#define NSLOT 513
#define H0F_BYTE ((size_t)65536)
#define H1F_BYTE (H0F_BYTE + (size_t)NSLOT*SLOTB)
#define WSF_NEED (H1F_BYTE + (size_t)NSLOT*SLOTB)          // ~134.5 MB (fits, r6-r8)

#define MFMA16 __builtin_amdgcn_mfma_f32_16x16x32_f16

__device__ __forceinline__ float sigm(float x){ return 1.0f/(1.0f+__expf(-x)); }
__device__ __forceinline__ float tanhf_(float x){
  x = fminf(15.0f, fmaxf(-15.0f, x));
  float e = __expf(-2.0f*x);
  return (1.0f - e)/(1.0f + e);
}

__global__ void init_fresh(void* ws){
  const uint4 z = {0,0,0,0};
  int idx = blockIdx.x*blockDim.x + threadIdx.x;
  const int total = 2048 + 8192 + 8192;   // 32KB flag region + h0 slot0 + h1 slot0
  for (int i = idx; i < total; i += gridDim.x*blockDim.x) {
    if (i < 2048)        ((uint4*)ws)[i] = z;
    else if (i < 10240)  ((uint4*)((char*)ws + H0F_BYTE))[i-2048]  = z;
    else                 ((uint4*)((char*)ws + H1F_BYTE))[i-10240] = z;
  }
}

// ---- sync primitives ----
__device__ __forceinline__ void setflag(unsigned* p, unsigned v){
  asm volatile("global_atomic_swap %0, %1, off" :: "v"(p), "v"(v) : "memory");
}

// poll one flag set (base u32 index fb) for >= tgt
__device__ __forceinline__ void poll1(unsigned* wsu, int fb, unsigned tgt, int tid){
  if (tid < 64) {
    const unsigned* p0 = wsu + fb + 16*tid;
    for (;;) {
      unsigned v0;
      asm volatile("global_load_dword %0, %1, off sc0 sc1\n\t"
                   "s_waitcnt vmcnt(0)"
                   : "=&v"(v0) : "v"(p0) : "memory");
      if (__all(v0 >= tgt)) break;
    }
  }
  asm volatile("s_waitcnt vmcnt(0)" ::: "memory");
  __builtin_amdgcn_sched_barrier(0);
  __syncthreads();
}

// poll two flag sets
__device__ __forceinline__ void poll2(unsigned* wsu, int fb0, unsigned tgt0,
                                      int fb1, unsigned tgt1, int tid){
  if (tid < 64) {
    const unsigned* p0 = wsu + fb0 + 16*tid;
    const unsigned* p1 = wsu + fb1 + 16*tid;
    for (;;) {
      unsigned v0, v1;
      asm volatile("global_load_dword %0, %2, off sc0 sc1\n\t"
                   "global_load_dword %1, %3, off sc0 sc1\n\t"
                   "s_waitcnt vmcnt(0)"
                   : "=&v"(v0), "=&v"(v1) : "v"(p0), "v"(p1) : "memory");
      if (__all((v0 >= tgt0) && (v1 >= tgt1))) break;
    }
  }
  asm volatile("s_waitcnt vmcnt(0)" ::: "memory");
  __builtin_amdgcn_sched_barrier(0);
  __syncthreads();
}

// tiled-layout batch: 8 plain cached 16B loads; pointers pre-offset +4096;
// each pointer serves ks pair via offsets {-4096, 0}; ks stride 4096B
#define ISSUE8T(A, P0, P1, P2, P3) asm volatile( \
  "global_load_dwordx4 %0, %8, off offset:-4096\n\t" \
  "global_load_dwordx4 %1, %8, off\n\t" \
  "global_load_dwordx4 %2, %9, off offset:-4096\n\t" \
  "global_load_dwordx4 %3, %9, off\n\t" \
  "global_load_dwordx4 %4, %10, off offset:-4096\n\t" \
  "global_load_dwordx4 %5, %10, off\n\t" \
  "global_load_dwordx4 %6, %11, off offset:-4096\n\t" \
  "global_load_dwordx4 %7, %11, off" \
  : "=&v"(A[0]), "=&v"(A[1]), "=&v"(A[2]), "=&v"(A[3]), \
    "=&v"(A[4]), "=&v"(A[5]), "=&v"(A[6]), "=&v"(A[7]) \
  : "v"(P0), "v"(P1), "v"(P2), "v"(P3) : "memory")

#define WAITV(N) do{ asm volatile("s_waitcnt vmcnt(" #N ")" ::: "memory"); \
                     __builtin_amdgcn_sched_barrier(0x106); }while(0)

// 8 k-steps of SINGLE-gate MFMA (gate baked into gofs)
#define CONS8S(Aarr, KSB) do{ \
  _Pragma("unroll") \
  for (int j = 0; j < 8; ++j){ \
    f16x8 bw = ldsA[(size_t)(gofs + (KSB) + j)*64]; \
    if (j & 1) aG1 = MFMA16(Aarr[j], bw, aG1, 0,0,0); \
    else       aG0 = MFMA16(Aarr[j], bw, aG0, 0,0,0); \
  } \
}while(0)

__device__ __forceinline__ f16x8 cvt8(float4 v0, float4 v1){
  f16x8 a;
  a[0]=v0.x; a[1]=v0.y; a[2]=v0.z; a[3]=v0.w;
  a[4]=v1.x; a[5]=v1.y; a[6]=v1.z; a[7]=v1.w;
  return a;
}

__global__ __launch_bounds__(256,1) void janet_persistent(
    const float* __restrict__ x,
    const float* __restrict__ Wf0, const float* __restrict__ bf0,
    const float* __restrict__ Wc0, const float* __restrict__ bc0,
    const float* __restrict__ Wf1, const float* __restrict__ bf1,
    const float* __restrict__ Wc1, const float* __restrict__ bc1,
    const float* __restrict__ Wfc, const float* __restrict__ bfc,
    float* __restrict__ out, void* __restrict__ ws)
{
  __shared__ __align__(16) unsigned char smem[133120];   // 128KB weights + 2KB scratch
  __builtin_amdgcn_fence(__ATOMIC_ACQUIRE, "agent");     // clear stale lines from prev replay

  unsigned* wsu = (unsigned*)ws;
  char* h0base = (char*)ws + H0F_BYTE;
  char* h1base = (char*)ws + H1F_BYTE;

  const int wid  = blockIdx.x;
  const int tid  = threadIdx.x;
  const bool isL0 = (wid < 128);
  const int half = (wid >> 6) & 1;
  const int lw   = wid & 63;           // col-group
  const int col0 = lw * 16;
  const int K    = isL0 ? (Ff + Hh) : (2*Hh);   // 1536 / 2048
  const int KS   = K >> 5;                      // 48 / 64

  // ---- stage weights into LDS in MFMA B-fragment order [gate][ks][lane] ----
  {
    const float* Wg[2] = { isL0 ? Wf0 : Wf1, isL0 ? Wc0 : Wc1 };
    for (int g = 0; g < 2; ++g) {
      const float* W = Wg[g];
      for (int e = tid; e < 16*K; e += 256) {
        int n = e & 15, k = e >> 4;
        float v = W[(size_t)k*Hh + col0 + n];
        int ks = k >> 5, sub = (k >> 3) & 3, j = k & 7;
        int lane = n + (sub << 4);
        int byte = ((g*KS + ks) << 10) + (lane << 4) + (j << 1);
        *(f16*)(smem + byte) = (f16)v;
      }
    }
  }
  __syncthreads();

  const int lane = tid & 63;
  const int wv   = tid >> 6;
  const int rt   = wv & 1;         // row-tile (16 rows) within the 32-row half
  const int g    = wv >> 1;        // gate: 0=F, 1=C
  const int gofs = g * KS;
  const int n    = lane & 15;
  const int kg   = lane >> 4;
  const int e8   = kg * 8;
  const int lrow = rt*16 + n;      // local row this lane LOADS (A-frag), 0..31
  const int grow = half*32 + lrow; // global batch row (x addressing)
  const int part = n & 3;          // store: 8B column-quarter
  const int rsel = n >> 2;         // store: which j to gather
  const int srowl = rt*16 + 4*kg + rsel;   // local row this lane writes

  const float* bfp = isL0 ? bf0 : bf1;
  const float* bcp = isL0 ? bc0 : bc1;
  const float bfv = bfp[col0 + n];
  const float bcv = bcp[col0 + n];

  const f16x8* ldsA = (const f16x8*)(smem + (size_t)lane*16);
  // per-lane read offset into a tiled h slot: cg=2*ks+(kg>>1) blocks of 2048B,
  // + half sub-tile, + local row, + 8-col half; +4096 for the -4096/0 pair trick
  const size_t rdoff = (size_t)(kg>>1)*2048 + (size_t)half*1024
                     + (size_t)lrow*32 + (size_t)(kg&1)*16 + 4096;

  const int fl0 = FL0_U32 + (half*64)*16;   // my half's flags0 base (u32 idx)
  const int fl1 = FL1_U32 + (half*64)*16;

  f32x4 cst = {0.f,0.f,0.f,0.f};

  if (isL0) {
    for (int t = 0; t < Ss; ++t) {
      // ---- issue ALL x(t) loads (plain cached); poll's vmcnt(0) drains them ----
      const float* xb = x + ((size_t)grow*Ss + (size_t)t)*Ff + e8;
      float4 xv0[16], xv1[16];
      #pragma unroll
      for (int i = 0; i < 16; ++i) {
        xv0[i] = *(const float4*)(xb + 32*i);
        xv1[i] = *(const float4*)(xb + 32*i + 4);
      }
      // ---- wait: h0(t-1) complete for my half ----
      poll1(wsu, fl0, (unsigned)t, tid);

      f32x4 aG0={0.f,0.f,0.f,0.f}, aG1={0.f,0.f,0.f,0.f};
      // ---- x-region MFMAs from registers ----
      #pragma unroll
      for (int ks = 0; ks < 16; ++ks) {
        f16x8 a  = cvt8(xv0[ks], xv1[ks]);
        f16x8 bw = ldsA[(size_t)(gofs + ks)*64];
        if (ks & 1) aG1 = MFMA16(a, bw, aG1, 0,0,0);
        else        aG0 = MFMA16(a, bw, aG0, 0,0,0);
      }
      // ---- h0(t-1) region: tiled slot t, pipelined loads ----
      const char* hb = h0base + (size_t)t*SLOTB + rdoff;
      f16x8 A0[8], A1[8], A2[8], A3[8];
      __builtin_amdgcn_sched_barrier(0);
      ISSUE8T(A0, hb,       hb+8192,  hb+16384, hb+24576);
      ISSUE8T(A1, hb+32768, hb+40960, hb+49152, hb+57344);
      ISSUE8T(A2, hb+65536, hb+73728, hb+81920, hb+90112);
      ISSUE8T(A3, hb+98304, hb+106496, hb+114688, hb+122880);
      WAITV(24); CONS8S(A0, 16);
      WAITV(16); CONS8S(A1, 24);
      WAITV(8);  CONS8S(A2, 32);
      WAITV(0);  CONS8S(A3, 40);
      // ---- gate exchange: C-wave -> LDS -> F-wave ----
      f32x4 p = aG0 + aG1;
      if (g == 1) *(f32x4*)(smem + 131072 + rt*1024 + lane*16) = p;
      __syncthreads();
      if (g == 0) {
        f32x4 pC = *(const f32x4*)(smem + 131072 + rt*1024 + lane*16);
        unsigned cu[4];
        #pragma unroll
        for (int j = 0; j < 4; ++j) {
          float f  = sigm(p[j] + bfv);
          float ct = tanhf_(pC[j] + bcv);
          cst[j] = f*cst[j] + (1.0f - f)*ct;
          union { _Float16 h; unsigned short u; } cv; cv.h = (f16)tanhf_(cst[j]);
          cu[j] = cv.u;
        }
        unsigned u01 = cu[0] | (cu[1] << 16);
        unsigned u23 = cu[2] | (cu[3] << 16);
        int sb = (kg << 4) + (part << 2);
        unsigned wsel[4];
        #pragma unroll
        for (int i = 0; i < 4; ++i) {
          unsigned w01 = __shfl(u01, sb + i, 64);
          unsigned w23 = __shfl(u23, sb + i, 64);
          unsigned w = (rsel < 2) ? w01 : w23;
          wsel[i] = (rsel & 1) ? (w >> 16) : (w & 0xffffu);
        }
        unsigned d0 = wsel[0] | (wsel[1] << 16);
        unsigned d1 = wsel[2] | (wsel[3] << 16);
        uint64_t dd = (uint64_t)d0 | ((uint64_t)d1 << 32);
        char* hd = h0base + (size_t)(t+1)*SLOTB + (size_t)lw*2048
                 + (size_t)half*1024 + (size_t)srowl*32 + (size_t)part*8;
        asm volatile("global_atomic_swap_x2 %0, %1, off" :: "v"(hd), "v"(dd) : "memory");
      }
      asm volatile("s_waitcnt vmcnt(0)" ::: "memory");
      __syncthreads();
      if (tid == 0) setflag(wsu + FL0_U32 + (half*64 + lw)*16, (unsigned)(t+1));
    }
  } else {
    for (int s = 0; s < Ss; ++s) {
      // need h0(s) (my half) and own-layer h1(s-1) (my half)
      poll2(wsu, fl0, (unsigned)(s+1), fl1, (unsigned)s, tid);
      f32x4 aG0={0.f,0.f,0.f,0.f}, aG1={0.f,0.f,0.f,0.f};
      const char* hbA = h0base + (size_t)(s+1)*SLOTB + rdoff;   // h0(s)
      const char* hbB = h1base + (size_t)s*SLOTB + rdoff;       // h1(s-1)
      f16x8 A0[8], A1[8], A2[8], A3[8];
      f16x8 B0[8], B1[8], B2[8], B3[8];
      __builtin_amdgcn_sched_barrier(0);
      ISSUE8T(A0, hbA,       hbA+8192,  hbA+16384, hbA+24576);
      ISSUE8T(A1, hbA+32768, hbA+40960, hbA+49152, hbA+57344);
      ISSUE8T(A2, hbA+65536, hbA+73728, hbA+81920, hbA+90112);
      ISSUE8T(A3, hbA+98304, hbA+106496, hbA+114688, hbA+122880);
      WAITV(24); CONS8S(A0, 0);
      WAITV(16); CONS8S(A1, 8);
      WAITV(8);  CONS8S(A2, 16);
      ISSUE8T(B0, hbB,       hbB+8192,  hbB+16384, hbB+24576);
      ISSUE8T(B1, hbB+32768, hbB+40960, hbB+49152, hbB+57344);
      ISSUE8T(B2, hbB+65536, hbB+73728, hbB+81920, hbB+90112);
      ISSUE8T(B3, hbB+98304, hbB+106496, hbB+114688, hbB+122880);
      WAITV(32); CONS8S(A3, 24);
      WAITV(24); CONS8S(B0, 32);
      WAITV(16); CONS8S(B1, 40);
      WAITV(8);  CONS8S(B2, 48);
      WAITV(0);  CONS8S(B3, 56);
      // ---- gate exchange: C-wave -> LDS -> F-wave ----
      f32x4 p = aG0 + aG1;
      if (g == 1) *(f32x4*)(smem + 131072 + rt*1024 + lane*16) = p;
      __syncthreads();
      if (g == 0) {
        f32x4 pC = *(const f32x4*)(smem + 131072 + rt*1024 + lane*16);
        unsigned cu[4];
        #pragma unroll
        for (int j = 0; j < 4; ++j) {
          float f  = sigm(p[j] + bfv);
          float ct = tanhf_(pC[j] + bcv);
          cst[j] = f*cst[j] + (1.0f - f)*ct;
          union { _Float16 h; unsigned short u; } cv; cv.h = (f16)tanhf_(cst[j]);
          cu[j] = cv.u;
        }
        unsigned u01 = cu[0] | (cu[1] << 16);
        unsigned u23 = cu[2] | (cu[3] << 16);
        int sb = (kg << 4) + (part << 2);
        unsigned wsel[4];
        #pragma unroll
        for (int i = 0; i < 4; ++i) {
          unsigned w01 = __shfl(u01, sb + i, 64);
          unsigned w23 = __shfl(u23, sb + i, 64);
          unsigned w = (rsel < 2) ? w01 : w23;
          wsel[i] = (rsel & 1) ? (w >> 16) : (w & 0xffffu);
        }
        unsigned d0 = wsel[0] | (wsel[1] << 16);
        unsigned d1 = wsel[2] | (wsel[3] << 16);
        uint64_t dd = (uint64_t)d0 | ((uint64_t)d1 << 32);
        char* hd = h1base + (size_t)(s+1)*SLOTB + (size_t)lw*2048
                 + (size_t)half*1024 + (size_t)srowl*32 + (size_t)part*8;
        asm volatile("global_atomic_swap_x2 %0, %1, off" :: "v"(hd), "v"(dd) : "memory");
      }
      asm volatile("s_waitcnt vmcnt(0)" ::: "memory");
      __syncthreads();
      if (tid == 0) setflag(wsu + FL1_U32 + (half*64 + lw)*16, (unsigned)(s+1));
    }
  }

  // ---- final projection: out = h1(511) @ Wfc + bfc ----
  // need BOTH halves of flags1 at 512
  poll2(wsu, FL1_U32, (unsigned)Ss, FL1_U32 + 64*16, (unsigned)Ss, tid);
  if (tid < 128) {
    const char* fin = h1base + (size_t)Ss*SLOTB;   // slot 512 = h1(511)
    const int o = wid*2 + (tid & 1);
    const int b = tid >> 1;
    const char* rowp = fin + (size_t)(b>>5)*1024 + (size_t)(b&31)*32;
    float acc = bfc[o];
    for (int cg = 0; cg < 64; ++cg) {
      f16x8 lo = *(const f16x8*)(rowp + (size_t)cg*2048);
      f16x8 hi = *(const f16x8*)(rowp + (size_t)cg*2048 + 16);
      #pragma unroll
      for (int i = 0; i < 8; ++i) {
        acc += (float)lo[i] * Wfc[(size_t)(cg*16 + i)*Oo + o];
        acc += (float)hi[i] * Wfc[(size_t)(cg*16 + 8 + i)*Oo + o];
      }
    }
    out[(size_t)b*Oo + o] = acc;
  }
}

extern "C" void kernel_launch(void* const* d_in, const int* in_sizes, int n_in,
                              void* d_out, int out_size, void* d_ws, size_t ws_size,
                              hipStream_t stream) {
  const float* x   = (const float*)d_in[0];
  const float* Wf0 = (const float*)d_in[1];
  const float* bf0 = (const float*)d_in[2];
  const float* Wc0 = (const float*)d_in[3];
  const float* bc0 = (const float*)d_in[4];
  const float* Wf1 = (const float*)d_in[5];
  const float* bf1 = (const float*)d_in[6];
  const float* Wc1 = (const float*)d_in[7];
  const float* bc1 = (const float*)d_in[8];
  const float* Wfc = (const float*)d_in[9];
  const float* bfc = (const float*)d_in[10];

  init_fresh<<<64, 256, 0, stream>>>(d_ws);
  janet_persistent<<<NWG, 256, 0, stream>>>(x, Wf0, bf0, Wc0, bc0,
                                            Wf1, bf1, Wc1, bc1, Wfc, bfc,
                                            (float*)d_out, d_ws);
}

// Round 10
// 3540.980 us; speedup vs baseline: 12.6816x; 1.0120x over previous
//
#include <hip/hip_runtime.h>
#include <stdint.h>

typedef _Float16 f16;
typedef _Float16 f16x8 __attribute__((ext_vector_type(8)));
typedef float    f32x4 __attribute__((ext_vector_type(4)));

#define Bm 64
#define Ss 512
#define Ff 512
#define Hh 1024
#define Oo 512
#define NWG 256          // {L0,L1} x {half0,half1} x 64 col-groups
#define HBh (Bm*Hh)
#define SLOTB (HBh*2)    // 131072 B per slot: 64 cg x (2 half x 32 row x 16 col x 2B)

// ---- flag layout: flags[layer][half][cg], 64B stride ----
#define FL0_U32 0                        // flags0[half*64+cg] at u32 16*idx
#define FL1_U32 4096                     // flags1[...] at byte 16384
// ---- ring layout: 8 slots per layer; slot k&7 holds h(k); slot 7 = h(-1)=0 ----
#define NSLOT 8
#define H0F_BYTE ((size_t)65536)
#define H1F_BYTE (H0F_BYTE + (size_t)NSLOT*SLOTB)
#define WSF_NEED (H1F_BYTE + (size_t)NSLOT*SLOTB)          // ~2.2 MB

#define MFMA16 __builtin_amdgcn_mfma_f32_16x16x32_f16

__device__ __forceinline__ float sigm(float x){ return 1.0f/(1.0f+__expf(-x)); }
__device__ __forceinline__ float tanhf_(float x){
  x = fminf(15.0f, fmaxf(-15.0f, x));
  float e = __expf(-2.0f*x);
  return (1.0f - e)/(1.0f + e);
}

__global__ void init_fresh(void* ws){
  const uint4 z = {0,0,0,0};
  int idx = blockIdx.x*blockDim.x + threadIdx.x;
  const int total = 4096 + 8192 + 8192;   // 64KB flag region + h0 slot7 + h1 slot7
  for (int i = idx; i < total; i += gridDim.x*blockDim.x) {
    if (i < 4096)        ((uint4*)ws)[i] = z;
    else if (i < 12288)  ((uint4*)((char*)ws + H0F_BYTE + (size_t)7*SLOTB))[i-4096]  = z;
    else                 ((uint4*)((char*)ws + H1F_BYTE + (size_t)7*SLOTB))[i-12288] = z;
  }
}

// ---- sync primitives ----
__device__ __forceinline__ void setflag(unsigned* p, unsigned v){
  asm volatile("global_atomic_swap %0, %1, off" :: "v"(p), "v"(v) : "memory");
}

// poll one flag set with backoff
__device__ __forceinline__ void poll1(unsigned* wsu, int fb, unsigned tgt, int tid){
  if (tid < 64) {
    const unsigned* p0 = wsu + fb + 16*tid;
    for (;;) {
      unsigned v0;
      asm volatile("global_load_dword %0, %1, off sc0 sc1\n\t"
                   "s_waitcnt vmcnt(0)"
                   : "=&v"(v0) : "v"(p0) : "memory");
      if (__all(v0 >= tgt)) break;
      __builtin_amdgcn_s_sleep(1);
    }
  }
  asm volatile("s_waitcnt vmcnt(0)" ::: "memory");
  __builtin_amdgcn_sched_barrier(0);
  __syncthreads();
}

// poll two flag sets with backoff
__device__ __forceinline__ void poll2(unsigned* wsu, int fb0, unsigned tgt0,
                                      int fb1, unsigned tgt1, int tid){
  if (tid < 64) {
    const unsigned* p0 = wsu + fb0 + 16*tid;
    const unsigned* p1 = wsu + fb1 + 16*tid;
    for (;;) {
      unsigned v0, v1;
      asm volatile("global_load_dword %0, %2, off sc0 sc1\n\t"
                   "global_load_dword %1, %3, off sc0 sc1\n\t"
                   "s_waitcnt vmcnt(0)"
                   : "=&v"(v0), "=&v"(v1) : "v"(p0), "v"(p1) : "memory");
      if (__all((v0 >= tgt0) && (v1 >= tgt1))) break;
      __builtin_amdgcn_s_sleep(1);
    }
  }
  asm volatile("s_waitcnt vmcnt(0)" ::: "memory");
  __builtin_amdgcn_sched_barrier(0);
  __syncthreads();
}

// ring-slot batch: 8 LLC-direct (sc0 sc1) 16B loads; pointers pre-offset +4096;
// each pointer serves a ks pair via offsets {-4096, 0}
#define ISSUE8T(A, P0, P1, P2, P3) asm volatile( \
  "global_load_dwordx4 %0, %8, off offset:-4096 sc0 sc1\n\t" \
  "global_load_dwordx4 %1, %8, off sc0 sc1\n\t" \
  "global_load_dwordx4 %2, %9, off offset:-4096 sc0 sc1\n\t" \
  "global_load_dwordx4 %3, %9, off sc0 sc1\n\t" \
  "global_load_dwordx4 %4, %10, off offset:-4096 sc0 sc1\n\t" \
  "global_load_dwordx4 %5, %10, off sc0 sc1\n\t" \
  "global_load_dwordx4 %6, %11, off offset:-4096 sc0 sc1\n\t" \
  "global_load_dwordx4 %7, %11, off sc0 sc1" \
  : "=&v"(A[0]), "=&v"(A[1]), "=&v"(A[2]), "=&v"(A[3]), \
    "=&v"(A[4]), "=&v"(A[5]), "=&v"(A[6]), "=&v"(A[7]) \
  : "v"(P0), "v"(P1), "v"(P2), "v"(P3) : "memory")

#define WAITV(N) do{ asm volatile("s_waitcnt vmcnt(" #N ")" ::: "memory"); \
                     __builtin_amdgcn_sched_barrier(0x106); }while(0)

// 8 k-steps of SINGLE-gate MFMA (gate baked into gofs)
#define CONS8S(Aarr, KSB) do{ \
  _Pragma("unroll") \
  for (int j = 0; j < 8; ++j){ \
    f16x8 bw = ldsA[(size_t)(gofs + (KSB) + j)*64]; \
    if (j & 1) aG1 = MFMA16(Aarr[j], bw, aG1, 0,0,0); \
    else       aG0 = MFMA16(Aarr[j], bw, aG0, 0,0,0); \
  } \
}while(0)

__device__ __forceinline__ f16x8 cvt8(float4 v0, float4 v1){
  f16x8 a;
  a[0]=v0.x; a[1]=v0.y; a[2]=v0.z; a[3]=v0.w;
  a[4]=v1.x; a[5]=v1.y; a[6]=v1.z; a[7]=v1.w;
  return a;
}

__global__ __launch_bounds__(256,1) void janet_persistent(
    const float* __restrict__ x,
    const float* __restrict__ Wf0, const float* __restrict__ bf0,
    const float* __restrict__ Wc0, const float* __restrict__ bc0,
    const float* __restrict__ Wf1, const float* __restrict__ bf1,
    const float* __restrict__ Wc1, const float* __restrict__ bc1,
    const float* __restrict__ Wfc, const float* __restrict__ bfc,
    float* __restrict__ out, void* __restrict__ ws)
{
  __shared__ __align__(16) unsigned char smem[133120];   // 128KB weights + 2KB scratch
  __builtin_amdgcn_fence(__ATOMIC_ACQUIRE, "agent");

  unsigned* wsu = (unsigned*)ws;
  char* h0base = (char*)ws + H0F_BYTE;
  char* h1base = (char*)ws + H1F_BYTE;

  const int wid  = blockIdx.x;
  const int tid  = threadIdx.x;
  const bool isL0 = (wid < 128);
  const int half = (wid >> 6) & 1;
  const int lw   = wid & 63;           // col-group
  const int col0 = lw * 16;
  const int K    = isL0 ? (Ff + Hh) : (2*Hh);   // 1536 / 2048
  const int KS   = K >> 5;                      // 48 / 64

  // ---- stage weights into LDS in MFMA B-fragment order [gate][ks][lane] ----
  {
    const float* Wg[2] = { isL0 ? Wf0 : Wf1, isL0 ? Wc0 : Wc1 };
    for (int g = 0; g < 2; ++g) {
      const float* W = Wg[g];
      for (int e = tid; e < 16*K; e += 256) {
        int n = e & 15, k = e >> 4;
        float v = W[(size_t)k*Hh + col0 + n];
        int ks = k >> 5, sub = (k >> 3) & 3, j = k & 7;
        int lane = n + (sub << 4);
        int byte = ((g*KS + ks) << 10) + (lane << 4) + (j << 1);
        *(f16*)(smem + byte) = (f16)v;
      }
    }
  }
  __syncthreads();

  const int lane = tid & 63;
  const int wv   = tid >> 6;
  const int rt   = wv & 1;         // row-tile within the 32-row half
  const int g    = wv >> 1;        // gate: 0=F, 1=C
  const int gofs = g * KS;
  const int n    = lane & 15;
  const int kg   = lane >> 4;
  const int e8   = kg * 8;
  const int lrow = rt*16 + n;      // local row this lane LOADS (A-frag)
  const int grow = half*32 + lrow; // global batch row (x addressing)
  const int part = n & 3;
  const int rsel = n >> 2;
  const int srowl = rt*16 + 4*kg + rsel;

  const float* bfp = isL0 ? bf0 : bf1;
  const float* bcp = isL0 ? bc0 : bc1;
  const float bfv = bfp[col0 + n];
  const float bcv = bcp[col0 + n];

  const f16x8* ldsA = (const f16x8*)(smem + (size_t)lane*16);
  const size_t rdoff = (size_t)(kg>>1)*2048 + (size_t)half*1024
                     + (size_t)lrow*32 + (size_t)(kg&1)*16 + 4096;

  const int fl0 = FL0_U32 + (half*64)*16;
  const int fl1 = FL1_U32 + (half*64)*16;

  f32x4 cst = {0.f,0.f,0.f,0.f};

  if (isL0) {
    for (int t = 0; t < Ss; ++t) {
      // ---- x(t) loads + x-MFMAs fully BEFORE the poll (off critical path) ----
      const float* xb = x + ((size_t)grow*Ss + (size_t)t)*Ff + e8;
      float4 xv0[16], xv1[16];
      #pragma unroll
      for (int i = 0; i < 16; ++i) {
        xv0[i] = *(const float4*)(xb + 32*i);
        xv1[i] = *(const float4*)(xb + 32*i + 4);
      }
      f32x4 aG0={0.f,0.f,0.f,0.f}, aG1={0.f,0.f,0.f,0.f};
      #pragma unroll
      for (int ks = 0; ks < 16; ++ks) {
        f16x8 a  = cvt8(xv0[ks], xv1[ks]);
        f16x8 bw = ldsA[(size_t)(gofs + ks)*64];
        if (ks & 1) aG1 = MFMA16(a, bw, aG1, 0,0,0);
        else        aG0 = MFMA16(a, bw, aG0, 0,0,0);
      }
      // ---- wait: h0(t-1) done (fl0>=t); ring WAR: L1 done reading h0(t-8) ----
      poll2(wsu, fl0, (unsigned)t, fl1, t >= 8 ? (unsigned)(t-7) : 0u, tid);
      // ---- h0(t-1) region: ring slot (t-1)&7, LLC-direct pipelined loads ----
      const char* hb = h0base + (size_t)((t+7)&7)*SLOTB + rdoff;
      f16x8 A0[8], A1[8], A2[8], A3[8];
      __builtin_amdgcn_sched_barrier(0);
      ISSUE8T(A0, hb,       hb+8192,  hb+16384, hb+24576);
      ISSUE8T(A1, hb+32768, hb+40960, hb+49152, hb+57344);
      ISSUE8T(A2, hb+65536, hb+73728, hb+81920, hb+90112);
      ISSUE8T(A3, hb+98304, hb+106496, hb+114688, hb+122880);
      WAITV(24); CONS8S(A0, 16);
      WAITV(16); CONS8S(A1, 24);
      WAITV(8);  CONS8S(A2, 32);
      WAITV(0);  CONS8S(A3, 40);
      // ---- gate exchange: C-wave -> LDS -> F-wave ----
      f32x4 p = aG0 + aG1;
      if (g == 1) *(f32x4*)(smem + 131072 + rt*1024 + lane*16) = p;
      __syncthreads();
      if (g == 0) {
        f32x4 pC = *(const f32x4*)(smem + 131072 + rt*1024 + lane*16);
        unsigned cu[4];
        #pragma unroll
        for (int j = 0; j < 4; ++j) {
          float f  = sigm(p[j] + bfv);
          float ct = tanhf_(pC[j] + bcv);
          cst[j] = f*cst[j] + (1.0f - f)*ct;
          union { _Float16 h; unsigned short u; } cv; cv.h = (f16)tanhf_(cst[j]);
          cu[j] = cv.u;
        }
        unsigned u01 = cu[0] | (cu[1] << 16);
        unsigned u23 = cu[2] | (cu[3] << 16);
        int sb = (kg << 4) + (part << 2);
        unsigned wsel[4];
        #pragma unroll
        for (int i = 0; i < 4; ++i) {
          unsigned w01 = __shfl(u01, sb + i, 64);
          unsigned w23 = __shfl(u23, sb + i, 64);
          unsigned w = (rsel < 2) ? w01 : w23;
          wsel[i] = (rsel & 1) ? (w >> 16) : (w & 0xffffu);
        }
        unsigned d0 = wsel[0] | (wsel[1] << 16);
        unsigned d1 = wsel[2] | (wsel[3] << 16);
        uint64_t dd = (uint64_t)d0 | ((uint64_t)d1 << 32);
        char* hd = h0base + (size_t)(t&7)*SLOTB + (size_t)lw*2048
                 + (size_t)half*1024 + (size_t)srowl*32 + (size_t)part*8;
        asm volatile("global_atomic_swap_x2 %0, %1, off" :: "v"(hd), "v"(dd) : "memory");
      }
      asm volatile("s_waitcnt vmcnt(0)" ::: "memory");
      __syncthreads();
      if (tid == 0) setflag(wsu + FL0_U32 + (half*64 + lw)*16, (unsigned)(t+1));
    }
  } else {
    for (int s = 0; s < Ss; ++s) {
      // need h0(s) (fl0>=s+1) and own-layer h1(s-1) (fl1>=s; also covers ring WAR)
      poll2(wsu, fl0, (unsigned)(s+1), fl1, (unsigned)s, tid);
      f32x4 aG0={0.f,0.f,0.f,0.f}, aG1={0.f,0.f,0.f,0.f};
      const char* hbA = h0base + (size_t)(s&7)*SLOTB + rdoff;       // h0(s)
      const char* hbB = h1base + (size_t)((s+7)&7)*SLOTB + rdoff;   // h1(s-1)
      f16x8 A0[8], A1[8], A2[8], A3[8];
      f16x8 B0[8], B1[8], B2[8], B3[8];
      __builtin_amdgcn_sched_barrier(0);
      ISSUE8T(A0, hbA,       hbA+8192,  hbA+16384, hbA+24576);
      ISSUE8T(A1, hbA+32768, hbA+40960, hbA+49152, hbA+57344);
      ISSUE8T(A2, hbA+65536, hbA+73728, hbA+81920, hbA+90112);
      ISSUE8T(A3, hbA+98304, hbA+106496, hbA+114688, hbA+122880);
      WAITV(24); CONS8S(A0, 0);
      WAITV(16); CONS8S(A1, 8);
      WAITV(8);  CONS8S(A2, 16);
      ISSUE8T(B0, hbB,       hbB+8192,  hbB+16384, hbB+24576);
      ISSUE8T(B1, hbB+32768, hbB+40960, hbB+49152, hbB+57344);
      ISSUE8T(B2, hbB+65536, hbB+73728, hbB+81920, hbB+90112);
      ISSUE8T(B3, hbB+98304, hbB+106496, hbB+114688, hbB+122880);
      WAITV(32); CONS8S(A3, 24);
      WAITV(24); CONS8S(B0, 32);
      WAITV(16); CONS8S(B1, 40);
      WAITV(8);  CONS8S(B2, 48);
      WAITV(0);  CONS8S(B3, 56);
      // ---- gate exchange: C-wave -> LDS -> F-wave ----
      f32x4 p = aG0 + aG1;
      if (g == 1) *(f32x4*)(smem + 131072 + rt*1024 + lane*16) = p;
      __syncthreads();
      if (g == 0) {
        f32x4 pC = *(const f32x4*)(smem + 131072 + rt*1024 + lane*16);
        unsigned cu[4];
        #pragma unroll
        for (int j = 0; j < 4; ++j) {
          float f  = sigm(p[j] + bfv);
          float ct = tanhf_(pC[j] + bcv);
          cst[j] = f*cst[j] + (1.0f - f)*ct;
          union { _Float16 h; unsigned short u; } cv; cv.h = (f16)tanhf_(cst[j]);
          cu[j] = cv.u;
        }
        unsigned u01 = cu[0] | (cu[1] << 16);
        unsigned u23 = cu[2] | (cu[3] << 16);
        int sb = (kg << 4) + (part << 2);
        unsigned wsel[4];
        #pragma unroll
        for (int i = 0; i < 4; ++i) {
          unsigned w01 = __shfl(u01, sb + i, 64);
          unsigned w23 = __shfl(u23, sb + i, 64);
          unsigned w = (rsel < 2) ? w01 : w23;
          wsel[i] = (rsel & 1) ? (w >> 16) : (w & 0xffffu);
        }
        unsigned d0 = wsel[0] | (wsel[1] << 16);
        unsigned d1 = wsel[2] | (wsel[3] << 16);
        uint64_t dd = (uint64_t)d0 | ((uint64_t)d1 << 32);
        char* hd = h1base + (size_t)(s&7)*SLOTB + (size_t)lw*2048
                 + (size_t)half*1024 + (size_t)srowl*32 + (size_t)part*8;
        asm volatile("global_atomic_swap_x2 %0, %1, off" :: "v"(hd), "v"(dd) : "memory");
      }
      asm volatile("s_waitcnt vmcnt(0)" ::: "memory");
      __syncthreads();
      if (tid == 0) setflag(wsu + FL1_U32 + (half*64 + lw)*16, (unsigned)(s+1));
    }
  }

  // ---- final projection: out = h1(511) @ Wfc + bfc ----
  poll2(wsu, FL1_U32, (unsigned)Ss, FL1_U32 + 64*16, (unsigned)Ss, tid);
  if (tid < 128) {
    const char* fin = h1base + (size_t)7*SLOTB;    // 511&7 == 7
    const int o = wid*2 + (tid & 1);
    const int b = tid >> 1;
    const char* rowp = fin + (size_t)(b>>5)*1024 + (size_t)(b&31)*32;
    float acc = bfc[o];
    for (int cg = 0; cg < 64; ++cg) {
      f16x8 lo, hi;
      asm volatile("global_load_dwordx4 %0, %2, off sc0 sc1\n\t"
                   "global_load_dwordx4 %1, %2, off offset:16 sc0 sc1\n\t"
                   "s_waitcnt vmcnt(0)"
                   : "=&v"(lo), "=&v"(hi) : "v"(rowp + (size_t)cg*2048) : "memory");
      #pragma unroll
      for (int i = 0; i < 8; ++i) {
        acc += (float)lo[i] * Wfc[(size_t)(cg*16 + i)*Oo + o];
        acc += (float)hi[i] * Wfc[(size_t)(cg*16 + 8 + i)*Oo + o];
      }
    }
    out[(size_t)b*Oo + o] = acc;
  }
}

extern "C" void kernel_launch(void* const* d_in, const int* in_sizes, int n_in,
                              void* d_out, int out_size, void* d_ws, size_t ws_size,
                              hipStream_t stream) {
  const float* x   = (const float*)d_in[0];
  const float* Wf0 = (const float*)d_in[1];
  const float* bf0 = (const float*)d_in[2];
  const float* Wc0 = (const float*)d_in[3];
  const float* bc0 = (const float*)d_in[4];
  const float* Wf1 = (const float*)d_in[5];
  const float* bf1 = (const float*)d_in[6];
  const float* Wc1 = (const float*)d_in[7];
  const float* bc1 = (const float*)d_in[8];
  const float* Wfc = (const float*)d_in[9];
  const float* bfc = (const float*)d_in[10];

  init_fresh<<<64, 256, 0, stream>>>(d_ws);
  janet_persistent<<<NWG, 256, 0, stream>>>(x, Wf0, bf0, Wc0, bc0,
                                            Wf1, bf1, Wc1, bc1, Wfc, bfc,
                                            (float*)d_out, d_ws);
}

// Round 13
// 3509.059 us; speedup vs baseline: 12.7970x; 1.0091x over previous
//
#include <hip/hip_runtime.h>
#include <stdint.h>

typedef _Float16 f16;
typedef _Float16 f16x8 __attribute__((ext_vector_type(8)));
typedef float    f32x4 __attribute__((ext_vector_type(4)));

#define Bm 64
#define Ss 512
#define Ff 512
#define Hh 1024
#define Oo 512
#define NWG 256          // {L0,L1} x {half0,half1} x 64 col-groups
#define HBh (Bm*Hh)
#define SLOTB (HBh*2)    // 131072 B per slot

// ---- flag layout: flags[layer][half][cg], 64B stride ----
#define FL0_U32 0                        // flags0[half*64+cg] at u32 16*idx
#define FL1_U32 4096                     // flags1[...] at byte 16384
// ---- ring layout: 8 slots per layer; slot k&7 holds h(k); slot 7 = h(-1)=0 ----
#define NSLOT 8
#define H0F_BYTE ((size_t)65536)
#define H1F_BYTE (H0F_BYTE + (size_t)NSLOT*SLOTB)

#define MFMA16 __builtin_amdgcn_mfma_f32_16x16x32_f16

__device__ __forceinline__ float sigm(float x){ return 1.0f/(1.0f+__expf(-x)); }
__device__ __forceinline__ float tanhf_(float x){
  x = fminf(15.0f, fmaxf(-15.0f, x));
  float e = __expf(-2.0f*x);
  return (1.0f - e)/(1.0f + e);
}

__global__ void init_fresh(void* ws){
  const uint4 z = {0,0,0,0};
  int idx = blockIdx.x*blockDim.x + threadIdx.x;
  const int total = 4096 + 8192 + 8192;   // 64KB flags + h0 slot7 + h1 slot7
  for (int i = idx; i < total; i += gridDim.x*blockDim.x) {
    if (i < 4096)        ((uint4*)ws)[i] = z;
    else if (i < 12288)  ((uint4*)((char*)ws + H0F_BYTE + (size_t)7*SLOTB))[i-4096]  = z;
    else                 ((uint4*)((char*)ws + H1F_BYTE + (size_t)7*SLOTB))[i-12288] = z;
  }
}

// ---- sync primitives ----
__device__ __forceinline__ void setflag(unsigned* p, unsigned v){
  asm volatile("global_atomic_swap %0, %1, off" :: "v"(p), "v"(v) : "memory");
}

// poll one flag set with backoff
__device__ __forceinline__ void poll1(unsigned* wsu, int fb, unsigned tgt, int tid){
  if (tid < 64) {
    const unsigned* p0 = wsu + fb + 16*tid;
    for (;;) {
      unsigned v0;
      asm volatile("global_load_dword %0, %1, off sc0 sc1\n\t"
                   "s_waitcnt vmcnt(0)"
                   : "=&v"(v0) : "v"(p0) : "memory");
      if (__all(v0 >= tgt)) break;
      __builtin_amdgcn_s_sleep(1);
    }
  }
  asm volatile("s_waitcnt vmcnt(0)" ::: "memory");
  __builtin_amdgcn_sched_barrier(0);
  __syncthreads();
}

// poll two flag sets with backoff
__device__ __forceinline__ void poll2(unsigned* wsu, int fb0, unsigned tgt0,
                                      int fb1, unsigned tgt1, int tid){
  if (tid < 64) {
    const unsigned* p0 = wsu + fb0 + 16*tid;
    const unsigned* p1 = wsu + fb1 + 16*tid;
    for (;;) {
      unsigned v0, v1;
      asm volatile("global_load_dword %0, %2, off sc0 sc1\n\t"
                   "global_load_dword %1, %3, off sc0 sc1\n\t"
                   "s_waitcnt vmcnt(0)"
                   : "=&v"(v0), "=&v"(v1) : "v"(p0), "v"(p1) : "memory");
      if (__all((v0 >= tgt0) && (v1 >= tgt1))) break;
      __builtin_amdgcn_s_sleep(1);
    }
  }
  asm volatile("s_waitcnt vmcnt(0)" ::: "memory");
  __builtin_amdgcn_sched_barrier(0);
  __syncthreads();
}

// ring-slot batch: 8 LLC-direct (sc0 sc1) 16B loads; pointers pre-offset +4096;
// each pointer serves a ks pair via offsets {-4096, 0}
#define ISSUE8T(A, P0, P1, P2, P3) asm volatile( \
  "global_load_dwordx4 %0, %8, off offset:-4096 sc0 sc1\n\t" \
  "global_load_dwordx4 %1, %8, off sc0 sc1\n\t" \
  "global_load_dwordx4 %2, %9, off offset:-4096 sc0 sc1\n\t" \
  "global_load_dwordx4 %3, %9, off sc0 sc1\n\t" \
  "global_load_dwordx4 %4, %10, off offset:-4096 sc0 sc1\n\t" \
  "global_load_dwordx4 %5, %10, off sc0 sc1\n\t" \
  "global_load_dwordx4 %6, %11, off offset:-4096 sc0 sc1\n\t" \
  "global_load_dwordx4 %7, %11, off sc0 sc1" \
  : "=&v"(A[0]), "=&v"(A[1]), "=&v"(A[2]), "=&v"(A[3]), \
    "=&v"(A[4]), "=&v"(A[5]), "=&v"(A[6]), "=&v"(A[7]) \
  : "v"(P0), "v"(P1), "v"(P2), "v"(P3) : "memory")

#define WAITV(N) do{ asm volatile("s_waitcnt vmcnt(" #N ")" ::: "memory"); \
                     __builtin_amdgcn_sched_barrier(0x106); }while(0)

// 8 k-steps of SINGLE-gate MFMA (gate baked into gofs)
#define CONS8S(Aarr, KSB) do{ \
  _Pragma("unroll") \
  for (int j = 0; j < 8; ++j){ \
    f16x8 bw = ldsA[(size_t)(gofs + (KSB) + j)*64]; \
    if (j & 1) aG1 = MFMA16(Aarr[j], bw, aG1, 0,0,0); \
    else       aG0 = MFMA16(Aarr[j], bw, aG0, 0,0,0); \
  } \
}while(0)

__device__ __forceinline__ f16x8 cvt8(float4 v0, float4 v1){
  f16x8 a;
  a[0]=v0.x; a[1]=v0.y; a[2]=v0.z; a[3]=v0.w;
  a[4]=v1.x; a[5]=v1.y; a[6]=v1.z; a[7]=v1.w;
  return a;
}

__global__ __launch_bounds__(256,1) void janet_persistent(
    const float* __restrict__ x,
    const float* __restrict__ Wf0, const float* __restrict__ bf0,
    const float* __restrict__ Wc0, const float* __restrict__ bc0,
    const float* __restrict__ Wf1, const float* __restrict__ bf1,
    const float* __restrict__ Wc1, const float* __restrict__ bc1,
    const float* __restrict__ Wfc, const float* __restrict__ bfc,
    float* __restrict__ out, void* __restrict__ ws)
{
  __shared__ __align__(16) unsigned char smem[133120];   // 128KB weights + 2KB scratch
  __builtin_amdgcn_fence(__ATOMIC_ACQUIRE, "agent");

  unsigned* wsu = (unsigned*)ws;
  char* h0base = (char*)ws + H0F_BYTE;
  char* h1base = (char*)ws + H1F_BYTE;

  const int wid  = blockIdx.x;
  const int tid  = threadIdx.x;
  const bool isL0 = (wid < 128);
  const int half = (wid >> 6) & 1;
  const int lw   = wid & 63;           // col-group
  const int col0 = lw * 16;
  const int K    = isL0 ? (Ff + Hh) : (2*Hh);   // 1536 / 2048
  const int KS   = K >> 5;                      // 48 / 64

  // ---- stage weights into LDS in MFMA B-fragment order [gate][ks][lane] ----
  {
    const float* Wg[2] = { isL0 ? Wf0 : Wf1, isL0 ? Wc0 : Wc1 };
    for (int g = 0; g < 2; ++g) {
      const float* W = Wg[g];
      for (int e = tid; e < 16*K; e += 256) {
        int n = e & 15, k = e >> 4;
        float v = W[(size_t)k*Hh + col0 + n];
        int ks = k >> 5, sub = (k >> 3) & 3, j = k & 7;
        int lane = n + (sub << 4);
        int byte = ((g*KS + ks) << 10) + (lane << 4) + (j << 1);
        *(f16*)(smem + byte) = (f16)v;
      }
    }
  }
  __syncthreads();

  const int lane = tid & 63;
  const int wv   = tid >> 6;
  const int rt   = wv & 1;         // row-tile within the 32-row half
  const int g    = wv >> 1;        // gate: 0=F, 1=C
  const int gofs = g * KS;
  const int n    = lane & 15;
  const int kg   = lane >> 4;
  const int e8   = kg * 8;
  const int lrow = rt*16 + n;      // local row this lane LOADS (A-frag)
  const int grow = half*32 + lrow; // global batch row (x addressing)
  const int part = n & 3;
  const int rsel = n >> 2;
  const int srowl = rt*16 + 4*kg + rsel;

  const float* bfp = isL0 ? bf0 : bf1;
  const float* bcp = isL0 ? bc0 : bc1;
  const float bfv = bfp[col0 + n];
  const float bcv = bcp[col0 + n];

  const f16x8* ldsA = (const f16x8*)(smem + (size_t)lane*16);
  const size_t rdoff = (size_t)(kg>>1)*2048 + (size_t)half*1024
                     + (size_t)lrow*32 + (size_t)(kg&1)*16 + 4096;

  const int fl0 = FL0_U32 + (half*64)*16;
  const int fl1 = FL1_U32 + (half*64)*16;

  f32x4 cst = {0.f,0.f,0.f,0.f};

  if (isL0) {
    for (int t = 0; t < Ss; ++t) {
      // ---- x(t) loads + x-MFMAs fully BEFORE the poll (off critical path) ----
      const float* xb = x + ((size_t)grow*Ss + (size_t)t)*Ff + e8;
      float4 xv0[16], xv1[16];
      #pragma unroll
      for (int i = 0; i < 16; ++i) {
        xv0[i] = *(const float4*)(xb + 32*i);
        xv1[i] = *(const float4*)(xb + 32*i + 4);
      }
      f32x4 aG0={0.f,0.f,0.f,0.f}, aG1={0.f,0.f,0.f,0.f};
      #pragma unroll
      for (int ks = 0; ks < 16; ++ks) {
        f16x8 a  = cvt8(xv0[ks], xv1[ks]);
        f16x8 bw = ldsA[(size_t)(gofs + ks)*64];
        if (ks & 1) aG1 = MFMA16(a, bw, aG1, 0,0,0);
        else        aG0 = MFMA16(a, bw, aG0, 0,0,0);
      }
      // ---- wait: h0(t-1) done (fl0>=t); ring WAR: L1 done reading h0(t-8) ----
      poll2(wsu, fl0, (unsigned)t, fl1, t >= 8 ? (unsigned)(t-7) : 0u, tid);
      // ---- h0(t-1) region: ring slot (t-1)&7, LLC-direct pipelined loads ----
      const char* hb = h0base + (size_t)((t+7)&7)*SLOTB + rdoff;
      f16x8 A0[8], A1[8], A2[8], A3[8];
      __builtin_amdgcn_sched_barrier(0);
      ISSUE8T(A0, hb,       hb+8192,  hb+16384, hb+24576);
      ISSUE8T(A1, hb+32768, hb+40960, hb+49152, hb+57344);
      ISSUE8T(A2, hb+65536, hb+73728, hb+81920, hb+90112);
      ISSUE8T(A3, hb+98304, hb+106496, hb+114688, hb+122880);
      WAITV(24); CONS8S(A0, 16);
      WAITV(16); CONS8S(A1, 24);
      WAITV(8);  CONS8S(A2, 32);
      WAITV(0);  CONS8S(A3, 40);
      // ---- gate exchange: C-wave -> LDS -> F-wave ----
      f32x4 p = aG0 + aG1;
      if (g == 1) *(f32x4*)(smem + 131072 + rt*1024 + lane*16) = p;
      __syncthreads();
      if (g == 0) {
        f32x4 pC = *(const f32x4*)(smem + 131072 + rt*1024 + lane*16);
        unsigned cu[4];
        #pragma unroll
        for (int j = 0; j < 4; ++j) {
          float f  = sigm(p[j] + bfv);
          float ct = tanhf_(pC[j] + bcv);
          cst[j] = f*cst[j] + (1.0f - f)*ct;
          union { _Float16 h; unsigned short u; } cv; cv.h = (f16)tanhf_(cst[j]);
          cu[j] = cv.u;
        }
        unsigned u01 = cu[0] | (cu[1] << 16);
        unsigned u23 = cu[2] | (cu[3] << 16);
        int sb = (kg << 4) + (part << 2);
        unsigned wsel[4];
        #pragma unroll
        for (int i = 0; i < 4; ++i) {
          unsigned w01 = __shfl(u01, sb + i, 64);
          unsigned w23 = __shfl(u23, sb + i, 64);
          unsigned w = (rsel < 2) ? w01 : w23;
          wsel[i] = (rsel & 1) ? (w >> 16) : (w & 0xffffu);
        }
        unsigned d0 = wsel[0] | (wsel[1] << 16);
        unsigned d1 = wsel[2] | (wsel[3] << 16);
        uint64_t dd = (uint64_t)d0 | ((uint64_t)d1 << 32);
        char* hd = h0base + (size_t)(t&7)*SLOTB + (size_t)lw*2048
                 + (size_t)half*1024 + (size_t)srowl*32 + (size_t)part*8;
        asm volatile("global_atomic_swap_x2 %0, %1, off" :: "v"(hd), "v"(dd) : "memory");
      }
      asm volatile("s_waitcnt vmcnt(0)" ::: "memory");
      __syncthreads();
      if (tid == 0) setflag(wsu + FL0_U32 + (half*64 + lw)*16, (unsigned)(t+1));
    }
  } else {
    for (int s = 0; s < Ss; ++s) {
      // need h0(s) (fl0>=s+1) and own-layer h1(s-1) (fl1>=s; also covers ring WAR)
      poll2(wsu, fl0, (unsigned)(s+1), fl1, (unsigned)s, tid);
      f32x4 aG0={0.f,0.f,0.f,0.f}, aG1={0.f,0.f,0.f,0.f};
      const char* hbA = h0base + (size_t)(s&7)*SLOTB + rdoff;       // h0(s)
      const char* hbB = h1base + (size_t)((s+7)&7)*SLOTB + rdoff;   // h1(s-1)
      f16x8 A0[8], A1[8], A2[8], A3[8];
      f16x8 B0[8], B1[8], B2[8], B3[8];
      __builtin_amdgcn_sched_barrier(0);
      // issue-early, capped at 48 outstanding (vmcnt is 6-bit; v11/v12's 64
      // outstanding is the prime suspect for the deterministic corruption)
      ISSUE8T(A0, hbA,       hbA+8192,  hbA+16384, hbA+24576);
      ISSUE8T(A1, hbA+32768, hbA+40960, hbA+49152, hbA+57344);
      ISSUE8T(A2, hbA+65536, hbA+73728, hbA+81920, hbA+90112);
      ISSUE8T(A3, hbA+98304, hbA+106496, hbA+114688, hbA+122880);
      ISSUE8T(B0, hbB,       hbB+8192,  hbB+16384, hbB+24576);
      ISSUE8T(B1, hbB+32768, hbB+40960, hbB+49152, hbB+57344);      // 48 in flight
      WAITV(40); CONS8S(A0, 0);
      WAITV(32); CONS8S(A1, 8);
      ISSUE8T(B2, hbB+65536, hbB+73728, hbB+81920, hbB+90112);
      ISSUE8T(B3, hbB+98304, hbB+106496, hbB+114688, hbB+122880);   // back to 48
      WAITV(40); CONS8S(A2, 16);
      WAITV(32); CONS8S(A3, 24);
      WAITV(24); CONS8S(B0, 32);
      WAITV(16); CONS8S(B1, 40);
      WAITV(8);  CONS8S(B2, 48);
      WAITV(0);  CONS8S(B3, 56);
      // ---- gate exchange: C-wave -> LDS -> F-wave ----
      f32x4 p = aG0 + aG1;
      if (g == 1) *(f32x4*)(smem + 131072 + rt*1024 + lane*16) = p;
      __syncthreads();
      if (g == 0) {
        f32x4 pC = *(const f32x4*)(smem + 131072 + rt*1024 + lane*16);
        unsigned cu[4];
        #pragma unroll
        for (int j = 0; j < 4; ++j) {
          float f  = sigm(p[j] + bfv);
          float ct = tanhf_(pC[j] + bcv);
          cst[j] = f*cst[j] + (1.0f - f)*ct;
          union { _Float16 h; unsigned short u; } cv; cv.h = (f16)tanhf_(cst[j]);
          cu[j] = cv.u;
        }
        unsigned u01 = cu[0] | (cu[1] << 16);
        unsigned u23 = cu[2] | (cu[3] << 16);
        int sb = (kg << 4) + (part << 2);
        unsigned wsel[4];
        #pragma unroll
        for (int i = 0; i < 4; ++i) {
          unsigned w01 = __shfl(u01, sb + i, 64);
          unsigned w23 = __shfl(u23, sb + i, 64);
          unsigned w = (rsel < 2) ? w01 : w23;
          wsel[i] = (rsel & 1) ? (w >> 16) : (w & 0xffffu);
        }
        unsigned d0 = wsel[0] | (wsel[1] << 16);
        unsigned d1 = wsel[2] | (wsel[3] << 16);
        uint64_t dd = (uint64_t)d0 | ((uint64_t)d1 << 32);
        char* hd = h1base + (size_t)(s&7)*SLOTB + (size_t)lw*2048
                 + (size_t)half*1024 + (size_t)srowl*32 + (size_t)part*8;
        asm volatile("global_atomic_swap_x2 %0, %1, off" :: "v"(hd), "v"(dd) : "memory");
      }
      asm volatile("s_waitcnt vmcnt(0)" ::: "memory");
      __syncthreads();
      if (tid == 0) setflag(wsu + FL1_U32 + (half*64 + lw)*16, (unsigned)(s+1));
    }
  }

  // ---- final projection: out = h1(511) @ Wfc + bfc ----
  poll2(wsu, FL1_U32, (unsigned)Ss, FL1_U32 + 64*16, (unsigned)Ss, tid);
  if (tid < 128) {
    const char* fin = h1base + (size_t)7*SLOTB;    // 511&7 == 7
    const int o = wid*2 + (tid & 1);
    const int b = tid >> 1;
    const char* rowp = fin + (size_t)(b>>5)*1024 + (size_t)(b&31)*32;
    float acc = bfc[o];
    for (int cg = 0; cg < 64; ++cg) {
      f16x8 lo, hi;
      asm volatile("global_load_dwordx4 %0, %2, off sc0 sc1\n\t"
                   "global_load_dwordx4 %1, %2, off offset:16 sc0 sc1\n\t"
                   "s_waitcnt vmcnt(0)"
                   : "=&v"(lo), "=&v"(hi) : "v"(rowp + (size_t)cg*2048) : "memory");
      #pragma unroll
      for (int i = 0; i < 8; ++i) {
        acc += (float)lo[i] * Wfc[(size_t)(cg*16 + i)*Oo + o];
        acc += (float)hi[i] * Wfc[(size_t)(cg*16 + 8 + i)*Oo + o];
      }
    }
    out[(size_t)b*Oo + o] = acc;
  }
}

extern "C" void kernel_launch(void* const* d_in, const int* in_sizes, int n_in,
                              void* d_out, int out_size, void* d_ws, size_t ws_size,
                              hipStream_t stream) {
  const float* x   = (const float*)d_in[0];
  const float* Wf0 = (const float*)d_in[1];
  const float* bf0 = (const float*)d_in[2];
  const float* Wc0 = (const float*)d_in[3];
  const float* bc0 = (const float*)d_in[4];
  const float* Wf1 = (const float*)d_in[5];
  const float* bf1 = (const float*)d_in[6];
  const float* Wc1 = (const float*)d_in[7];
  const float* bc1 = (const float*)d_in[8];
  const float* Wfc = (const float*)d_in[9];
  const float* bfc = (const float*)d_in[10];

  init_fresh<<<64, 256, 0, stream>>>(d_ws);
  janet_persistent<<<NWG, 256, 0, stream>>>(x, Wf0, bf0, Wc0, bc0,
                                            Wf1, bf1, Wc1, bc1, Wfc, bfc,
                                            (float*)d_out, d_ws);
}

// Round 14
// 2538.243 us; speedup vs baseline: 17.6915x; 1.3825x over previous
//
#include <hip/hip_runtime.h>
#include <stdint.h>

typedef _Float16 f16;
typedef _Float16 f16x8 __attribute__((ext_vector_type(8)));
typedef float    f32x4 __attribute__((ext_vector_type(4)));

#define Bm 64
#define Ss 512
#define Ff 512
#define Hh 1024
#define Oo 512
#define NWG 256          // {L0,L1} x {half0,half1} x 64 col-groups
#define HBh (Bm*Hh)
#define SLOTB (HBh*2)    // 131072 B per slot

// ---- flag layout: flags[layer][half][cg], 64B stride ----
#define FL0_U32 0                        // flags0[half*64+cg] at u32 16*idx
#define FL1_U32 4096                     // flags1[...] at byte 16384
// ---- ring layout: 8 slots per layer; slot k&7 holds h(k); slot 7 = h(-1)=0 ----
#define NSLOT 8
#define H0F_BYTE ((size_t)65536)
#define H1F_BYTE (H0F_BYTE + (size_t)NSLOT*SLOTB)

#define MFMA16 __builtin_amdgcn_mfma_f32_16x16x32_f16

__device__ __forceinline__ float sigm(float x){ return 1.0f/(1.0f+__expf(-x)); }
__device__ __forceinline__ float tanhf_(float x){
  x = fminf(15.0f, fmaxf(-15.0f, x));
  float e = __expf(-2.0f*x);
  return (1.0f - e)/(1.0f + e);
}

__global__ void init_fresh(void* ws){
  const uint4 z = {0,0,0,0};
  int idx = blockIdx.x*blockDim.x + threadIdx.x;
  const int total = 4096 + 8192 + 8192;   // 64KB flags + h0 slot7 + h1 slot7
  for (int i = idx; i < total; i += gridDim.x*blockDim.x) {
    if (i < 4096)        ((uint4*)ws)[i] = z;
    else if (i < 12288)  ((uint4*)((char*)ws + H0F_BYTE + (size_t)7*SLOTB))[i-4096]  = z;
    else                 ((uint4*)((char*)ws + H1F_BYTE + (size_t)7*SLOTB))[i-12288] = z;
  }
}

// ---- sync primitives ----
__device__ __forceinline__ void setflag(unsigned* p, unsigned v){
  asm volatile("global_atomic_swap %0, %1, off" :: "v"(p), "v"(v) : "memory");
}

// poll two flag sets with backoff (wave 0 polls; barrier holds the WG)
__device__ __forceinline__ void poll2(unsigned* wsu, int fb0, unsigned tgt0,
                                      int fb1, unsigned tgt1, int tid){
  if (tid < 64) {
    const unsigned* p0 = wsu + fb0 + 16*tid;
    const unsigned* p1 = wsu + fb1 + 16*tid;
    for (;;) {
      unsigned v0, v1;
      asm volatile("global_load_dword %0, %2, off sc0 sc1\n\t"
                   "global_load_dword %1, %3, off sc0 sc1\n\t"
                   "s_waitcnt vmcnt(0)"
                   : "=&v"(v0), "=&v"(v1) : "v"(p0), "v"(p1) : "memory");
      if (__all((v0 >= tgt0) && (v1 >= tgt1))) break;
      __builtin_amdgcn_s_sleep(1);
    }
  }
  asm volatile("s_waitcnt vmcnt(0)" ::: "memory");
  __builtin_amdgcn_sched_barrier(0);
  __syncthreads();
}

// ring-slot batch: 8 LLC-direct (sc0 sc1) 16B loads; pointers pre-offset +4096;
// each pointer serves a ks pair via offsets {-4096, 0}
#define ISSUE8T(A, P0, P1, P2, P3) asm volatile( \
  "global_load_dwordx4 %0, %8, off offset:-4096 sc0 sc1\n\t" \
  "global_load_dwordx4 %1, %8, off sc0 sc1\n\t" \
  "global_load_dwordx4 %2, %9, off offset:-4096 sc0 sc1\n\t" \
  "global_load_dwordx4 %3, %9, off sc0 sc1\n\t" \
  "global_load_dwordx4 %4, %10, off offset:-4096 sc0 sc1\n\t" \
  "global_load_dwordx4 %5, %10, off sc0 sc1\n\t" \
  "global_load_dwordx4 %6, %11, off offset:-4096 sc0 sc1\n\t" \
  "global_load_dwordx4 %7, %11, off sc0 sc1" \
  : "=&v"(A[0]), "=&v"(A[1]), "=&v"(A[2]), "=&v"(A[3]), \
    "=&v"(A[4]), "=&v"(A[5]), "=&v"(A[6]), "=&v"(A[7]) \
  : "v"(P0), "v"(P1), "v"(P2), "v"(P3) : "memory")

#define WAITV(N) do{ asm volatile("s_waitcnt vmcnt(" #N ")" ::: "memory"); \
                     __builtin_amdgcn_sched_barrier(0x106); }while(0)

// 8 k-steps of DUAL-gate MFMA; F weights at ks, C weights at KSC+ks
#define CONS8D(Aarr, KSB, KSC) do{ \
  _Pragma("unroll") \
  for (int j = 0; j < 8; ++j){ \
    f16x8 bw = ldsA[(size_t)((KSB)+j)*64]; \
    f16x8 cw = ldsA[(size_t)((KSC)+(KSB)+j)*64]; \
    if (j & 1){ aF1 = MFMA16(Aarr[j], bw, aF1, 0,0,0); aC1 = MFMA16(Aarr[j], cw, aC1, 0,0,0); } \
    else      { aF0 = MFMA16(Aarr[j], bw, aF0, 0,0,0); aC0 = MFMA16(Aarr[j], cw, aC0, 0,0,0); } \
  } \
}while(0)

__device__ __forceinline__ f16x8 cvt8(float4 v0, float4 v1){
  f16x8 a;
  a[0]=v0.x; a[1]=v0.y; a[2]=v0.z; a[3]=v0.w;
  a[4]=v1.x; a[5]=v1.y; a[6]=v1.z; a[7]=v1.w;
  return a;
}

__global__ __launch_bounds__(256,1) void janet_persistent(
    const float* __restrict__ x,
    const float* __restrict__ Wf0, const float* __restrict__ bf0,
    const float* __restrict__ Wc0, const float* __restrict__ bc0,
    const float* __restrict__ Wf1, const float* __restrict__ bf1,
    const float* __restrict__ Wc1, const float* __restrict__ bc1,
    const float* __restrict__ Wfc, const float* __restrict__ bfc,
    float* __restrict__ out, void* __restrict__ ws)
{
  __shared__ __align__(16) unsigned char smem[135168];   // 128KB W + 4KB partial-xchg
  __builtin_amdgcn_fence(__ATOMIC_ACQUIRE, "agent");

  unsigned* wsu = (unsigned*)ws;
  char* h0base = (char*)ws + H0F_BYTE;
  char* h1base = (char*)ws + H1F_BYTE;

  const int wid  = blockIdx.x;
  const int tid  = threadIdx.x;
  const bool isL0 = (wid < 128);
  const int half = (wid >> 6) & 1;
  const int lw   = wid & 63;           // col-group
  const int col0 = lw * 16;
  const int K    = isL0 ? (Ff + Hh) : (2*Hh);   // 1536 / 2048
  const int KS   = K >> 5;                      // 48 / 64

  // ---- stage weights into LDS in MFMA B-fragment order [gate][ks][lane] ----
  {
    const float* Wg[2] = { isL0 ? Wf0 : Wf1, isL0 ? Wc0 : Wc1 };
    for (int g = 0; g < 2; ++g) {
      const float* W = Wg[g];
      for (int e = tid; e < 16*K; e += 256) {
        int n = e & 15, k = e >> 4;
        float v = W[(size_t)k*Hh + col0 + n];
        int ks = k >> 5, sub = (k >> 3) & 3, j = k & 7;
        int lane = n + (sub << 4);
        int byte = ((g*KS + ks) << 10) + (lane << 4) + (j << 1);
        *(f16*)(smem + byte) = (f16)v;
      }
    }
  }
  __syncthreads();

  const int lane = tid & 63;
  const int wv   = tid >> 6;
  const int rt   = wv & 1;         // row-tile within the 32-row half
  const int kh   = wv >> 1;        // K-half: which half of the reduction axis
  const int n    = lane & 15;
  const int kg   = lane >> 4;
  const int e8   = kg * 8;
  const int lrow = rt*16 + n;      // local row this lane LOADS (A-frag)
  const int grow = half*32 + lrow; // global batch row (x addressing)
  const int part = n & 3;
  const int rsel = n >> 2;
  const int srowl = rt*16 + 4*kg + rsel;

  const float* bfp = isL0 ? bf0 : bf1;
  const float* bcp = isL0 ? bc0 : bc1;
  const float bfv = bfp[col0 + n];
  const float bcv = bcp[col0 + n];

  const f16x8* ldsA = (const f16x8*)(smem + (size_t)lane*16);
  const size_t rdoff = (size_t)(kg>>1)*2048 + (size_t)half*1024
                     + (size_t)lrow*32 + (size_t)(kg&1)*16 + 4096;
  // partial-sum exchange buffer: rt*2048 + lane*32 (two f32x4 per lane)
  float* xchg = (float*)(smem + 131072 + rt*2048 + lane*32);

  const int fl0 = FL0_U32 + (half*64)*16;
  const int fl1 = FL1_U32 + (half*64)*16;

  f32x4 cst = {0.f,0.f,0.f,0.f};

  if (isL0) {
    for (int t = 0; t < Ss; ++t) {
      f32x4 aF0={0.f,0.f,0.f,0.f}, aF1={0.f,0.f,0.f,0.f};
      f32x4 aC0={0.f,0.f,0.f,0.f}, aC1={0.f,0.f,0.f,0.f};
      // ---- x sub-range for this K-half wave, fully BEFORE the poll ----
      // wave kh covers x k-steps [kh*8, kh*8+8)
      const float* xb = x + ((size_t)grow*Ss + (size_t)t)*Ff + (size_t)kh*256 + e8;
      float4 xv0[8], xv1[8];
      #pragma unroll
      for (int i = 0; i < 8; ++i) {
        xv0[i] = *(const float4*)(xb + 32*i);
        xv1[i] = *(const float4*)(xb + 32*i + 4);
      }
      #pragma unroll
      for (int i = 0; i < 8; ++i) {
        f16x8 a  = cvt8(xv0[i], xv1[i]);
        int ks = kh*8 + i;
        f16x8 bw = ldsA[(size_t)ks*64];
        f16x8 cw = ldsA[(size_t)(48 + ks)*64];
        if (i & 1){ aF1 = MFMA16(a, bw, aF1, 0,0,0); aC1 = MFMA16(a, cw, aC1, 0,0,0); }
        else      { aF0 = MFMA16(a, bw, aF0, 0,0,0); aC0 = MFMA16(a, cw, aC0, 0,0,0); }
      }
      // ---- wait: h0(t-1) done (fl0>=t); ring WAR: L1 done reading h0(t-8) ----
      poll2(wsu, fl0, (unsigned)t, fl1, t >= 8 ? (unsigned)(t-7) : 0u, tid);
      // ---- h0(t-1): wave kh covers h k-steps [kh*16, kh*16+16) ----
      const char* hb = h0base + (size_t)((t+7)&7)*SLOTB + rdoff + (size_t)kh*65536;
      f16x8 A0[8], A1[8];
      __builtin_amdgcn_sched_barrier(0);
      ISSUE8T(A0, hb,       hb+8192,  hb+16384, hb+24576);
      ISSUE8T(A1, hb+32768, hb+40960, hb+49152, hb+57344);
      WAITV(8); CONS8D(A0, 16 + kh*16, 48);
      WAITV(0); CONS8D(A1, 24 + kh*16, 48);
      // ---- K-half reduce: kh=1 -> LDS -> kh=0 adds; acts+store by kh=0 ----
      f32x4 pF = aF0 + aF1, pC = aC0 + aC1;
      if (kh == 1) { *(f32x4*)xchg = pF; *(f32x4*)(xchg+4) = pC; }
      __syncthreads();
      if (kh == 0) {
        pF += *(const f32x4*)xchg;
        pC += *(const f32x4*)(xchg+4);
        unsigned cu[4];
        #pragma unroll
        for (int j = 0; j < 4; ++j) {
          float f  = sigm(pF[j] + bfv);
          float ct = tanhf_(pC[j] + bcv);
          cst[j] = f*cst[j] + (1.0f - f)*ct;
          union { _Float16 h; unsigned short u; } cv; cv.h = (f16)tanhf_(cst[j]);
          cu[j] = cv.u;
        }
        unsigned u01 = cu[0] | (cu[1] << 16);
        unsigned u23 = cu[2] | (cu[3] << 16);
        int sb = (kg << 4) + (part << 2);
        unsigned wsel[4];
        #pragma unroll
        for (int i = 0; i < 4; ++i) {
          unsigned w01 = __shfl(u01, sb + i, 64);
          unsigned w23 = __shfl(u23, sb + i, 64);
          unsigned w = (rsel < 2) ? w01 : w23;
          wsel[i] = (rsel & 1) ? (w >> 16) : (w & 0xffffu);
        }
        unsigned d0 = wsel[0] | (wsel[1] << 16);
        unsigned d1 = wsel[2] | (wsel[3] << 16);
        uint64_t dd = (uint64_t)d0 | ((uint64_t)d1 << 32);
        char* hd = h0base + (size_t)(t&7)*SLOTB + (size_t)lw*2048
                 + (size_t)half*1024 + (size_t)srowl*32 + (size_t)part*8;
        asm volatile("global_atomic_swap_x2 %0, %1, off" :: "v"(hd), "v"(dd) : "memory");
      }
      asm volatile("s_waitcnt vmcnt(0)" ::: "memory");
      __syncthreads();
      if (tid == 0) setflag(wsu + FL0_U32 + (half*64 + lw)*16, (unsigned)(t+1));
    }
  } else {
    for (int s = 0; s < Ss; ++s) {
      // need h0(s) (fl0>=s+1) and own-layer h1(s-1) (fl1>=s; also covers ring WAR)
      poll2(wsu, fl0, (unsigned)(s+1), fl1, (unsigned)s, tid);
      f32x4 aF0={0.f,0.f,0.f,0.f}, aF1={0.f,0.f,0.f,0.f};
      f32x4 aC0={0.f,0.f,0.f,0.f}, aC1={0.f,0.f,0.f,0.f};
      // wave kh=0: h0(s) (k-steps 0..31); kh=1: h1(s-1) (k-steps 32..63)
      const char* hb = (kh == 0)
        ? h0base + (size_t)(s&7)*SLOTB + rdoff
        : h1base + (size_t)((s+7)&7)*SLOTB + rdoff;
      f16x8 A0[8], A1[8], A2[8], A3[8];
      __builtin_amdgcn_sched_barrier(0);
      ISSUE8T(A0, hb,       hb+8192,  hb+16384, hb+24576);
      ISSUE8T(A1, hb+32768, hb+40960, hb+49152, hb+57344);
      ISSUE8T(A2, hb+65536, hb+73728, hb+81920, hb+90112);
      ISSUE8T(A3, hb+98304, hb+106496, hb+114688, hb+122880);
      {
        const int kb = kh*32;
        WAITV(24); CONS8D(A0, kb + 0,  64);
        WAITV(16); CONS8D(A1, kb + 8,  64);
        WAITV(8);  CONS8D(A2, kb + 16, 64);
        WAITV(0);  CONS8D(A3, kb + 24, 64);
      }
      // ---- K-half reduce + acts + store ----
      f32x4 pF = aF0 + aF1, pC = aC0 + aC1;
      if (kh == 1) { *(f32x4*)xchg = pF; *(f32x4*)(xchg+4) = pC; }
      __syncthreads();
      if (kh == 0) {
        pF += *(const f32x4*)xchg;
        pC += *(const f32x4*)(xchg+4);
        unsigned cu[4];
        #pragma unroll
        for (int j = 0; j < 4; ++j) {
          float f  = sigm(pF[j] + bfv);
          float ct = tanhf_(pC[j] + bcv);
          cst[j] = f*cst[j] + (1.0f - f)*ct;
          union { _Float16 h; unsigned short u; } cv; cv.h = (f16)tanhf_(cst[j]);
          cu[j] = cv.u;
        }
        unsigned u01 = cu[0] | (cu[1] << 16);
        unsigned u23 = cu[2] | (cu[3] << 16);
        int sb = (kg << 4) + (part << 2);
        unsigned wsel[4];
        #pragma unroll
        for (int i = 0; i < 4; ++i) {
          unsigned w01 = __shfl(u01, sb + i, 64);
          unsigned w23 = __shfl(u23, sb + i, 64);
          unsigned w = (rsel < 2) ? w01 : w23;
          wsel[i] = (rsel & 1) ? (w >> 16) : (w & 0xffffu);
        }
        unsigned d0 = wsel[0] | (wsel[1] << 16);
        unsigned d1 = wsel[2] | (wsel[3] << 16);
        uint64_t dd = (uint64_t)d0 | ((uint64_t)d1 << 32);
        char* hd = h1base + (size_t)(s&7)*SLOTB + (size_t)lw*2048
                 + (size_t)half*1024 + (size_t)srowl*32 + (size_t)part*8;
        asm volatile("global_atomic_swap_x2 %0, %1, off" :: "v"(hd), "v"(dd) : "memory");
      }
      asm volatile("s_waitcnt vmcnt(0)" ::: "memory");
      __syncthreads();
      if (tid == 0) setflag(wsu + FL1_U32 + (half*64 + lw)*16, (unsigned)(s+1));
    }
  }

  // ---- final projection: out = h1(511) @ Wfc + bfc ----
  poll2(wsu, FL1_U32, (unsigned)Ss, FL1_U32 + 64*16, (unsigned)Ss, tid);
  if (tid < 128) {
    const char* fin = h1base + (size_t)7*SLOTB;    // 511&7 == 7
    const int o = wid*2 + (tid & 1);
    const int b = tid >> 1;
    const char* rowp = fin + (size_t)(b>>5)*1024 + (size_t)(b&31)*32;
    float acc = bfc[o];
    for (int cg = 0; cg < 64; ++cg) {
      f16x8 lo, hi;
      asm volatile("global_load_dwordx4 %0, %2, off sc0 sc1\n\t"
                   "global_load_dwordx4 %1, %2, off offset:16 sc0 sc1\n\t"
                   "s_waitcnt vmcnt(0)"
                   : "=&v"(lo), "=&v"(hi) : "v"(rowp + (size_t)cg*2048) : "memory");
      #pragma unroll
      for (int i = 0; i < 8; ++i) {
        acc += (float)lo[i] * Wfc[(size_t)(cg*16 + i)*Oo + o];
        acc += (float)hi[i] * Wfc[(size_t)(cg*16 + 8 + i)*Oo + o];
      }
    }
    out[(size_t)b*Oo + o] = acc;
  }
}

extern "C" void kernel_launch(void* const* d_in, const int* in_sizes, int n_in,
                              void* d_out, int out_size, void* d_ws, size_t ws_size,
                              hipStream_t stream) {
  const float* x   = (const float*)d_in[0];
  const float* Wf0 = (const float*)d_in[1];
  const float* bf0 = (const float*)d_in[2];
  const float* Wc0 = (const float*)d_in[3];
  const float* bc0 = (const float*)d_in[4];
  const float* Wf1 = (const float*)d_in[5];
  const float* bf1 = (const float*)d_in[6];
  const float* Wc1 = (const float*)d_in[7];
  const float* bc1 = (const float*)d_in[8];
  const float* Wfc = (const float*)d_in[9];
  const float* bfc = (const float*)d_in[10];

  init_fresh<<<64, 256, 0, stream>>>(d_ws);
  janet_persistent<<<NWG, 256, 0, stream>>>(x, Wf0, bf0, Wc0, bc0,
                                            Wf1, bf1, Wc1, bc1, Wfc, bfc,
                                            (float*)d_out, d_ws);
}

// Round 15
// 2448.532 us; speedup vs baseline: 18.3397x; 1.0366x over previous
//
#include <hip/hip_runtime.h>
#include <stdint.h>

typedef _Float16 f16;
typedef _Float16 f16x8 __attribute__((ext_vector_type(8)));
typedef float    f32x4 __attribute__((ext_vector_type(4)));

#define Bm 64
#define Ss 512
#define Ff 512
#define Hh 1024
#define Oo 512
#define NWG 256          // {L0,L1} x {half0,half1} x 64 col-groups
#define HBh (Bm*Hh)
#define SLOTB (HBh*2)    // 131072 B per slot

// ---- flag layout: flags[layer][half][cg], 64B stride ----
#define FL0_U32 0                        // flags0[half*64+cg] at u32 16*idx
#define FL1_U32 4096                     // flags1[...] at byte 16384
// ---- write-once layout: slot k holds h(k-1); slot 0 = zeros ----
#define NSLOT 513
#define H0F_BYTE ((size_t)65536)
#define H1F_BYTE (H0F_BYTE + (size_t)NSLOT*SLOTB)
#define WSF_NEED (H1F_BYTE + (size_t)NSLOT*SLOTB)   // ~134.5 MB (fits: r6-r9)

#define MFMA16 __builtin_amdgcn_mfma_f32_16x16x32_f16

__device__ __forceinline__ float sigm(float x){ return 1.0f/(1.0f+__expf(-x)); }
__device__ __forceinline__ float tanhf_(float x){
  x = fminf(15.0f, fmaxf(-15.0f, x));
  float e = __expf(-2.0f*x);
  return (1.0f - e)/(1.0f + e);
}

__global__ void init_fresh(void* ws){
  const uint4 z = {0,0,0,0};
  int idx = blockIdx.x*blockDim.x + threadIdx.x;
  const int total = 4096 + 8192 + 8192;   // 64KB flags + h0 slot0 + h1 slot0
  for (int i = idx; i < total; i += gridDim.x*blockDim.x) {
    if (i < 4096)        ((uint4*)ws)[i] = z;
    else if (i < 12288)  ((uint4*)((char*)ws + H0F_BYTE))[i-4096]  = z;
    else                 ((uint4*)((char*)ws + H1F_BYTE))[i-12288] = z;
  }
}

// ---- sync primitives ----
__device__ __forceinline__ void setflag(unsigned* p, unsigned v){
  asm volatile("global_atomic_swap %0, %1, off" :: "v"(p), "v"(v) : "memory");
}

// poll one flag set with backoff
__device__ __forceinline__ void poll1(unsigned* wsu, int fb, unsigned tgt, int tid){
  if (tid < 64) {
    const unsigned* p0 = wsu + fb + 16*tid;
    for (;;) {
      unsigned v0;
      asm volatile("global_load_dword %0, %1, off sc0 sc1\n\t"
                   "s_waitcnt vmcnt(0)"
                   : "=&v"(v0) : "v"(p0) : "memory");
      if (__all(v0 >= tgt)) break;
      __builtin_amdgcn_s_sleep(1);
    }
  }
  asm volatile("s_waitcnt vmcnt(0)" ::: "memory");
  __builtin_amdgcn_sched_barrier(0);
  __syncthreads();
}

// poll two flag sets with backoff
__device__ __forceinline__ void poll2(unsigned* wsu, int fb0, unsigned tgt0,
                                      int fb1, unsigned tgt1, int tid){
  if (tid < 64) {
    const unsigned* p0 = wsu + fb0 + 16*tid;
    const unsigned* p1 = wsu + fb1 + 16*tid;
    for (;;) {
      unsigned v0, v1;
      asm volatile("global_load_dword %0, %2, off sc0 sc1\n\t"
                   "global_load_dword %1, %3, off sc0 sc1\n\t"
                   "s_waitcnt vmcnt(0)"
                   : "=&v"(v0), "=&v"(v1) : "v"(p0), "v"(p1) : "memory");
      if (__all((v0 >= tgt0) && (v1 >= tgt1))) break;
      __builtin_amdgcn_s_sleep(1);
    }
  }
  asm volatile("s_waitcnt vmcnt(0)" ::: "memory");
  __builtin_amdgcn_sched_barrier(0);
  __syncthreads();
}

// write-once-slot batch: 8 PLAIN CACHED 16B loads (L2 multicast across the
// ~8 same-(layer,half) WGs per XCD); pointers pre-offset +4096; each pointer
// serves a ks pair via offsets {-4096, 0}. Safe because slots are write-once
// per launch and the kernel entry does an agent-acquire fence (v9-proven).
#define ISSUE8T(A, P0, P1, P2, P3) asm volatile( \
  "global_load_dwordx4 %0, %8, off offset:-4096\n\t" \
  "global_load_dwordx4 %1, %8, off\n\t" \
  "global_load_dwordx4 %2, %9, off offset:-4096\n\t" \
  "global_load_dwordx4 %3, %9, off\n\t" \
  "global_load_dwordx4 %4, %10, off offset:-4096\n\t" \
  "global_load_dwordx4 %5, %10, off\n\t" \
  "global_load_dwordx4 %6, %11, off offset:-4096\n\t" \
  "global_load_dwordx4 %7, %11, off" \
  : "=&v"(A[0]), "=&v"(A[1]), "=&v"(A[2]), "=&v"(A[3]), \
    "=&v"(A[4]), "=&v"(A[5]), "=&v"(A[6]), "=&v"(A[7]) \
  : "v"(P0), "v"(P1), "v"(P2), "v"(P3) : "memory")

#define WAITV(N) do{ asm volatile("s_waitcnt vmcnt(" #N ")" ::: "memory"); \
                     __builtin_amdgcn_sched_barrier(0x106); }while(0)

// 8 k-steps of DUAL-gate MFMA; F weights at ks, C weights at KSC+ks
#define CONS8D(Aarr, KSB, KSC) do{ \
  _Pragma("unroll") \
  for (int j = 0; j < 8; ++j){ \
    f16x8 bw = ldsA[(size_t)((KSB)+j)*64]; \
    f16x8 cw = ldsA[(size_t)((KSC)+(KSB)+j)*64]; \
    if (j & 1){ aF1 = MFMA16(Aarr[j], bw, aF1, 0,0,0); aC1 = MFMA16(Aarr[j], cw, aC1, 0,0,0); } \
    else      { aF0 = MFMA16(Aarr[j], bw, aF0, 0,0,0); aC0 = MFMA16(Aarr[j], cw, aC0, 0,0,0); } \
  } \
}while(0)

__device__ __forceinline__ f16x8 cvt8(float4 v0, float4 v1){
  f16x8 a;
  a[0]=v0.x; a[1]=v0.y; a[2]=v0.z; a[3]=v0.w;
  a[4]=v1.x; a[5]=v1.y; a[6]=v1.z; a[7]=v1.w;
  return a;
}

__global__ __launch_bounds__(256,1) void janet_persistent(
    const float* __restrict__ x,
    const float* __restrict__ Wf0, const float* __restrict__ bf0,
    const float* __restrict__ Wc0, const float* __restrict__ bc0,
    const float* __restrict__ Wf1, const float* __restrict__ bf1,
    const float* __restrict__ Wc1, const float* __restrict__ bc1,
    const float* __restrict__ Wfc, const float* __restrict__ bfc,
    float* __restrict__ out, void* __restrict__ ws)
{
  __shared__ __align__(16) unsigned char smem[135168];   // 128KB W + 4KB xchg
  // clear stale L1/L2 lines from the previous graph replay (write-once scheme)
  __builtin_amdgcn_fence(__ATOMIC_ACQUIRE, "agent");

  unsigned* wsu = (unsigned*)ws;
  char* h0base = (char*)ws + H0F_BYTE;
  char* h1base = (char*)ws + H1F_BYTE;

  const int wid  = blockIdx.x;
  const int tid  = threadIdx.x;
  const bool isL0 = (wid < 128);
  const int half = (wid >> 6) & 1;
  const int lw   = wid & 63;           // col-group
  const int col0 = lw * 16;
  const int K    = isL0 ? (Ff + Hh) : (2*Hh);   // 1536 / 2048
  const int KS   = K >> 5;                      // 48 / 64

  // ---- stage weights into LDS in MFMA B-fragment order [gate][ks][lane] ----
  {
    const float* Wg[2] = { isL0 ? Wf0 : Wf1, isL0 ? Wc0 : Wc1 };
    for (int g = 0; g < 2; ++g) {
      const float* W = Wg[g];
      for (int e = tid; e < 16*K; e += 256) {
        int n = e & 15, k = e >> 4;
        float v = W[(size_t)k*Hh + col0 + n];
        int ks = k >> 5, sub = (k >> 3) & 3, j = k & 7;
        int lane = n + (sub << 4);
        int byte = ((g*KS + ks) << 10) + (lane << 4) + (j << 1);
        *(f16*)(smem + byte) = (f16)v;
      }
    }
  }
  __syncthreads();

  const int lane = tid & 63;
  const int wv   = tid >> 6;
  const int rt   = wv & 1;         // row-tile within the 32-row half
  const int kh   = wv >> 1;        // K-half: which half of the reduction axis
  const int n    = lane & 15;
  const int kg   = lane >> 4;
  const int e8   = kg * 8;
  const int lrow = rt*16 + n;      // local row this lane LOADS (A-frag)
  const int grow = half*32 + lrow; // global batch row (x addressing)
  const int part = n & 3;
  const int rsel = n >> 2;
  const int srowl = rt*16 + 4*kg + rsel;

  const float* bfp = isL0 ? bf0 : bf1;
  const float* bcp = isL0 ? bc0 : bc1;
  const float bfv = bfp[col0 + n];
  const float bcv = bcp[col0 + n];

  const f16x8* ldsA = (const f16x8*)(smem + (size_t)lane*16);
  const size_t rdoff = (size_t)(kg>>1)*2048 + (size_t)half*1024
                     + (size_t)lrow*32 + (size_t)(kg&1)*16 + 4096;
  // partial-sum exchange: CONTIGUOUS 16B per lane (conflict-free; v14's 32B
  // stride was a 16-way bank conflict -> 6.75M SQ_LDS_BANK_CONFLICT)
  float* xchgF = (float*)(smem + 131072 + rt*1024 + lane*16);
  float* xchgC = (float*)(smem + 133120 + rt*1024 + lane*16);

  const int fl0 = FL0_U32 + (half*64)*16;
  const int fl1 = FL1_U32 + (half*64)*16;

  f32x4 cst = {0.f,0.f,0.f,0.f};

  if (isL0) {
    for (int t = 0; t < Ss; ++t) {
      f32x4 aF0={0.f,0.f,0.f,0.f}, aF1={0.f,0.f,0.f,0.f};
      f32x4 aC0={0.f,0.f,0.f,0.f}, aC1={0.f,0.f,0.f,0.f};
      // ---- x sub-range for this K-half wave, fully BEFORE the poll ----
      const float* xb = x + ((size_t)grow*Ss + (size_t)t)*Ff + (size_t)kh*256 + e8;
      float4 xv0[8], xv1[8];
      #pragma unroll
      for (int i = 0; i < 8; ++i) {
        xv0[i] = *(const float4*)(xb + 32*i);
        xv1[i] = *(const float4*)(xb + 32*i + 4);
      }
      #pragma unroll
      for (int i = 0; i < 8; ++i) {
        f16x8 a  = cvt8(xv0[i], xv1[i]);
        int ks = kh*8 + i;
        f16x8 bw = ldsA[(size_t)ks*64];
        f16x8 cw = ldsA[(size_t)(48 + ks)*64];
        if (i & 1){ aF1 = MFMA16(a, bw, aF1, 0,0,0); aC1 = MFMA16(a, cw, aC1, 0,0,0); }
        else      { aF0 = MFMA16(a, bw, aF0, 0,0,0); aC0 = MFMA16(a, cw, aC0, 0,0,0); }
      }
      // ---- wait: h0(t-1) written (write-once: no WAR term) ----
      poll1(wsu, fl0, (unsigned)t, tid);
      // ---- h0(t-1) = slot t: wave kh covers h k-steps [kh*16, kh*16+16) ----
      const char* hb = h0base + (size_t)t*SLOTB + rdoff + (size_t)kh*65536;
      f16x8 A0[8], A1[8];
      __builtin_amdgcn_sched_barrier(0);
      ISSUE8T(A0, hb,       hb+8192,  hb+16384, hb+24576);
      ISSUE8T(A1, hb+32768, hb+40960, hb+49152, hb+57344);
      WAITV(8); CONS8D(A0, 16 + kh*16, 48);
      WAITV(0); CONS8D(A1, 24 + kh*16, 48);
      // ---- K-half reduce: kh=1 -> LDS -> kh=0 adds; acts+store by kh=0 ----
      f32x4 pF = aF0 + aF1, pC = aC0 + aC1;
      if (kh == 1) { *(f32x4*)xchgF = pF; *(f32x4*)xchgC = pC; }
      __syncthreads();
      if (kh == 0) {
        pF += *(const f32x4*)xchgF;
        pC += *(const f32x4*)xchgC;
        unsigned cu[4];
        #pragma unroll
        for (int j = 0; j < 4; ++j) {
          float f  = sigm(pF[j] + bfv);
          float ct = tanhf_(pC[j] + bcv);
          cst[j] = f*cst[j] + (1.0f - f)*ct;
          union { _Float16 h; unsigned short u; } cv; cv.h = (f16)tanhf_(cst[j]);
          cu[j] = cv.u;
        }
        unsigned u01 = cu[0] | (cu[1] << 16);
        unsigned u23 = cu[2] | (cu[3] << 16);
        int sb = (kg << 4) + (part << 2);
        unsigned wsel[4];
        #pragma unroll
        for (int i = 0; i < 4; ++i) {
          unsigned w01 = __shfl(u01, sb + i, 64);
          unsigned w23 = __shfl(u23, sb + i, 64);
          unsigned w = (rsel < 2) ? w01 : w23;
          wsel[i] = (rsel & 1) ? (w >> 16) : (w & 0xffffu);
        }
        unsigned d0 = wsel[0] | (wsel[1] << 16);
        unsigned d1 = wsel[2] | (wsel[3] << 16);
        uint64_t dd = (uint64_t)d0 | ((uint64_t)d1 << 32);
        char* hd = h0base + (size_t)(t+1)*SLOTB + (size_t)lw*2048
                 + (size_t)half*1024 + (size_t)srowl*32 + (size_t)part*8;
        asm volatile("global_atomic_swap_x2 %0, %1, off" :: "v"(hd), "v"(dd) : "memory");
      }
      asm volatile("s_waitcnt vmcnt(0)" ::: "memory");
      __syncthreads();
      if (tid == 0) setflag(wsu + FL0_U32 + (half*64 + lw)*16, (unsigned)(t+1));
    }
  } else {
    for (int s = 0; s < Ss; ++s) {
      // need h0(s) (fl0>=s+1) and own-layer h1(s-1) (fl1>=s)
      poll2(wsu, fl0, (unsigned)(s+1), fl1, (unsigned)s, tid);
      f32x4 aF0={0.f,0.f,0.f,0.f}, aF1={0.f,0.f,0.f,0.f};
      f32x4 aC0={0.f,0.f,0.f,0.f}, aC1={0.f,0.f,0.f,0.f};
      // wave kh=0: h0(s) = h0 slot s+1; kh=1: h1(s-1) = h1 slot s
      const char* hb = (kh == 0)
        ? h0base + (size_t)(s+1)*SLOTB + rdoff
        : h1base + (size_t)s*SLOTB + rdoff;
      f16x8 A0[8], A1[8], A2[8], A3[8];
      __builtin_amdgcn_sched_barrier(0);
      ISSUE8T(A0, hb,       hb+8192,  hb+16384, hb+24576);
      ISSUE8T(A1, hb+32768, hb+40960, hb+49152, hb+57344);
      ISSUE8T(A2, hb+65536, hb+73728, hb+81920, hb+90112);
      ISSUE8T(A3, hb+98304, hb+106496, hb+114688, hb+122880);
      {
        const int kb = kh*32;
        WAITV(24); CONS8D(A0, kb + 0,  64);
        WAITV(16); CONS8D(A1, kb + 8,  64);
        WAITV(8);  CONS8D(A2, kb + 16, 64);
        WAITV(0);  CONS8D(A3, kb + 24, 64);
      }
      // ---- K-half reduce + acts + store ----
      f32x4 pF = aF0 + aF1, pC = aC0 + aC1;
      if (kh == 1) { *(f32x4*)xchgF = pF; *(f32x4*)xchgC = pC; }
      __syncthreads();
      if (kh == 0) {
        pF += *(const f32x4*)xchgF;
        pC += *(const f32x4*)xchgC;
        unsigned cu[4];
        #pragma unroll
        for (int j = 0; j < 4; ++j) {
          float f  = sigm(pF[j] + bfv);
          float ct = tanhf_(pC[j] + bcv);
          cst[j] = f*cst[j] + (1.0f - f)*ct;
          union { _Float16 h; unsigned short u; } cv; cv.h = (f16)tanhf_(cst[j]);
          cu[j] = cv.u;
        }
        unsigned u01 = cu[0] | (cu[1] << 16);
        unsigned u23 = cu[2] | (cu[3] << 16);
        int sb = (kg << 4) + (part << 2);
        unsigned wsel[4];
        #pragma unroll
        for (int i = 0; i < 4; ++i) {
          unsigned w01 = __shfl(u01, sb + i, 64);
          unsigned w23 = __shfl(u23, sb + i, 64);
          unsigned w = (rsel < 2) ? w01 : w23;
          wsel[i] = (rsel & 1) ? (w >> 16) : (w & 0xffffu);
        }
        unsigned d0 = wsel[0] | (wsel[1] << 16);
        unsigned d1 = wsel[2] | (wsel[3] << 16);
        uint64_t dd = (uint64_t)d0 | ((uint64_t)d1 << 32);
        char* hd = h1base + (size_t)(s+1)*SLOTB + (size_t)lw*2048
                 + (size_t)half*1024 + (size_t)srowl*32 + (size_t)part*8;
        asm volatile("global_atomic_swap_x2 %0, %1, off" :: "v"(hd), "v"(dd) : "memory");
      }
      asm volatile("s_waitcnt vmcnt(0)" ::: "memory");
      __syncthreads();
      if (tid == 0) setflag(wsu + FL1_U32 + (half*64 + lw)*16, (unsigned)(s+1));
    }
  }

  // ---- final projection: out = h1(511) @ Wfc + bfc ----
  poll2(wsu, FL1_U32, (unsigned)Ss, FL1_U32 + 64*16, (unsigned)Ss, tid);
  if (tid < 128) {
    const char* fin = h1base + (size_t)Ss*SLOTB;   // slot 512 = h1(511)
    const int o = wid*2 + (tid & 1);
    const int b = tid >> 1;
    const char* rowp = fin + (size_t)(b>>5)*1024 + (size_t)(b&31)*32;
    float acc = bfc[o];
    for (int cg = 0; cg < 64; ++cg) {
      f16x8 lo, hi;
      asm volatile("global_load_dwordx4 %0, %2, off sc0 sc1\n\t"
                   "global_load_dwordx4 %1, %2, off offset:16 sc0 sc1\n\t"
                   "s_waitcnt vmcnt(0)"
                   : "=&v"(lo), "=&v"(hi) : "v"(rowp + (size_t)cg*2048) : "memory");
      #pragma unroll
      for (int i = 0; i < 8; ++i) {
        acc += (float)lo[i] * Wfc[(size_t)(cg*16 + i)*Oo + o];
        acc += (float)hi[i] * Wfc[(size_t)(cg*16 + 8 + i)*Oo + o];
      }
    }
    out[(size_t)b*Oo + o] = acc;
  }
}

extern "C" void kernel_launch(void* const* d_in, const int* in_sizes, int n_in,
                              void* d_out, int out_size, void* d_ws, size_t ws_size,
                              hipStream_t stream) {
  const float* x   = (const float*)d_in[0];
  const float* Wf0 = (const float*)d_in[1];
  const float* bf0 = (const float*)d_in[2];
  const float* Wc0 = (const float*)d_in[3];
  const float* bc0 = (const float*)d_in[4];
  const float* Wf1 = (const float*)d_in[5];
  const float* bf1 = (const float*)d_in[6];
  const float* Wc1 = (const float*)d_in[7];
  const float* bc1 = (const float*)d_in[8];
  const float* Wfc = (const float*)d_in[9];
  const float* bfc = (const float*)d_in[10];

  init_fresh<<<64, 256, 0, stream>>>(d_ws);
  janet_persistent<<<NWG, 256, 0, stream>>>(x, Wf0, bf0, Wc0, bc0,
                                            Wf1, bf1, Wc1, bc1, Wfc, bfc,
                                            (float*)d_out, d_ws);
}